// Round 14
// baseline (5403.855 us; speedup 1.0000x reference)
//
#include <hip/hip_runtime.h>
#include <math.h>

#define B   256
#define TX  50
#define TY  100
#define NX  64
#define NY  64
#define H   512
#define HOR 60
#define M1  1024
#define M2  512
#define G3  (3*H)        // 1536
#define DIN (2*H + NY)   // 1088

typedef __attribute__((ext_vector_type(8))) short short8;
typedef __attribute__((ext_vector_type(4))) float floatx4;

__device__ __forceinline__ unsigned short f2bf(float f) {
    union { float f; unsigned u; } v; v.f = f;
    return (unsigned short)((v.u + 0x7FFFu + ((v.u >> 16) & 1u)) >> 16);
}

__device__ __forceinline__ float sigmoidf_(float v) {
    return 1.f / (1.f + __expf(-v));
}

__device__ __forceinline__ short8 ld8(const unsigned short* p) {
    return *(const short8*)p;
}

__device__ __forceinline__ floatx4 mfma16(short8 a, short8 b, floatx4 c) {
    return __builtin_amdgcn_mfma_f32_16x16x32_bf16(a, b, c, 0, 0, 0);
}

__device__ __forceinline__ void gload_lds16(const void* g, void* lds) {
    __builtin_amdgcn_global_load_lds(
        (const __attribute__((address_space(1))) void*)g,
        (__attribute__((address_space(3))) void*)lds, 16, 0, 0);
}

// ===========================================================================
// BMxBN MFMA GEMM body, 256 threads — double-buffered K-pipeline (r11).
// ===========================================================================
template<int BM, int BN>
__device__ __forceinline__ void mgemm_body(
    int tid, unsigned short* smA, unsigned short* smB,
    const unsigned short* __restrict__ A, int lda, int arow0,
    const unsigned short* __restrict__ W, int ldw, int wrow0,
    const float* __restrict__ bias,
    float* __restrict__ Cf, int ldcf,
    unsigned short* __restrict__ Cb, int ldcb,
    int K, int relu)
{
    constexpr int MF = BM / 32;
    constexpr int NF = BN / 32;
    const int w  = tid >> 6, l = tid & 63;
    const int wr = w >> 1, wc = w & 1;
    const int lg = l >> 4, r16 = l & 15;

    auto stage = [&](int k0, int buf) {
#pragma unroll
        for (int i = 0; i < BM / 64; ++i) {
            const int ci = tid + i * 256;
            const int row = ci >> 2, pc = ci & 3;
            const int lc = pc ^ ((row >> 1) & 3);
            gload_lds16(A + (size_t)(arow0 + row) * lda + k0 + lc * 8,
                        (char*)smA + buf * (BM * 64) + w * 1024 + i * 4096);
        }
#pragma unroll
        for (int i = 0; i < BN / 64; ++i) {
            const int ci = tid + i * 256;
            const int row = ci >> 2, pc = ci & 3;
            const int lc = pc ^ ((row >> 1) & 3);
            gload_lds16(W + (size_t)(wrow0 + row) * ldw + k0 + lc * 8,
                        (char*)smB + buf * (BN * 64) + w * 1024 + i * 4096);
        }
    };

    floatx4 acc[MF][NF];
#pragma unroll
    for (int m = 0; m < MF; ++m)
#pragma unroll
        for (int n = 0; n < NF; ++n) acc[m][n] = floatx4{0.f, 0.f, 0.f, 0.f};

    const int nk = K >> 5;
    stage(0, 0);
    for (int ck = 0; ck < nk; ++ck) {
        __syncthreads();
        if (ck + 1 < nk) stage((ck + 1) << 5, (ck + 1) & 1);
        const unsigned short* bA = smA + (ck & 1) * BM * 32;
        const unsigned short* bB = smB + (ck & 1) * BN * 32;

        short8 af[MF], bfr[NF];
#pragma unroll
        for (int m = 0; m < MF; ++m) {
            const int row = wr * (BM / 2) + m * 16 + r16;
            const int pc = lg ^ ((row >> 1) & 3);
            af[m] = *(const short8*)&bA[row * 32 + pc * 8];
        }
#pragma unroll
        for (int n = 0; n < NF; ++n) {
            const int row = wc * (BN / 2) + n * 16 + r16;
            const int pc = lg ^ ((row >> 1) & 3);
            bfr[n] = *(const short8*)&bB[row * 32 + pc * 8];
        }
#pragma unroll
        for (int m = 0; m < MF; ++m)
#pragma unroll
            for (int n = 0; n < NF; ++n)
                acc[m][n] = mfma16(af[m], bfr[n], acc[m][n]);
    }

#pragma unroll
    for (int m = 0; m < MF; ++m) {
#pragma unroll
        for (int n = 0; n < NF; ++n) {
#pragma unroll
            for (int j = 0; j < 4; ++j) {
                const int r = arow0 + wr * (BM / 2) + m * 16 + lg * 4 + j;
                const int c = wrow0 + wc * (BN / 2) + n * 16 + r16;
                float v = acc[m][n][j];
                if (bias) v += bias[c];
                if (relu && v < 0.f) v = 0.f;
                if (Cf) Cf[(size_t)r * ldcf + c] = v;
                if (Cb) Cb[(size_t)r * ldcb + c] = f2bf(v);
            }
        }
    }
}

template<int BM, int BN>
__global__ __launch_bounds__(256, 1) void k_mgemm(
    const unsigned short* __restrict__ A, int lda,
    const unsigned short* __restrict__ W, int ldw,
    const float* __restrict__ bias,
    float* __restrict__ Cf, int ldcf,
    unsigned short* __restrict__ Cb, int ldcb,
    int K, int relu)
{
    __shared__ __align__(16) unsigned short smA[2 * BM * 32];
    __shared__ __align__(16) unsigned short smB[2 * BN * 32];
    mgemm_body<BM, BN>(threadIdx.x, smA, smB, A, lda, blockIdx.y * BM,
                       W, ldw, blockIdx.x * BN, bias,
                       Cf, ldcf, Cb, ldcb, K, relu);
}

// ===========================================================================
// fused fp32 -> bf16 conversion (18 segments, one launch)
// ===========================================================================
struct CvtArgs {
    const float* src[18];
    unsigned short* dst[18];
    int n[18];
};

__global__ __launch_bounds__(256) void k_cvt_all(CvtArgs a)
{
    const int seg = blockIdx.y;
    const float* s = a.src[seg];
    unsigned short* d = a.dst[seg];
    const int c4 = a.n[seg] >> 2;
    for (int i = blockIdx.x * 256 + threadIdx.x; i < c4; i += gridDim.x * 256) {
        float4 v = ((const float4*)s)[i];
        ushort4 o;
        o.x = f2bf(v.x); o.y = f2bf(v.y); o.z = f2bf(v.z); o.w = f2bf(v.w);
        ((ushort4*)d)[i] = o;
    }
}

// ===========================================================================
// h_x = hxf + hxb ; h_y = hef + heb ; hcat = [h_x,h_y] bf16 ; cz[:, :H] = h_x
// ===========================================================================
__global__ __launch_bounds__(256) void k_sum_concat(
    const float* __restrict__ Hs,
    unsigned short* __restrict__ hcatb, unsigned short* __restrict__ czb)
{
    const int idx = blockIdx.x * 256 + threadIdx.x;  // B*H
    const int b = idx / H, i = idx % H;
    const float hx = Hs[idx] + Hs[(size_t)B * H + idx];
    const float hy = Hs[2 * (size_t)B * H + idx] + Hs[3 * (size_t)B * H + idx];
    const unsigned short hxb = f2bf(hx);
    hcatb[(size_t)b * (2 * H) + i] = hxb;
    hcatb[(size_t)b * (2 * H) + H + i] = f2bf(hy);
    czb[(size_t)b * (2 * H) + i] = hxb;
}

// ===========================================================================
// Fused encoder step (r13-proven): ONE launch per time step, double-buffered,
// __launch_bounds__(512, 2).
// ===========================================================================
struct EncP {
    const unsigned short *xb, *yb;
    unsigned short *Hsb0, *Hsb1;
    float* Hs;
    const unsigned short *wih[4], *whh[4];
    const float *bih[4], *bhh[4];
    int t, job0;
};

__global__ __launch_bounds__(512, 2) void k_enc_step(EncP p)
{
    __shared__ __align__(16) char smA[2 * 8192];    // 2 x 128x32 bf16
    __shared__ __align__(16) char smB[2 * 12288];   // 2 x 192x32 bf16
    const int job = p.job0 + blockIdx.z;
    const int h0 = blockIdx.x * 64;
    const int row0 = blockIdx.y * 128;
    const int tid = threadIdx.x;
    const int w = tid >> 6, l = tid & 63;
    const int lg = l >> 4, r16 = l & 15;
    const int wrh = w >> 2, wcg = w & 3;
    const int T = (job < 2) ? TX : TY;
    const int tt = (job & 1) ? (T - 1 - p.t) : p.t;
    const unsigned short* xsrc = (job < 2) ? p.xb : p.yb;
    const unsigned short* wihg = p.wih[job];
    const unsigned short* whhg = p.whh[job];
    const unsigned short* hin =
        ((p.t & 1) ? p.Hsb1 : p.Hsb0) + (size_t)job * B * H;
    unsigned short* hout =
        ((p.t & 1) ? p.Hsb0 : p.Hsb1) + (size_t)job * B * H;

    const int sAr = tid >> 2;
    const int sAl = (tid & 3) ^ ((sAr >> 1) & 3);
    const int f0 = sAr >> 4;
    const int W0 = (f0 % 3) * H + h0 + (f0 / 3) * 16 + (sAr & 15);
    const int sB1r = 128 + (tid >> 2);             // tid<256 only
    const int sB1l = (tid & 3) ^ ((sB1r >> 1) & 3);
    const int f1 = sB1r >> 4;
    const int W1 = (f1 % 3) * H + h0 + (f1 / 3) * 16 + (sB1r & 15);

    auto stage = [&](int ck, int buf) {
        char* dA  = smA + buf * 8192 + tid * 16;
        char* dB0 = smB + buf * 12288 + tid * 16;
        char* dB1 = smB + buf * 12288 + 8192 + tid * 16;
        if (ck < 16) {
            gload_lds16(hin + (size_t)(row0 + sAr) * H + ck * 32 + sAl * 8, dA);
            gload_lds16(whhg + (size_t)W0 * H + ck * 32 + sAl * 8, dB0);
            if (tid < 256)
                gload_lds16(whhg + (size_t)W1 * H + ck * 32 + sB1l * 8, dB1);
        } else {
            const int kk = (ck - 16) * 32;
            gload_lds16(xsrc + ((size_t)(row0 + sAr) * T + tt) * NX + kk + sAl * 8, dA);
            gload_lds16(wihg + (size_t)W0 * NX + kk + sAl * 8, dB0);
            if (tid < 256)
                gload_lds16(wihg + (size_t)W1 * NX + kk + sB1l * 8, dB1);
        }
    };

    floatx4 am[4][3], axn[4];
#pragma unroll
    for (int m = 0; m < 4; ++m) {
        axn[m] = floatx4{0.f, 0.f, 0.f, 0.f};
#pragma unroll
        for (int g = 0; g < 3; ++g) am[m][g] = floatx4{0.f, 0.f, 0.f, 0.f};
    }

    stage(0, 0);
    for (int ck = 0; ck < 18; ++ck) {
        __syncthreads();
        if (ck + 1 < 18) stage(ck + 1, (ck + 1) & 1);
        const char* bA = smA + (ck & 1) * 8192;
        const char* bB = smB + (ck & 1) * 12288;

        short8 af[4], bf[3];
#pragma unroll
        for (int m = 0; m < 4; ++m) {
            const int row = wrh * 64 + m * 16 + r16;
            af[m] = *(const short8*)(bA + row * 64 + ((lg ^ ((row >> 1) & 3)) << 4));
        }
#pragma unroll
        for (int g = 0; g < 3; ++g) {
            const int rb = wcg * 48 + g * 16 + r16;
            bf[g] = *(const short8*)(bB + rb * 64 + ((lg ^ ((rb >> 1) & 3)) << 4));
        }
        if (ck < 16) {
#pragma unroll
            for (int m = 0; m < 4; ++m) {
                am[m][0] = mfma16(af[m], bf[0], am[m][0]);
                am[m][1] = mfma16(af[m], bf[1], am[m][1]);
                am[m][2] = mfma16(af[m], bf[2], am[m][2]);
            }
        } else {
#pragma unroll
            for (int m = 0; m < 4; ++m) {
                am[m][0] = mfma16(af[m], bf[0], am[m][0]);
                am[m][1] = mfma16(af[m], bf[1], am[m][1]);
                axn[m]   = mfma16(af[m], bf[2], axn[m]);
            }
        }
    }

    // ---- gate epilogue ----
    const int u = h0 + wcg * 16 + r16;
    const float bi0 = p.bih[job][u]        + p.bhh[job][u];
    const float bi1 = p.bih[job][H + u]    + p.bhh[job][H + u];
    const float bi2 = p.bih[job][2 * H + u];
    const float bh2 = p.bhh[job][2 * H + u];
    float* HsJ = p.Hs + (size_t)job * B * H;
#pragma unroll
    for (int m = 0; m < 4; ++m) {
#pragma unroll
        for (int j = 0; j < 4; ++j) {
            const int br = row0 + wrh * 64 + m * 16 + lg * 4 + j;
            const float rr = sigmoidf_(am[m][0][j] + bi0);
            const float zz = sigmoidf_(am[m][1][j] + bi1);
            const float nn = tanhf(axn[m][j] + bi2 + rr * (am[m][2][j] + bh2));
            const float hold = HsJ[(size_t)br * H + u];
            const float hv = (1.f - zz) * nn + zz * hold;
            HsJ[(size_t)br * H + u] = hv;
            hout[(size_t)br * H + u] = f2bf(hv);
        }
    }
}

// ===========================================================================
// Decoder step kernel k_dec1 — 16 blocks x 512 thr, __launch_bounds__(512,2).
// Block owns 16 rows x all 512 hidden. Phases:
//   S  (mode!=0): stage hm1 (16x1024) into swizzled LDS
//   M2 (mode!=0): hm2 = relu(hm1 @ W2^T + b2)  [K=1024, direct W2 loads]
//   A  (mode!=0): y_{t-1} = hm2 @ doW^T + dob -> outp + ytile
//        mode==0: ytile = x[:, TX-1, :]
//   B  (mode!=2): xgd (K=64) + gates -> hd, hdb
// ===========================================================================
struct DecQ {
    const unsigned short* xb;
    unsigned short* hdb;
    float* hd;
    const float* hga;
    const float* constb;
    const unsigned short* dWihb;
    const float* dbhh;
    const unsigned short* doWb;  const float* dob;
    const unsigned short* hm1b;
    const unsigned short* dmW2b; const float* dmb2;
    float* outp;
    int mode, tprev;
};

__global__ __launch_bounds__(512, 2) void k_dec1(DecQ p)
{
    __shared__ __align__(16) unsigned short hm1t[16 * 1024];  // 32KB swizzled
    __shared__ __align__(16) unsigned short hm2t[16 * 512];   // 16KB swizzled
    __shared__ __align__(16) unsigned short ytile[16 * 64];   // 2KB swizzled
    const int bid = blockIdx.x;
    const int r0 = bid * 16;
    const int tid = threadIdx.x;
    const int w = tid >> 6, l = tid & 63;
    const int lg = l >> 4, r16 = l & 15;

    if (p.mode != 0) {
        // ---- S: stage hm1 (16 rows x 1024) swizzled: 4 x short8 per thread ----
#pragma unroll
        for (int c = 0; c < 4; ++c) {
            const int cid = tid + c * 512;        // 8-short chunk id, 0..2047
            const int row = cid >> 7, k8 = cid & 127;
            const short8 v = ld8(p.hm1b + (size_t)(r0 + row) * M1 + k8 * 8);
            *(short8*)((char*)hm1t + row * 2048 + ((k8 * 16) ^ ((row & 7) << 4))) = v;
        }
        __syncthreads();

        // ---- M2: hm2 = relu(hm1 @ W2^T + b2); wave w owns cols [w*64,+64) ----
        floatx4 m2[4];
#pragma unroll
        for (int f = 0; f < 4; ++f) m2[f] = floatx4{0.f, 0.f, 0.f, 0.f};
#pragma unroll 2
        for (int kc = 0; kc < 32; ++kc) {
            const short8 af = *(const short8*)((char*)hm1t + r16 * 2048
                                + ((kc * 64 + lg * 16) ^ ((r16 & 7) << 4)));
#pragma unroll
            for (int f = 0; f < 4; ++f) {
                const int col = w * 64 + f * 16 + r16;
                const short8 bv = ld8(p.dmW2b + (size_t)col * M1 + kc * 32 + lg * 8);
                m2[f] = mfma16(af, bv, m2[f]);
            }
        }
#pragma unroll
        for (int f = 0; f < 4; ++f) {
            const int col = w * 64 + f * 16 + r16;
            const float bia = p.dmb2[col];
#pragma unroll
            for (int j = 0; j < 4; ++j) {
                const int row = lg * 4 + j;
                float v = m2[f][j] + bia;
                if (v < 0.f) v = 0.f;
                *(unsigned short*)((char*)hm2t + row * 1024
                    + ((col * 2) ^ ((row & 7) << 4))) = f2bf(v);
            }
        }
        __syncthreads();

        // ---- A: y = hm2 @ doW^T + dob (16 x 64, K=512); waves 0-3 ----
        if (w < 4) {
            const int col = w * 16 + r16;
            floatx4 acc = floatx4{0.f, 0.f, 0.f, 0.f};
#pragma unroll 4
            for (int kc = 0; kc < 16; ++kc) {
                const short8 af = *(const short8*)((char*)hm2t + r16 * 1024
                                    + ((kc * 64 + lg * 16) ^ ((r16 & 7) << 4)));
                const short8 bv = ld8(p.doWb + (size_t)col * M2 + kc * 32 + lg * 8);
                acc = mfma16(af, bv, acc);
            }
            const float bia = p.dob[col];
#pragma unroll
            for (int j = 0; j < 4; ++j) {
                const int row = lg * 4 + j;
                const float v = acc[j] + bia;
                p.outp[(size_t)(r0 + row) * (HOR * NY) + (size_t)p.tprev * NY + col] = v;
                *(unsigned short*)((char*)ytile + row * 128
                    + ((col * 2) ^ ((row & 7) << 4))) = f2bf(v);
            }
        }
    } else {
        // ---- ytile = x[:, TX-1, :]  (16x64 = 1024 shorts; 512 thr x 2) ----
        const int i = tid * 2;
        const int row = i >> 6, col = i & 63;
        const unsigned short* s = p.xb + ((size_t)(r0 + row) * TX + TX - 1) * NX + col;
        const unsigned v = (unsigned)s[0] | ((unsigned)s[1] << 16);
        *(unsigned*)((char*)ytile + row * 128 + ((col * 2) ^ ((row & 7) << 4))) = v;
    }
    if (p.mode == 2) return;
    __syncthreads();

    // ---- B: xgd (16 x 1536, K=64) + gates; wave w owns hidden [w*64,+64) ----
    const int u0 = w * 64;
    short8 ya[2];
#pragma unroll
    for (int ks = 0; ks < 2; ++ks) {
        const int k0 = ks * 32 + lg * 8;
        ya[ks] = *(const short8*)((char*)ytile + r16 * 128
                    + ((k0 * 2) ^ ((r16 & 7) << 4)));
    }
    floatx4 ag[3][4];
#pragma unroll
    for (int g = 0; g < 3; ++g)
#pragma unroll
        for (int f = 0; f < 4; ++f) ag[g][f] = floatx4{0.f, 0.f, 0.f, 0.f};
#pragma unroll
    for (int ks = 0; ks < 2; ++ks)
#pragma unroll
        for (int g = 0; g < 3; ++g)
#pragma unroll
            for (int f = 0; f < 4; ++f) {
                const int u = u0 + f * 16 + r16;
                const short8 xw = ld8(p.dWihb + (size_t)(g * H + u) * DIN
                                              + 2 * H + ks * 32 + lg * 8);
                ag[g][f] = mfma16(ya[ks], xw, ag[g][f]);
            }

#pragma unroll
    for (int f = 0; f < 4; ++f) {
        const int u = u0 + f * 16 + r16;
        const float db0 = p.dbhh[u], db1 = p.dbhh[H + u], db2 = p.dbhh[2 * H + u];
#pragma unroll
        for (int j = 0; j < 4; ++j) {
            const int row = lg * 4 + j;
            const int b = r0 + row;
            const size_t g3 = (size_t)b * G3;
            const float xr = ag[0][f][j] + p.constb[g3 + u];
            const float xz = ag[1][f][j] + p.constb[g3 + H + u];
            const float xn = ag[2][f][j] + p.constb[g3 + 2 * H + u];
            const float hr = p.hga[g3 + u] + db0;
            const float hz = p.hga[g3 + H + u] + db1;
            const float hn = p.hga[g3 + 2 * H + u] + db2;
            const float rr = sigmoidf_(xr + hr);
            const float zz = sigmoidf_(xz + hz);
            const float nn = tanhf(xn + rr * hn);
            const float hold = p.hd[(size_t)b * H + u];
            const float hv = (1.f - zz) * nn + zz * hold;
            p.hd[(size_t)b * H + u] = hv;
            p.hdb[(size_t)b * H + u] = f2bf(hv);
        }
    }
}

// ===========================================================================
// kE: hga_next (48 roles) || MLP1 (32 roles) — 80 blocks x 256 threads.
// ===========================================================================
__global__ __launch_bounds__(256, 1) void k_dec_bk(
    const unsigned short* __restrict__ hdb,
    const unsigned short* __restrict__ dWhhb,
    const unsigned short* __restrict__ dmW1b, const float* __restrict__ dmb1,
    float* __restrict__ hga, unsigned short* __restrict__ hm1b)
{
    __shared__ __align__(16) unsigned short smA[2 * 64 * 32];
    __shared__ __align__(16) unsigned short smB[2 * 128 * 32];
    const int bid = blockIdx.x;
    if (bid < 48) {
        const int arow0 = (bid & 3) * 64, wrow0 = (bid >> 2) * 128;
        mgemm_body<64, 128>(threadIdx.x, smA, smB, hdb, H, arow0,
                            dWhhb, H, wrow0, nullptr,
                            hga, G3, nullptr, 0, H, 0);
    } else {
        const int b2 = bid - 48;
        const int arow0 = (b2 & 3) * 64, wrow0 = (b2 >> 2) * 128;
        mgemm_body<64, 128>(threadIdx.x, smA, smB, hdb, H, arow0,
                            dmW1b, H, wrow0, dmb1,
                            nullptr, 0, hm1b, M1, H, 1);
    }
}

// ===========================================================================
extern "C" void kernel_launch(void* const* d_in, const int* in_sizes, int n_in,
                              void* d_out, int out_size, void* d_ws, size_t ws_size,
                              hipStream_t stream)
{
    const float* x      = (const float*)d_in[0];
    const float* y      = (const float*)d_in[1];
    const float* xf_bih = (const float*)d_in[4];
    const float* xf_bhh = (const float*)d_in[5];
    const float* xb_bih = (const float*)d_in[8];
    const float* xb_bhh = (const float*)d_in[9];
    const float* ef_bih = (const float*)d_in[12];
    const float* ef_bhh = (const float*)d_in[13];
    const float* eb_bih = (const float*)d_in[16];
    const float* eb_bhh = (const float*)d_in[17];
    const float* em_b1  = (const float*)d_in[19];
    const float* em_b2  = (const float*)d_in[21];
    const float* eo_b   = (const float*)d_in[23];
    const float* d_bih  = (const float*)d_in[26];
    const float* d_bhh  = (const float*)d_in[27];
    const float* dm_b1  = (const float*)d_in[29];
    const float* dm_b2  = (const float*)d_in[31];
    const float* do_b   = (const float*)d_in[33];
    float* out = (float*)d_out;

    // ---- workspace carve-up ----
    float* fp = (float*)d_ws;
    float* Hs     = fp; fp += 4 * (size_t)B * H;
    float* hd     = fp; fp += (size_t)B * H;
    float* hga    = fp; fp += (size_t)B * G3;
    float* constb = fp; fp += (size_t)B * G3;

    unsigned short* up = (unsigned short*)fp;
    unsigned short* xb16  = up; up += (size_t)B * TX * NX;
    unsigned short* yb16  = up; up += (size_t)B * TY * NY;
    unsigned short* Hsb0  = up; up += 4 * (size_t)B * H;
    unsigned short* Hsb1  = up; up += 4 * (size_t)B * H;
    unsigned short* hdb   = up; up += (size_t)B * H;
    unsigned short* hcatb = up; up += (size_t)B * 2 * H;
    unsigned short* czb   = up; up += (size_t)B * 2 * H;
    unsigned short* h1b   = up; up += (size_t)B * M1;
    unsigned short* h2b   = up; up += (size_t)B * M2;
    unsigned short* hm1b  = up; up += (size_t)B * M1;
    unsigned short* hm2b  = up; up += (size_t)B * M2;

    const int    widx[16] = {2, 3, 6, 7, 10, 11, 14, 15, 18, 20, 22, 24, 25, 28, 30, 32};
    const size_t wsz[16]  = {
        (size_t)G3 * NX, (size_t)G3 * H, (size_t)G3 * NX, (size_t)G3 * H,
        (size_t)G3 * NX, (size_t)G3 * H, (size_t)G3 * NX, (size_t)G3 * H,
        (size_t)M1 * 2 * H, (size_t)M2 * M1, (size_t)H * M2,
        (size_t)G3 * DIN, (size_t)G3 * H, (size_t)M1 * H, (size_t)M2 * M1,
        (size_t)NY * M2};
    unsigned short* wb[16];
    for (int i = 0; i < 16; ++i) { wb[i] = up; up += wsz[i]; }

    // ---- conversions + state init ----
    CvtArgs ca;
    for (int i = 0; i < 16; ++i) {
        ca.src[i] = (const float*)d_in[widx[i]];
        ca.dst[i] = wb[i];
        ca.n[i]   = (int)wsz[i];
    }
    ca.src[16] = x; ca.dst[16] = xb16; ca.n[16] = B * TX * NX;
    ca.src[17] = y; ca.dst[17] = yb16; ca.n[17] = B * TY * NY;
    k_cvt_all<<<dim3(64, 18), 256, 0, stream>>>(ca);

    hipMemsetAsync(Hs,   0, sizeof(float) * 4 * (size_t)B * H, stream);
    hipMemsetAsync(Hsb0, 0, sizeof(unsigned short) * 4 * (size_t)B * H, stream);
    hipMemsetAsync(hd,   0, sizeof(float) * (size_t)B * H, stream);
    hipMemsetAsync(hga,  0, sizeof(float) * (size_t)B * G3, stream);

    // ---- encoder: 1 fused launch per step ----
    EncP ep;
    ep.xb = xb16; ep.yb = yb16; ep.Hsb0 = Hsb0; ep.Hsb1 = Hsb1; ep.Hs = Hs;
    ep.wih[0] = wb[0]; ep.whh[0] = wb[1];
    ep.wih[1] = wb[2]; ep.whh[1] = wb[3];
    ep.wih[2] = wb[4]; ep.whh[2] = wb[5];
    ep.wih[3] = wb[6]; ep.whh[3] = wb[7];
    ep.bih[0] = xf_bih; ep.bhh[0] = xf_bhh;
    ep.bih[1] = xb_bih; ep.bhh[1] = xb_bhh;
    ep.bih[2] = ef_bih; ep.bhh[2] = ef_bhh;
    ep.bih[3] = eb_bih; ep.bhh[3] = eb_bhh;
    for (int t = 0; t < TY; ++t) {
        ep.t = t;
        ep.job0 = (t < TX) ? 0 : 2;
        const int nj = (t < TX) ? 4 : 2;
        k_enc_step<<<dim3(8, 2, nj), 512, 0, stream>>>(ep);
    }

    // ---- bottleneck MLP ----
    k_sum_concat<<<B * H / 256, 256, 0, stream>>>(Hs, hcatb, czb);
    k_mgemm<128, 128><<<dim3(M1 / 128, B / 128), 256, 0, stream>>>(
        hcatb, 2 * H, wb[8], 2 * H, em_b1, nullptr, 0, h1b, M1, 2 * H, 1);
    k_mgemm<128, 128><<<dim3(M2 / 128, B / 128), 256, 0, stream>>>(
        h1b, M1, wb[9], M1, em_b2, nullptr, 0, h2b, M2, M1, 1);
    k_mgemm<128, 128><<<dim3(H / 128, B / 128), 256, 0, stream>>>(
        h2b, M2, wb[10], M2, eo_b, nullptr, 0, czb + H, 2 * H, M2, 0);
    k_mgemm<128, 128><<<dim3(G3 / 128, B / 128), 256, 0, stream>>>(
        czb, 2 * H, wb[11], DIN, d_bih, constb, G3, nullptr, 0, 2 * H, 0);

    // ---- decoder: 2 launches per step ----
    DecQ dq;
    dq.xb = xb16; dq.hdb = hdb; dq.hd = hd; dq.hga = hga; dq.constb = constb;
    dq.dWihb = wb[11]; dq.dbhh = d_bhh;
    dq.doWb = wb[15]; dq.dob = do_b;
    dq.hm1b = hm1b; dq.dmW2b = wb[14]; dq.dmb2 = dm_b2;
    dq.outp = out;
    for (int t = 0; t < HOR; ++t) {
        dq.mode = (t == 0) ? 0 : 1;
        dq.tprev = t - 1;
        k_dec1<<<16, 512, 0, stream>>>(dq);
        k_dec_bk<<<80, 256, 0, stream>>>(hdb, wb[12], wb[13], dm_b1, hga, hm1b);
    }
    dq.mode = 2;
    dq.tprev = HOR - 1;
    k_dec1<<<16, 512, 0, stream>>>(dq);
}

// Round 15
// 4741.813 us; speedup vs baseline: 1.1396x; 1.1396x over previous
//
#include <hip/hip_runtime.h>
#include <math.h>

#define B   256
#define TX  50
#define TY  100
#define NX  64
#define NY  64
#define H   512
#define HOR 60
#define M1  1024
#define M2  512
#define G3  (3*H)        // 1536
#define DIN (2*H + NY)   // 1088

typedef __attribute__((ext_vector_type(8))) short short8;
typedef __attribute__((ext_vector_type(4))) float floatx4;

__device__ __forceinline__ unsigned short f2bf(float f) {
    union { float f; unsigned u; } v; v.f = f;
    return (unsigned short)((v.u + 0x7FFFu + ((v.u >> 16) & 1u)) >> 16);
}

__device__ __forceinline__ float sigmoidf_(float v) {
    return 1.f / (1.f + __expf(-v));
}

__device__ __forceinline__ short8 ld8(const unsigned short* p) {
    return *(const short8*)p;
}

__device__ __forceinline__ floatx4 mfma16(short8 a, short8 b, floatx4 c) {
    return __builtin_amdgcn_mfma_f32_16x16x32_bf16(a, b, c, 0, 0, 0);
}

__device__ __forceinline__ void gload_lds16(const void* g, void* lds) {
    __builtin_amdgcn_global_load_lds(
        (const __attribute__((address_space(1))) void*)g,
        (__attribute__((address_space(3))) void*)lds, 16, 0, 0);
}

// ===========================================================================
// BMxBN MFMA GEMM body, 256 threads — double-buffered K-pipeline (r11).
// ===========================================================================
template<int BM, int BN>
__device__ __forceinline__ void mgemm_body(
    int tid, unsigned short* smA, unsigned short* smB,
    const unsigned short* __restrict__ A, int lda, int arow0,
    const unsigned short* __restrict__ W, int ldw, int wrow0,
    const float* __restrict__ bias,
    float* __restrict__ Cf, int ldcf,
    unsigned short* __restrict__ Cb, int ldcb,
    int K, int relu)
{
    constexpr int MF = BM / 32;
    constexpr int NF = BN / 32;
    const int w  = tid >> 6, l = tid & 63;
    const int wr = w >> 1, wc = w & 1;
    const int lg = l >> 4, r16 = l & 15;

    auto stage = [&](int k0, int buf) {
#pragma unroll
        for (int i = 0; i < BM / 64; ++i) {
            const int ci = tid + i * 256;
            const int row = ci >> 2, pc = ci & 3;
            const int lc = pc ^ ((row >> 1) & 3);
            gload_lds16(A + (size_t)(arow0 + row) * lda + k0 + lc * 8,
                        (char*)smA + buf * (BM * 64) + w * 1024 + i * 4096);
        }
#pragma unroll
        for (int i = 0; i < BN / 64; ++i) {
            const int ci = tid + i * 256;
            const int row = ci >> 2, pc = ci & 3;
            const int lc = pc ^ ((row >> 1) & 3);
            gload_lds16(W + (size_t)(wrow0 + row) * ldw + k0 + lc * 8,
                        (char*)smB + buf * (BN * 64) + w * 1024 + i * 4096);
        }
    };

    floatx4 acc[MF][NF];
#pragma unroll
    for (int m = 0; m < MF; ++m)
#pragma unroll
        for (int n = 0; n < NF; ++n) acc[m][n] = floatx4{0.f, 0.f, 0.f, 0.f};

    const int nk = K >> 5;
    stage(0, 0);
    for (int ck = 0; ck < nk; ++ck) {
        __syncthreads();
        if (ck + 1 < nk) stage((ck + 1) << 5, (ck + 1) & 1);
        const unsigned short* bA = smA + (ck & 1) * BM * 32;
        const unsigned short* bB = smB + (ck & 1) * BN * 32;

        short8 af[MF], bfr[NF];
#pragma unroll
        for (int m = 0; m < MF; ++m) {
            const int row = wr * (BM / 2) + m * 16 + r16;
            const int pc = lg ^ ((row >> 1) & 3);
            af[m] = *(const short8*)&bA[row * 32 + pc * 8];
        }
#pragma unroll
        for (int n = 0; n < NF; ++n) {
            const int row = wc * (BN / 2) + n * 16 + r16;
            const int pc = lg ^ ((row >> 1) & 3);
            bfr[n] = *(const short8*)&bB[row * 32 + pc * 8];
        }
#pragma unroll
        for (int m = 0; m < MF; ++m)
#pragma unroll
            for (int n = 0; n < NF; ++n)
                acc[m][n] = mfma16(af[m], bfr[n], acc[m][n]);
    }

#pragma unroll
    for (int m = 0; m < MF; ++m) {
#pragma unroll
        for (int n = 0; n < NF; ++n) {
#pragma unroll
            for (int j = 0; j < 4; ++j) {
                const int r = arow0 + wr * (BM / 2) + m * 16 + lg * 4 + j;
                const int c = wrow0 + wc * (BN / 2) + n * 16 + r16;
                float v = acc[m][n][j];
                if (bias) v += bias[c];
                if (relu && v < 0.f) v = 0.f;
                if (Cf) Cf[(size_t)r * ldcf + c] = v;
                if (Cb) Cb[(size_t)r * ldcb + c] = f2bf(v);
            }
        }
    }
}

template<int BM, int BN>
__global__ __launch_bounds__(256, 1) void k_mgemm(
    const unsigned short* __restrict__ A, int lda,
    const unsigned short* __restrict__ W, int ldw,
    const float* __restrict__ bias,
    float* __restrict__ Cf, int ldcf,
    unsigned short* __restrict__ Cb, int ldcb,
    int K, int relu)
{
    __shared__ __align__(16) unsigned short smA[2 * BM * 32];
    __shared__ __align__(16) unsigned short smB[2 * BN * 32];
    mgemm_body<BM, BN>(threadIdx.x, smA, smB, A, lda, blockIdx.y * BM,
                       W, ldw, blockIdx.x * BN, bias,
                       Cf, ldcf, Cb, ldcb, K, relu);
}

// ===========================================================================
// fused fp32 -> bf16 conversion (18 segments, one launch)
// ===========================================================================
struct CvtArgs {
    const float* src[18];
    unsigned short* dst[18];
    int n[18];
};

__global__ __launch_bounds__(256) void k_cvt_all(CvtArgs a)
{
    const int seg = blockIdx.y;
    const float* s = a.src[seg];
    unsigned short* d = a.dst[seg];
    const int c4 = a.n[seg] >> 2;
    for (int i = blockIdx.x * 256 + threadIdx.x; i < c4; i += gridDim.x * 256) {
        float4 v = ((const float4*)s)[i];
        ushort4 o;
        o.x = f2bf(v.x); o.y = f2bf(v.y); o.z = f2bf(v.z); o.w = f2bf(v.w);
        ((ushort4*)d)[i] = o;
    }
}

// ===========================================================================
// h_x = hxf + hxb ; h_y = hef + heb ; hcat = [h_x,h_y] bf16 ; cz[:, :H] = h_x
// ===========================================================================
__global__ __launch_bounds__(256) void k_sum_concat(
    const float* __restrict__ Hs,
    unsigned short* __restrict__ hcatb, unsigned short* __restrict__ czb)
{
    const int idx = blockIdx.x * 256 + threadIdx.x;  // B*H
    const int b = idx / H, i = idx % H;
    const float hx = Hs[idx] + Hs[(size_t)B * H + idx];
    const float hy = Hs[2 * (size_t)B * H + idx] + Hs[3 * (size_t)B * H + idx];
    const unsigned short hxb = f2bf(hx);
    hcatb[(size_t)b * (2 * H) + i] = hxb;
    hcatb[(size_t)b * (2 * H) + H + i] = f2bf(hy);
    czb[(size_t)b * (2 * H) + i] = hxb;
}

// ===========================================================================
// Fused encoder step (r13-proven): ONE launch per time step, double-buffered,
// __launch_bounds__(512, 2).
// ===========================================================================
struct EncP {
    const unsigned short *xb, *yb;
    unsigned short *Hsb0, *Hsb1;
    float* Hs;
    const unsigned short *wih[4], *whh[4];
    const float *bih[4], *bhh[4];
    int t, job0;
};

__global__ __launch_bounds__(512, 2) void k_enc_step(EncP p)
{
    __shared__ __align__(16) char smA[2 * 8192];    // 2 x 128x32 bf16
    __shared__ __align__(16) char smB[2 * 12288];   // 2 x 192x32 bf16
    const int job = p.job0 + blockIdx.z;
    const int h0 = blockIdx.x * 64;
    const int row0 = blockIdx.y * 128;
    const int tid = threadIdx.x;
    const int w = tid >> 6, l = tid & 63;
    const int lg = l >> 4, r16 = l & 15;
    const int wrh = w >> 2, wcg = w & 3;
    const int T = (job < 2) ? TX : TY;
    const int tt = (job & 1) ? (T - 1 - p.t) : p.t;
    const unsigned short* xsrc = (job < 2) ? p.xb : p.yb;
    const unsigned short* wihg = p.wih[job];
    const unsigned short* whhg = p.whh[job];
    const unsigned short* hin =
        ((p.t & 1) ? p.Hsb1 : p.Hsb0) + (size_t)job * B * H;
    unsigned short* hout =
        ((p.t & 1) ? p.Hsb0 : p.Hsb1) + (size_t)job * B * H;

    const int sAr = tid >> 2;
    const int sAl = (tid & 3) ^ ((sAr >> 1) & 3);
    const int f0 = sAr >> 4;
    const int W0 = (f0 % 3) * H + h0 + (f0 / 3) * 16 + (sAr & 15);
    const int sB1r = 128 + (tid >> 2);             // tid<256 only
    const int sB1l = (tid & 3) ^ ((sB1r >> 1) & 3);
    const int f1 = sB1r >> 4;
    const int W1 = (f1 % 3) * H + h0 + (f1 / 3) * 16 + (sB1r & 15);

    auto stage = [&](int ck, int buf) {
        char* dA  = smA + buf * 8192 + tid * 16;
        char* dB0 = smB + buf * 12288 + tid * 16;
        char* dB1 = smB + buf * 12288 + 8192 + tid * 16;
        if (ck < 16) {
            gload_lds16(hin + (size_t)(row0 + sAr) * H + ck * 32 + sAl * 8, dA);
            gload_lds16(whhg + (size_t)W0 * H + ck * 32 + sAl * 8, dB0);
            if (tid < 256)
                gload_lds16(whhg + (size_t)W1 * H + ck * 32 + sB1l * 8, dB1);
        } else {
            const int kk = (ck - 16) * 32;
            gload_lds16(xsrc + ((size_t)(row0 + sAr) * T + tt) * NX + kk + sAl * 8, dA);
            gload_lds16(wihg + (size_t)W0 * NX + kk + sAl * 8, dB0);
            if (tid < 256)
                gload_lds16(wihg + (size_t)W1 * NX + kk + sB1l * 8, dB1);
        }
    };

    floatx4 am[4][3], axn[4];
#pragma unroll
    for (int m = 0; m < 4; ++m) {
        axn[m] = floatx4{0.f, 0.f, 0.f, 0.f};
#pragma unroll
        for (int g = 0; g < 3; ++g) am[m][g] = floatx4{0.f, 0.f, 0.f, 0.f};
    }

    stage(0, 0);
    for (int ck = 0; ck < 18; ++ck) {
        __syncthreads();
        if (ck + 1 < 18) stage(ck + 1, (ck + 1) & 1);
        const char* bA = smA + (ck & 1) * 8192;
        const char* bB = smB + (ck & 1) * 12288;

        short8 af[4], bf[3];
#pragma unroll
        for (int m = 0; m < 4; ++m) {
            const int row = wrh * 64 + m * 16 + r16;
            af[m] = *(const short8*)(bA + row * 64 + ((lg ^ ((row >> 1) & 3)) << 4));
        }
#pragma unroll
        for (int g = 0; g < 3; ++g) {
            const int rb = wcg * 48 + g * 16 + r16;
            bf[g] = *(const short8*)(bB + rb * 64 + ((lg ^ ((rb >> 1) & 3)) << 4));
        }
        if (ck < 16) {
#pragma unroll
            for (int m = 0; m < 4; ++m) {
                am[m][0] = mfma16(af[m], bf[0], am[m][0]);
                am[m][1] = mfma16(af[m], bf[1], am[m][1]);
                am[m][2] = mfma16(af[m], bf[2], am[m][2]);
            }
        } else {
#pragma unroll
            for (int m = 0; m < 4; ++m) {
                am[m][0] = mfma16(af[m], bf[0], am[m][0]);
                am[m][1] = mfma16(af[m], bf[1], am[m][1]);
                axn[m]   = mfma16(af[m], bf[2], axn[m]);
            }
        }
    }

    // ---- gate epilogue ----
    const int u = h0 + wcg * 16 + r16;
    const float bi0 = p.bih[job][u]        + p.bhh[job][u];
    const float bi1 = p.bih[job][H + u]    + p.bhh[job][H + u];
    const float bi2 = p.bih[job][2 * H + u];
    const float bh2 = p.bhh[job][2 * H + u];
    float* HsJ = p.Hs + (size_t)job * B * H;
#pragma unroll
    for (int m = 0; m < 4; ++m) {
#pragma unroll
        for (int j = 0; j < 4; ++j) {
            const int br = row0 + wrh * 64 + m * 16 + lg * 4 + j;
            const float rr = sigmoidf_(am[m][0][j] + bi0);
            const float zz = sigmoidf_(am[m][1][j] + bi1);
            const float nn = tanhf(axn[m][j] + bi2 + rr * (am[m][2][j] + bh2));
            const float hold = HsJ[(size_t)br * H + u];
            const float hv = (1.f - zz) * nn + zz * hold;
            HsJ[(size_t)br * H + u] = hv;
            hout[(size_t)br * H + u] = f2bf(hv);
        }
    }
}

// ===========================================================================
// Decoder step kernel (STAGED, r15): out-GEMM (K=512, 16-chunk dbuf pipeline)
// + xgd (K=64, pre-staged gate tile) + gates. Grid (8 hid-slices, 2 batch
// halves), 512 threads. dWih gate-tile staging ISSUED AT ENTRY so its latency
// hides under phase A. All weight traffic via global_load_lds.
// mode: 0 = t==0 (y from x[:,-1]), 1 = normal, 2 = out-only (final y).
// ===========================================================================
struct DecP {
    const unsigned short* xb;
    unsigned short* hdb;
    float* hd;
    const float* hga;
    const float* constb;
    const unsigned short* dWihb;
    const float* dbhh;
    const unsigned short* doWb; const float* dob;
    const unsigned short* hm2b;
    float* outp;
    int mode, tprev;
};

__global__ __launch_bounds__(512, 2) void k_dec_step(DecP p)
{
    __shared__ __align__(16) char sA[2 * 8192];          // hm2 tiles (dbuf)
    __shared__ __align__(16) char sW[2 * 4096];          // doW tiles (dbuf)
    __shared__ __align__(16) char sX[2 * 12288];         // dWih gate tiles (2 k-chunks)
    __shared__ __align__(16) unsigned short ytile[128 * 64];  // swizzled
    const int tid = threadIdx.x;
    const int w = tid >> 6, l = tid & 63;
    const int lg = l >> 4, r16 = l & 15;
    const int row0 = blockIdx.y * 128;
    const int h0 = blockIdx.x * 64;

    // staging index math (identical convention to k_enc_step)
    const int sAr = tid >> 2;
    const int sAl = (tid & 3) ^ ((sAr >> 1) & 3);
    const int f0 = sAr >> 4;
    const int W0 = (f0 % 3) * H + h0 + (f0 / 3) * 16 + (sAr & 15);
    const int sB1r = 128 + (tid >> 2);             // tid<256 only
    const int sB1l = (tid & 3) ^ ((sB1r >> 1) & 3);
    const int f1 = sB1r >> 4;
    const int W1 = (f1 % 3) * H + h0 + (f1 / 3) * 16 + (sB1r & 15);

    // ---- issue gate-tile staging immediately (completes under phase A) ----
    if (p.mode != 2) {
#pragma unroll
        for (int kc = 0; kc < 2; ++kc) {
            gload_lds16(p.dWihb + (size_t)W0 * DIN + 2 * H + kc * 32 + sAl * 8,
                        sX + kc * 12288 + tid * 16);
            if (tid < 256)
                gload_lds16(p.dWihb + (size_t)W1 * DIN + 2 * H + kc * 32 + sB1l * 8,
                            sX + kc * 12288 + 8192 + tid * 16);
        }
    }

    if (p.mode != 0) {
        // ---- phase A: y = hm2b @ doW^T + dob (128x64, K=512), staged dbuf ----
        auto stageA = [&](int ck, int buf) {
            gload_lds16(p.hm2b + (size_t)(row0 + sAr) * M2 + ck * 32 + sAl * 8,
                        sA + buf * 8192 + tid * 16);
            if (tid < 256) {
                const int sWr = tid >> 2;
                const int sWl = (tid & 3) ^ ((sWr >> 1) & 3);
                gload_lds16(p.doWb + (size_t)sWr * M2 + ck * 32 + sWl * 8,
                            sW + buf * 4096 + tid * 16);
            }
        };
        const int wrA = w >> 1, wcA = w & 1;   // 4 x 2 waves, 32x32 tiles
        floatx4 acc[2][2];
#pragma unroll
        for (int mA = 0; mA < 2; ++mA)
#pragma unroll
            for (int nA = 0; nA < 2; ++nA) acc[mA][nA] = floatx4{0.f, 0.f, 0.f, 0.f};

        stageA(0, 0);
        for (int ck = 0; ck < 16; ++ck) {
            __syncthreads();
            if (ck + 1 < 16) stageA(ck + 1, (ck + 1) & 1);
            const char* bA = sA + (ck & 1) * 8192;
            const char* bW = sW + (ck & 1) * 4096;
            short8 av[2], bv[2];
#pragma unroll
            for (int mA = 0; mA < 2; ++mA) {
                const int row = wrA * 32 + mA * 16 + r16;
                av[mA] = *(const short8*)(bA + row * 64 + ((lg ^ ((row >> 1) & 3)) << 4));
            }
#pragma unroll
            for (int nA = 0; nA < 2; ++nA) {
                const int row = wcA * 32 + nA * 16 + r16;
                bv[nA] = *(const short8*)(bW + row * 64 + ((lg ^ ((row >> 1) & 3)) << 4));
            }
#pragma unroll
            for (int mA = 0; mA < 2; ++mA)
#pragma unroll
                for (int nA = 0; nA < 2; ++nA)
                    acc[mA][nA] = mfma16(av[mA], bv[nA], acc[mA][nA]);
        }
#pragma unroll
        for (int mA = 0; mA < 2; ++mA) {
#pragma unroll
            for (int nA = 0; nA < 2; ++nA) {
#pragma unroll
                for (int j = 0; j < 4; ++j) {
                    const int rr = wrA * 32 + mA * 16 + lg * 4 + j;
                    const int cc = wcA * 32 + nA * 16 + r16;
                    const float v = acc[mA][nA][j] + p.dob[cc];
                    if (blockIdx.x == 0)
                        p.outp[(size_t)(row0 + rr) * (HOR * NY)
                               + (size_t)p.tprev * NY + cc] = v;
                    *(unsigned short*)((char*)ytile + rr * 128
                        + ((cc * 2) ^ ((rr & 7) << 4))) = f2bf(v);
                }
            }
        }
    } else {
        for (int i = tid; i < 128 * 64; i += 512) {
            const int rr = i >> 6, cc = i & 63;
            const unsigned short v =
                p.xb[((size_t)(row0 + rr) * TX + TX - 1) * NX + cc];
            *(unsigned short*)((char*)ytile + rr * 128
                + ((cc * 2) ^ ((rr & 7) << 4))) = v;
        }
    }
    if (p.mode == 2) return;
    __syncthreads();   // ytile ready; sX staging drained

    // ---- phase B: xgd (128 x 192 gate-cols, K=64 from sX) + gates ----
    const int wrh = w >> 2, wcg = w & 3;
    floatx4 ag[4][3];
#pragma unroll
    for (int m = 0; m < 4; ++m)
#pragma unroll
        for (int g = 0; g < 3; ++g) ag[m][g] = floatx4{0.f, 0.f, 0.f, 0.f};
#pragma unroll
    for (int ks = 0; ks < 2; ++ks) {
        short8 ya[4], bf[3];
#pragma unroll
        for (int m = 0; m < 4; ++m) {
            const int row = wrh * 64 + m * 16 + r16;
            const int k0 = ks * 32 + lg * 8;
            ya[m] = *(const short8*)((char*)ytile + row * 128
                          + ((k0 * 2) ^ ((row & 7) << 4)));
        }
#pragma unroll
        for (int g = 0; g < 3; ++g) {
            const int rb = wcg * 48 + g * 16 + r16;
            bf[g] = *(const short8*)(sX + ks * 12288 + rb * 64
                          + ((lg ^ ((rb >> 1) & 3)) << 4));
        }
#pragma unroll
        for (int m = 0; m < 4; ++m)
#pragma unroll
            for (int g = 0; g < 3; ++g)
                ag[m][g] = mfma16(ya[m], bf[g], ag[m][g]);
    }

    const int u = h0 + wcg * 16 + r16;
    const float db0 = p.dbhh[u], db1 = p.dbhh[H + u], db2 = p.dbhh[2 * H + u];
#pragma unroll
    for (int m = 0; m < 4; ++m) {
#pragma unroll
        for (int j = 0; j < 4; ++j) {
            const int b = row0 + wrh * 64 + m * 16 + lg * 4 + j;
            const size_t g3 = (size_t)b * G3;
            const float xr = ag[m][0][j] + p.constb[g3 + u];
            const float xz = ag[m][1][j] + p.constb[g3 + H + u];
            const float xn = ag[m][2][j] + p.constb[g3 + 2 * H + u];
            const float hr = p.hga[g3 + u] + db0;
            const float hz = p.hga[g3 + H + u] + db1;
            const float hn = p.hga[g3 + 2 * H + u] + db2;
            const float rr = sigmoidf_(xr + hr);
            const float zz = sigmoidf_(xz + hz);
            const float nn = tanhf(xn + rr * hn);
            const float hold = p.hd[(size_t)b * H + u];
            const float hv = (1.f - zz) * nn + zz * hold;
            p.hd[(size_t)b * H + u] = hv;
            p.hdb[(size_t)b * H + u] = f2bf(hv);
        }
    }
}

// ===========================================================================
// kB: hga_next (48 roles) || MLP1 (32 roles) — 80 blocks x 256 threads.
// ===========================================================================
__global__ __launch_bounds__(256, 1) void k_dec_bk(
    const unsigned short* __restrict__ hdb,
    const unsigned short* __restrict__ dWhhb,
    const unsigned short* __restrict__ dmW1b, const float* __restrict__ dmb1,
    float* __restrict__ hga, unsigned short* __restrict__ hm1b)
{
    __shared__ __align__(16) unsigned short smA[2 * 64 * 32];
    __shared__ __align__(16) unsigned short smB[2 * 128 * 32];
    const int bid = blockIdx.x;
    if (bid < 48) {
        const int arow0 = (bid & 3) * 64, wrow0 = (bid >> 2) * 128;
        mgemm_body<64, 128>(threadIdx.x, smA, smB, hdb, H, arow0,
                            dWhhb, H, wrow0, nullptr,
                            hga, G3, nullptr, 0, H, 0);
    } else {
        const int b2 = bid - 48;
        const int arow0 = (b2 & 3) * 64, wrow0 = (b2 >> 2) * 128;
        mgemm_body<64, 128>(threadIdx.x, smA, smB, hdb, H, arow0,
                            dmW1b, H, wrow0, dmb1,
                            nullptr, 0, hm1b, M1, H, 1);
    }
}

// ===========================================================================
extern "C" void kernel_launch(void* const* d_in, const int* in_sizes, int n_in,
                              void* d_out, int out_size, void* d_ws, size_t ws_size,
                              hipStream_t stream)
{
    const float* x      = (const float*)d_in[0];
    const float* y      = (const float*)d_in[1];
    const float* xf_bih = (const float*)d_in[4];
    const float* xf_bhh = (const float*)d_in[5];
    const float* xb_bih = (const float*)d_in[8];
    const float* xb_bhh = (const float*)d_in[9];
    const float* ef_bih = (const float*)d_in[12];
    const float* ef_bhh = (const float*)d_in[13];
    const float* eb_bih = (const float*)d_in[16];
    const float* eb_bhh = (const float*)d_in[17];
    const float* em_b1  = (const float*)d_in[19];
    const float* em_b2  = (const float*)d_in[21];
    const float* eo_b   = (const float*)d_in[23];
    const float* d_bih  = (const float*)d_in[26];
    const float* d_bhh  = (const float*)d_in[27];
    const float* dm_b1  = (const float*)d_in[29];
    const float* dm_b2  = (const float*)d_in[31];
    const float* do_b   = (const float*)d_in[33];
    float* out = (float*)d_out;

    // ---- workspace carve-up ----
    float* fp = (float*)d_ws;
    float* Hs     = fp; fp += 4 * (size_t)B * H;
    float* hd     = fp; fp += (size_t)B * H;
    float* hga    = fp; fp += (size_t)B * G3;
    float* constb = fp; fp += (size_t)B * G3;

    unsigned short* up = (unsigned short*)fp;
    unsigned short* xb16  = up; up += (size_t)B * TX * NX;
    unsigned short* yb16  = up; up += (size_t)B * TY * NY;
    unsigned short* Hsb0  = up; up += 4 * (size_t)B * H;
    unsigned short* Hsb1  = up; up += 4 * (size_t)B * H;
    unsigned short* hdb   = up; up += (size_t)B * H;
    unsigned short* hcatb = up; up += (size_t)B * 2 * H;
    unsigned short* czb   = up; up += (size_t)B * 2 * H;
    unsigned short* h1b   = up; up += (size_t)B * M1;
    unsigned short* h2b   = up; up += (size_t)B * M2;
    unsigned short* hm1b  = up; up += (size_t)B * M1;
    unsigned short* hm2b  = up; up += (size_t)B * M2;

    const int    widx[16] = {2, 3, 6, 7, 10, 11, 14, 15, 18, 20, 22, 24, 25, 28, 30, 32};
    const size_t wsz[16]  = {
        (size_t)G3 * NX, (size_t)G3 * H, (size_t)G3 * NX, (size_t)G3 * H,
        (size_t)G3 * NX, (size_t)G3 * H, (size_t)G3 * NX, (size_t)G3 * H,
        (size_t)M1 * 2 * H, (size_t)M2 * M1, (size_t)H * M2,
        (size_t)G3 * DIN, (size_t)G3 * H, (size_t)M1 * H, (size_t)M2 * M1,
        (size_t)NY * M2};
    unsigned short* wb[16];
    for (int i = 0; i < 16; ++i) { wb[i] = up; up += wsz[i]; }

    // ---- conversions + state init ----
    CvtArgs ca;
    for (int i = 0; i < 16; ++i) {
        ca.src[i] = (const float*)d_in[widx[i]];
        ca.dst[i] = wb[i];
        ca.n[i]   = (int)wsz[i];
    }
    ca.src[16] = x; ca.dst[16] = xb16; ca.n[16] = B * TX * NX;
    ca.src[17] = y; ca.dst[17] = yb16; ca.n[17] = B * TY * NY;
    k_cvt_all<<<dim3(64, 18), 256, 0, stream>>>(ca);

    hipMemsetAsync(Hs,   0, sizeof(float) * 4 * (size_t)B * H, stream);
    hipMemsetAsync(Hsb0, 0, sizeof(unsigned short) * 4 * (size_t)B * H, stream);
    hipMemsetAsync(hd,   0, sizeof(float) * (size_t)B * H, stream);
    hipMemsetAsync(hga,  0, sizeof(float) * (size_t)B * G3, stream);

    // ---- encoder: 1 fused launch per step ----
    EncP ep;
    ep.xb = xb16; ep.yb = yb16; ep.Hsb0 = Hsb0; ep.Hsb1 = Hsb1; ep.Hs = Hs;
    ep.wih[0] = wb[0]; ep.whh[0] = wb[1];
    ep.wih[1] = wb[2]; ep.whh[1] = wb[3];
    ep.wih[2] = wb[4]; ep.whh[2] = wb[5];
    ep.wih[3] = wb[6]; ep.whh[3] = wb[7];
    ep.bih[0] = xf_bih; ep.bhh[0] = xf_bhh;
    ep.bih[1] = xb_bih; ep.bhh[1] = xb_bhh;
    ep.bih[2] = ef_bih; ep.bhh[2] = ef_bhh;
    ep.bih[3] = eb_bih; ep.bhh[3] = eb_bhh;
    for (int t = 0; t < TY; ++t) {
        ep.t = t;
        ep.job0 = (t < TX) ? 0 : 2;
        const int nj = (t < TX) ? 4 : 2;
        k_enc_step<<<dim3(8, 2, nj), 512, 0, stream>>>(ep);
    }

    // ---- bottleneck MLP ----
    k_sum_concat<<<B * H / 256, 256, 0, stream>>>(Hs, hcatb, czb);
    k_mgemm<128, 128><<<dim3(M1 / 128, B / 128), 256, 0, stream>>>(
        hcatb, 2 * H, wb[8], 2 * H, em_b1, nullptr, 0, h1b, M1, 2 * H, 1);
    k_mgemm<128, 128><<<dim3(M2 / 128, B / 128), 256, 0, stream>>>(
        h1b, M1, wb[9], M1, em_b2, nullptr, 0, h2b, M2, M1, 1);
    k_mgemm<128, 128><<<dim3(H / 128, B / 128), 256, 0, stream>>>(
        h2b, M2, wb[10], M2, eo_b, nullptr, 0, czb + H, 2 * H, M2, 0);
    k_mgemm<128, 128><<<dim3(G3 / 128, B / 128), 256, 0, stream>>>(
        czb, 2 * H, wb[11], DIN, d_bih, constb, G3, nullptr, 0, 2 * H, 0);

    // ---- decoder: 3 launches per step ----
    DecP dp;
    dp.xb = xb16; dp.hdb = hdb; dp.hd = hd; dp.hga = hga; dp.constb = constb;
    dp.dWihb = wb[11]; dp.dbhh = d_bhh;
    dp.doWb = wb[15]; dp.dob = do_b;
    dp.hm2b = hm2b; dp.outp = out;
    for (int t = 0; t < HOR; ++t) {
        dp.mode = (t == 0) ? 0 : 1;
        dp.tprev = t - 1;
        k_dec_step<<<dim3(8, 2), 512, 0, stream>>>(dp);
        k_dec_bk<<<80, 256, 0, stream>>>(hdb, wb[12], wb[13], dm_b1, hga, hm1b);
        k_mgemm<64, 64><<<dim3(M2 / 64, B / 64), 256, 0, stream>>>(
            hm1b, M1, wb[14], M1, dm_b2, nullptr, 0, hm2b, M2, M1, 1);
    }
    dp.mode = 2;
    dp.tprev = HOR - 1;
    k_dec_step<<<dim3(1, 2), 512, 0, stream>>>(dp);
}

// Round 16
// 4588.599 us; speedup vs baseline: 1.1777x; 1.0334x over previous
//
#include <hip/hip_runtime.h>
#include <math.h>

#define B   256
#define TX  50
#define TY  100
#define NX  64
#define NY  64
#define H   512
#define HOR 60
#define M1  1024
#define M2  512
#define G3  (3*H)        // 1536
#define DIN (2*H + NY)   // 1088

typedef __attribute__((ext_vector_type(8))) short short8;
typedef __attribute__((ext_vector_type(4))) float floatx4;

__device__ __forceinline__ unsigned short f2bf(float f) {
    union { float f; unsigned u; } v; v.f = f;
    return (unsigned short)((v.u + 0x7FFFu + ((v.u >> 16) & 1u)) >> 16);
}

__device__ __forceinline__ float sigmoidf_(float v) {
    return 1.f / (1.f + __expf(-v));
}

__device__ __forceinline__ short8 ld8(const unsigned short* p) {
    return *(const short8*)p;
}

__device__ __forceinline__ floatx4 mfma16(short8 a, short8 b, floatx4 c) {
    return __builtin_amdgcn_mfma_f32_16x16x32_bf16(a, b, c, 0, 0, 0);
}

__device__ __forceinline__ void gload_lds16(const void* g, void* lds) {
    __builtin_amdgcn_global_load_lds(
        (const __attribute__((address_space(1))) void*)g,
        (__attribute__((address_space(3))) void*)lds, 16, 0, 0);
}

// BK=64 row layout: [row][8 chunks of 16B], row stride 128B.
// Swizzle (2-way bank aliasing): logical chunk l at physical position p:
//   p = ((l>>2)^(row&1))<<2 | ((l&3)^((row>>1)&3))   (involution per row)
__device__ __forceinline__ int swz_src(int pc8, int row) {
    return (((pc8 >> 2) ^ (row & 1)) << 2) | ((pc8 & 3) ^ ((row >> 1) & 3));
}
__device__ __forceinline__ int swz_rd(int h, int lg, int row) {
    return (((h ^ (row & 1)) & 1) << 2) | ((lg ^ ((row >> 1) & 3)) & 3);
}

// ===========================================================================
// BMxBN MFMA GEMM body, 256 threads — BK=64 double-buffered K-pipeline.
// Caller provides smA[2*BM*64], smB[2*BN*64] shorts.
// ===========================================================================
template<int BM, int BN>
__device__ __forceinline__ void mgemm_body(
    int tid, unsigned short* smA, unsigned short* smB,
    const unsigned short* __restrict__ A, int lda, int arow0,
    const unsigned short* __restrict__ W, int ldw, int wrow0,
    const float* __restrict__ bias,
    float* __restrict__ Cf, int ldcf,
    unsigned short* __restrict__ Cb, int ldcb,
    int K, int relu)
{
    constexpr int MF = BM / 32;
    constexpr int NF = BN / 32;
    const int w  = tid >> 6, l = tid & 63;
    const int wr = w >> 1, wc = w & 1;
    const int lg = l >> 4, r16 = l & 15;

    auto stage = [&](int k0, int buf) {
#pragma unroll
        for (int i = 0; i < BM / 32; ++i) {
            const int ci = tid + i * 256;
            const int row = ci >> 3, pc = ci & 7;
            const int lc = swz_src(pc, row);
            gload_lds16(A + (size_t)(arow0 + row) * lda + k0 + lc * 8,
                        (char*)smA + buf * (BM * 128) + ci * 16);
        }
#pragma unroll
        for (int i = 0; i < BN / 32; ++i) {
            const int ci = tid + i * 256;
            const int row = ci >> 3, pc = ci & 7;
            const int lc = swz_src(pc, row);
            gload_lds16(W + (size_t)(wrow0 + row) * ldw + k0 + lc * 8,
                        (char*)smB + buf * (BN * 128) + ci * 16);
        }
    };

    floatx4 acc[MF][NF];
#pragma unroll
    for (int m = 0; m < MF; ++m)
#pragma unroll
        for (int n = 0; n < NF; ++n) acc[m][n] = floatx4{0.f, 0.f, 0.f, 0.f};

    const int nk = K >> 6;
    stage(0, 0);
    for (int s = 0; s < nk; ++s) {
        __syncthreads();
        if (s + 1 < nk) stage((s + 1) << 6, (s + 1) & 1);
        const char* bA = (char*)smA + (s & 1) * (BM * 128);
        const char* bB = (char*)smB + (s & 1) * (BN * 128);
#pragma unroll
        for (int h = 0; h < 2; ++h) {
            short8 af[MF], bfr[NF];
#pragma unroll
            for (int m = 0; m < MF; ++m) {
                const int row = wr * (BM / 2) + m * 16 + r16;
                af[m] = *(const short8*)(bA + row * 128 + swz_rd(h, lg, row) * 16);
            }
#pragma unroll
            for (int n = 0; n < NF; ++n) {
                const int row = wc * (BN / 2) + n * 16 + r16;
                bfr[n] = *(const short8*)(bB + row * 128 + swz_rd(h, lg, row) * 16);
            }
#pragma unroll
            for (int m = 0; m < MF; ++m)
#pragma unroll
                for (int n = 0; n < NF; ++n)
                    acc[m][n] = mfma16(af[m], bfr[n], acc[m][n]);
        }
    }

#pragma unroll
    for (int m = 0; m < MF; ++m) {
#pragma unroll
        for (int n = 0; n < NF; ++n) {
#pragma unroll
            for (int j = 0; j < 4; ++j) {
                const int r = arow0 + wr * (BM / 2) + m * 16 + lg * 4 + j;
                const int c = wrow0 + wc * (BN / 2) + n * 16 + r16;
                float v = acc[m][n][j];
                if (bias) v += bias[c];
                if (relu && v < 0.f) v = 0.f;
                if (Cf) Cf[(size_t)r * ldcf + c] = v;
                if (Cb) Cb[(size_t)r * ldcb + c] = f2bf(v);
            }
        }
    }
}

template<int BM, int BN>
__global__ __launch_bounds__(256, 1) void k_mgemm(
    const unsigned short* __restrict__ A, int lda,
    const unsigned short* __restrict__ W, int ldw,
    const float* __restrict__ bias,
    float* __restrict__ Cf, int ldcf,
    unsigned short* __restrict__ Cb, int ldcb,
    int K, int relu)
{
    __shared__ __align__(16) unsigned short smA[2 * BM * 64];
    __shared__ __align__(16) unsigned short smB[2 * BN * 64];
    mgemm_body<BM, BN>(threadIdx.x, smA, smB, A, lda, blockIdx.y * BM,
                       W, ldw, blockIdx.x * BN, bias,
                       Cf, ldcf, Cb, ldcb, K, relu);
}

// ===========================================================================
// fused fp32 -> bf16 conversion (18 segments, one launch)
// ===========================================================================
struct CvtArgs {
    const float* src[18];
    unsigned short* dst[18];
    int n[18];
};

__global__ __launch_bounds__(256) void k_cvt_all(CvtArgs a)
{
    const int seg = blockIdx.y;
    const float* s = a.src[seg];
    unsigned short* d = a.dst[seg];
    const int c4 = a.n[seg] >> 2;
    for (int i = blockIdx.x * 256 + threadIdx.x; i < c4; i += gridDim.x * 256) {
        float4 v = ((const float4*)s)[i];
        ushort4 o;
        o.x = f2bf(v.x); o.y = f2bf(v.y); o.z = f2bf(v.z); o.w = f2bf(v.w);
        ((ushort4*)d)[i] = o;
    }
}

// ===========================================================================
// h_x = hxf + hxb ; h_y = hef + heb ; hcat = [h_x,h_y] bf16 ; cz[:, :H] = h_x
// ===========================================================================
__global__ __launch_bounds__(256) void k_sum_concat(
    const float* __restrict__ Hs,
    unsigned short* __restrict__ hcatb, unsigned short* __restrict__ czb)
{
    const int idx = blockIdx.x * 256 + threadIdx.x;  // B*H
    const int b = idx / H, i = idx % H;
    const float hx = Hs[idx] + Hs[(size_t)B * H + idx];
    const float hy = Hs[2 * (size_t)B * H + idx] + Hs[3 * (size_t)B * H + idx];
    const unsigned short hxb = f2bf(hx);
    hcatb[(size_t)b * (2 * H) + i] = hxb;
    hcatb[(size_t)b * (2 * H) + H + i] = f2bf(hy);
    czb[(size_t)b * (2 * H) + i] = hxb;
}

// ===========================================================================
// Fused encoder step — BK=64 pipeline: 9 stages (8 h-chunks + 1 x-chunk).
// Grid (8 hid-slices, 2 batch-halves, njobs); 512 threads = 8 waves (2x4).
// LDS: A 2x16KB + B 2x24KB = 80KB.
// ===========================================================================
struct EncP {
    const unsigned short *xb, *yb;
    unsigned short *Hsb0, *Hsb1;
    float* Hs;
    const unsigned short *wih[4], *whh[4];
    const float *bih[4], *bhh[4];
    int t, job0;
};

__global__ __launch_bounds__(512, 2) void k_enc_step(EncP p)
{
    __shared__ __align__(16) char smA[2 * 16384];   // 2 x 128x64 bf16
    __shared__ __align__(16) char smB[2 * 24576];   // 2 x 192x64 bf16
    const int job = p.job0 + blockIdx.z;
    const int h0 = blockIdx.x * 64;
    const int row0 = blockIdx.y * 128;
    const int tid = threadIdx.x;
    const int w = tid >> 6, l = tid & 63;
    const int lg = l >> 4, r16 = l & 15;
    const int wrh = w >> 2, wcg = w & 3;
    const int T = (job < 2) ? TX : TY;
    const int tt = (job & 1) ? (T - 1 - p.t) : p.t;
    const unsigned short* xsrc = (job < 2) ? p.xb : p.yb;
    const unsigned short* wihg = p.wih[job];
    const unsigned short* whhg = p.whh[job];
    const unsigned short* hin =
        ((p.t & 1) ? p.Hsb1 : p.Hsb0) + (size_t)job * B * H;
    unsigned short* hout =
        ((p.t & 1) ? p.Hsb0 : p.Hsb1) + (size_t)job * B * H;

    // staging index precompute: A 1024 chunks (2/thr), B 1536 chunks (3/thr)
    int aRow[2], aLc[2];
#pragma unroll
    for (int i = 0; i < 2; ++i) {
        const int ci = tid + i * 512;
        aRow[i] = ci >> 3;
        aLc[i] = swz_src(ci & 7, aRow[i]);
    }
    int bWr[3], bLc[3];
#pragma unroll
    for (int i = 0; i < 3; ++i) {
        const int ci = tid + i * 512;
        const int row = ci >> 3;
        const int f = row >> 4;
        bWr[i] = (f % 3) * H + h0 + (f / 3) * 16 + (row & 15);
        bLc[i] = swz_src(ci & 7, row);
    }

    auto stage = [&](int s, int buf) {
        char* dA = smA + buf * 16384;
        char* dB = smB + buf * 24576;
        if (s < 8) {
            const int k0 = s * 64;
#pragma unroll
            for (int i = 0; i < 2; ++i)
                gload_lds16(hin + (size_t)(row0 + aRow[i]) * H + k0 + aLc[i] * 8,
                            dA + (tid + i * 512) * 16);
#pragma unroll
            for (int i = 0; i < 3; ++i)
                gload_lds16(whhg + (size_t)bWr[i] * H + k0 + bLc[i] * 8,
                            dB + (tid + i * 512) * 16);
        } else {
#pragma unroll
            for (int i = 0; i < 2; ++i)
                gload_lds16(xsrc + ((size_t)(row0 + aRow[i]) * T + tt) * NX + aLc[i] * 8,
                            dA + (tid + i * 512) * 16);
#pragma unroll
            for (int i = 0; i < 3; ++i)
                gload_lds16(wihg + (size_t)bWr[i] * NX + bLc[i] * 8,
                            dB + (tid + i * 512) * 16);
        }
    };

    floatx4 am[4][3], axn[4];
#pragma unroll
    for (int m = 0; m < 4; ++m) {
        axn[m] = floatx4{0.f, 0.f, 0.f, 0.f};
#pragma unroll
        for (int g = 0; g < 3; ++g) am[m][g] = floatx4{0.f, 0.f, 0.f, 0.f};
    }

    stage(0, 0);
    for (int s = 0; s < 9; ++s) {
        __syncthreads();
        if (s + 1 < 9) stage(s + 1, (s + 1) & 1);
        const char* bA = smA + (s & 1) * 16384;
        const char* bB = smB + (s & 1) * 24576;
        const bool isx = (s == 8);
#pragma unroll
        for (int h = 0; h < 2; ++h) {
            short8 af[4], bf[3];
#pragma unroll
            for (int m = 0; m < 4; ++m) {
                const int row = wrh * 64 + m * 16 + r16;
                af[m] = *(const short8*)(bA + row * 128 + swz_rd(h, lg, row) * 16);
            }
#pragma unroll
            for (int g = 0; g < 3; ++g) {
                const int rb = wcg * 48 + g * 16 + r16;
                bf[g] = *(const short8*)(bB + rb * 128 + swz_rd(h, lg, rb) * 16);
            }
            if (!isx) {
#pragma unroll
                for (int m = 0; m < 4; ++m) {
                    am[m][0] = mfma16(af[m], bf[0], am[m][0]);
                    am[m][1] = mfma16(af[m], bf[1], am[m][1]);
                    am[m][2] = mfma16(af[m], bf[2], am[m][2]);
                }
            } else {
#pragma unroll
                for (int m = 0; m < 4; ++m) {
                    am[m][0] = mfma16(af[m], bf[0], am[m][0]);
                    am[m][1] = mfma16(af[m], bf[1], am[m][1]);
                    axn[m]   = mfma16(af[m], bf[2], axn[m]);
                }
            }
        }
    }

    // ---- gate epilogue ----
    const int u = h0 + wcg * 16 + r16;
    const float bi0 = p.bih[job][u]        + p.bhh[job][u];
    const float bi1 = p.bih[job][H + u]    + p.bhh[job][H + u];
    const float bi2 = p.bih[job][2 * H + u];
    const float bh2 = p.bhh[job][2 * H + u];
    float* HsJ = p.Hs + (size_t)job * B * H;
#pragma unroll
    for (int m = 0; m < 4; ++m) {
#pragma unroll
        for (int j = 0; j < 4; ++j) {
            const int br = row0 + wrh * 64 + m * 16 + lg * 4 + j;
            const float rr = sigmoidf_(am[m][0][j] + bi0);
            const float zz = sigmoidf_(am[m][1][j] + bi1);
            const float nn = tanhf(axn[m][j] + bi2 + rr * (am[m][2][j] + bh2));
            const float hold = HsJ[(size_t)br * H + u];
            const float hv = (1.f - zz) * nn + zz * hold;
            HsJ[(size_t)br * H + u] = hv;
            hout[(size_t)br * H + u] = f2bf(hv);
        }
    }
}

// ===========================================================================
// Decoder step kernel (STAGED, BK=64 phase A): out-GEMM (8-stage pipeline)
// + xgd (pre-staged gate tile, old 32-wide format) + gates.
// Grid (8 hid-slices, 2 batch halves), 512 threads.
// mode: 0 = t==0 (y from x[:,-1]), 1 = normal, 2 = out-only (final y).
// ===========================================================================
struct DecP {
    const unsigned short* xb;
    unsigned short* hdb;
    float* hd;
    const float* hga;
    const float* constb;
    const unsigned short* dWihb;
    const float* dbhh;
    const unsigned short* doWb; const float* dob;
    const unsigned short* hm2b;
    float* outp;
    int mode, tprev;
};

__global__ __launch_bounds__(512, 2) void k_dec_step(DecP p)
{
    __shared__ __align__(16) char sA[2 * 16384];         // hm2 tiles (dbuf, 128x64)
    __shared__ __align__(16) char sW[2 * 8192];          // doW tiles (dbuf, 64x64)
    __shared__ __align__(16) char sX[2 * 12288];         // dWih gate tiles (old fmt)
    __shared__ __align__(16) unsigned short ytile[128 * 64];  // swizzled
    const int tid = threadIdx.x;
    const int w = tid >> 6, l = tid & 63;
    const int lg = l >> 4, r16 = l & 15;
    const int row0 = blockIdx.y * 128;
    const int h0 = blockIdx.x * 64;

    // old-format staging math for sX (32-elem rows, 4-chunk swizzle)
    const int sAr = tid >> 2;
    const int sAl = (tid & 3) ^ ((sAr >> 1) & 3);
    const int f0 = sAr >> 4;
    const int W0 = (f0 % 3) * H + h0 + (f0 / 3) * 16 + (sAr & 15);
    const int sB1r = 128 + (tid >> 2);             // tid<256 only
    const int sB1l = (tid & 3) ^ ((sB1r >> 1) & 3);
    const int f1 = sB1r >> 4;
    const int W1 = (f1 % 3) * H + h0 + (f1 / 3) * 16 + (sB1r & 15);

    // ---- issue gate-tile staging immediately (completes under phase A) ----
    if (p.mode != 2) {
#pragma unroll
        for (int kc = 0; kc < 2; ++kc) {
            gload_lds16(p.dWihb + (size_t)W0 * DIN + 2 * H + kc * 32 + sAl * 8,
                        sX + kc * 12288 + tid * 16);
            if (tid < 256)
                gload_lds16(p.dWihb + (size_t)W1 * DIN + 2 * H + kc * 32 + sB1l * 8,
                            sX + kc * 12288 + 8192 + tid * 16);
        }
    }

    if (p.mode != 0) {
        // ---- phase A: y = hm2b @ doW^T + dob (128x64, K=512), BK=64 dbuf ----
        int aRow[2], aLc[2];
#pragma unroll
        for (int i = 0; i < 2; ++i) {
            const int ci = tid + i * 512;
            aRow[i] = ci >> 3;
            aLc[i] = swz_src(ci & 7, aRow[i]);
        }
        const int wRow = tid >> 3;
        const int wLc = swz_src(tid & 7, wRow);
        auto stageA = [&](int s, int buf) {
            const int k0 = s * 64;
#pragma unroll
            for (int i = 0; i < 2; ++i)
                gload_lds16(p.hm2b + (size_t)(row0 + aRow[i]) * M2 + k0 + aLc[i] * 8,
                            sA + buf * 16384 + (tid + i * 512) * 16);
            gload_lds16(p.doWb + (size_t)wRow * M2 + k0 + wLc * 8,
                        sW + buf * 8192 + tid * 16);
        };
        const int wrA = w >> 1, wcA = w & 1;   // 4 x 2 waves, 32x32 tiles
        floatx4 acc[2][2];
#pragma unroll
        for (int mA = 0; mA < 2; ++mA)
#pragma unroll
            for (int nA = 0; nA < 2; ++nA) acc[mA][nA] = floatx4{0.f, 0.f, 0.f, 0.f};

        stageA(0, 0);
        for (int s = 0; s < 8; ++s) {
            __syncthreads();
            if (s + 1 < 8) stageA(s + 1, (s + 1) & 1);
            const char* bA = sA + (s & 1) * 16384;
            const char* bW = sW + (s & 1) * 8192;
#pragma unroll
            for (int h = 0; h < 2; ++h) {
                short8 av[2], bv[2];
#pragma unroll
                for (int mA = 0; mA < 2; ++mA) {
                    const int row = wrA * 32 + mA * 16 + r16;
                    av[mA] = *(const short8*)(bA + row * 128 + swz_rd(h, lg, row) * 16);
                }
#pragma unroll
                for (int nA = 0; nA < 2; ++nA) {
                    const int row = wcA * 32 + nA * 16 + r16;
                    bv[nA] = *(const short8*)(bW + row * 128 + swz_rd(h, lg, row) * 16);
                }
#pragma unroll
                for (int mA = 0; mA < 2; ++mA)
#pragma unroll
                    for (int nA = 0; nA < 2; ++nA)
                        acc[mA][nA] = mfma16(av[mA], bv[nA], acc[mA][nA]);
            }
        }
#pragma unroll
        for (int mA = 0; mA < 2; ++mA) {
#pragma unroll
            for (int nA = 0; nA < 2; ++nA) {
#pragma unroll
                for (int j = 0; j < 4; ++j) {
                    const int rr = wrA * 32 + mA * 16 + lg * 4 + j;
                    const int cc = wcA * 32 + nA * 16 + r16;
                    const float v = acc[mA][nA][j] + p.dob[cc];
                    if (blockIdx.x == 0)
                        p.outp[(size_t)(row0 + rr) * (HOR * NY)
                               + (size_t)p.tprev * NY + cc] = v;
                    *(unsigned short*)((char*)ytile + rr * 128
                        + ((cc * 2) ^ ((rr & 7) << 4))) = f2bf(v);
                }
            }
        }
    } else {
        for (int i = tid; i < 128 * 64; i += 512) {
            const int rr = i >> 6, cc = i & 63;
            const unsigned short v =
                p.xb[((size_t)(row0 + rr) * TX + TX - 1) * NX + cc];
            *(unsigned short*)((char*)ytile + rr * 128
                + ((cc * 2) ^ ((rr & 7) << 4))) = v;
        }
    }
    if (p.mode == 2) return;
    __syncthreads();   // ytile ready; sX staging drained

    // ---- phase B: xgd (128 x 192 gate-cols, K=64 from sX) + gates ----
    const int wrh = w >> 2, wcg = w & 3;
    floatx4 ag[4][3];
#pragma unroll
    for (int m = 0; m < 4; ++m)
#pragma unroll
        for (int g = 0; g < 3; ++g) ag[m][g] = floatx4{0.f, 0.f, 0.f, 0.f};
#pragma unroll
    for (int ks = 0; ks < 2; ++ks) {
        short8 ya[4], bf[3];
#pragma unroll
        for (int m = 0; m < 4; ++m) {
            const int row = wrh * 64 + m * 16 + r16;
            const int k0 = ks * 32 + lg * 8;
            ya[m] = *(const short8*)((char*)ytile + row * 128
                          + ((k0 * 2) ^ ((row & 7) << 4)));
        }
#pragma unroll
        for (int g = 0; g < 3; ++g) {
            const int rb = wcg * 48 + g * 16 + r16;
            bf[g] = *(const short8*)(sX + ks * 12288 + rb * 64
                          + ((lg ^ ((rb >> 1) & 3)) << 4));
        }
#pragma unroll
        for (int m = 0; m < 4; ++m)
#pragma unroll
            for (int g = 0; g < 3; ++g)
                ag[m][g] = mfma16(ya[m], bf[g], ag[m][g]);
    }

    const int u = h0 + wcg * 16 + r16;
    const float db0 = p.dbhh[u], db1 = p.dbhh[H + u], db2 = p.dbhh[2 * H + u];
#pragma unroll
    for (int m = 0; m < 4; ++m) {
#pragma unroll
        for (int j = 0; j < 4; ++j) {
            const int b = row0 + wrh * 64 + m * 16 + lg * 4 + j;
            const size_t g3 = (size_t)b * G3;
            const float xr = ag[m][0][j] + p.constb[g3 + u];
            const float xz = ag[m][1][j] + p.constb[g3 + H + u];
            const float xn = ag[m][2][j] + p.constb[g3 + 2 * H + u];
            const float hr = p.hga[g3 + u] + db0;
            const float hz = p.hga[g3 + H + u] + db1;
            const float hn = p.hga[g3 + 2 * H + u] + db2;
            const float rr = sigmoidf_(xr + hr);
            const float zz = sigmoidf_(xz + hz);
            const float nn = tanhf(xn + rr * hn);
            const float hold = p.hd[(size_t)b * H + u];
            const float hv = (1.f - zz) * nn + zz * hold;
            p.hd[(size_t)b * H + u] = hv;
            p.hdb[(size_t)b * H + u] = f2bf(hv);
        }
    }
}

// ===========================================================================
// kB: hga_next (48 roles) || MLP1 (32 roles) — 80 blocks x 256 threads.
// ===========================================================================
__global__ __launch_bounds__(256, 1) void k_dec_bk(
    const unsigned short* __restrict__ hdb,
    const unsigned short* __restrict__ dWhhb,
    const unsigned short* __restrict__ dmW1b, const float* __restrict__ dmb1,
    float* __restrict__ hga, unsigned short* __restrict__ hm1b)
{
    __shared__ __align__(16) unsigned short smA[2 * 64 * 64];
    __shared__ __align__(16) unsigned short smB[2 * 128 * 64];
    const int bid = blockIdx.x;
    if (bid < 48) {
        const int arow0 = (bid & 3) * 64, wrow0 = (bid >> 2) * 128;
        mgemm_body<64, 128>(threadIdx.x, smA, smB, hdb, H, arow0,
                            dWhhb, H, wrow0, nullptr,
                            hga, G3, nullptr, 0, H, 0);
    } else {
        const int b2 = bid - 48;
        const int arow0 = (b2 & 3) * 64, wrow0 = (b2 >> 2) * 128;
        mgemm_body<64, 128>(threadIdx.x, smA, smB, hdb, H, arow0,
                            dmW1b, H, wrow0, dmb1,
                            nullptr, 0, hm1b, M1, H, 1);
    }
}

// ===========================================================================
extern "C" void kernel_launch(void* const* d_in, const int* in_sizes, int n_in,
                              void* d_out, int out_size, void* d_ws, size_t ws_size,
                              hipStream_t stream)
{
    const float* x      = (const float*)d_in[0];
    const float* y      = (const float*)d_in[1];
    const float* xf_bih = (const float*)d_in[4];
    const float* xf_bhh = (const float*)d_in[5];
    const float* xb_bih = (const float*)d_in[8];
    const float* xb_bhh = (const float*)d_in[9];
    const float* ef_bih = (const float*)d_in[12];
    const float* ef_bhh = (const float*)d_in[13];
    const float* eb_bih = (const float*)d_in[16];
    const float* eb_bhh = (const float*)d_in[17];
    const float* em_b1  = (const float*)d_in[19];
    const float* em_b2  = (const float*)d_in[21];
    const float* eo_b   = (const float*)d_in[23];
    const float* d_bih  = (const float*)d_in[26];
    const float* d_bhh  = (const float*)d_in[27];
    const float* dm_b1  = (const float*)d_in[29];
    const float* dm_b2  = (const float*)d_in[31];
    const float* do_b   = (const float*)d_in[33];
    float* out = (float*)d_out;

    // ---- workspace carve-up ----
    float* fp = (float*)d_ws;
    float* Hs     = fp; fp += 4 * (size_t)B * H;
    float* hd     = fp; fp += (size_t)B * H;
    float* hga    = fp; fp += (size_t)B * G3;
    float* constb = fp; fp += (size_t)B * G3;

    unsigned short* up = (unsigned short*)fp;
    unsigned short* xb16  = up; up += (size_t)B * TX * NX;
    unsigned short* yb16  = up; up += (size_t)B * TY * NY;
    unsigned short* Hsb0  = up; up += 4 * (size_t)B * H;
    unsigned short* Hsb1  = up; up += 4 * (size_t)B * H;
    unsigned short* hdb   = up; up += (size_t)B * H;
    unsigned short* hcatb = up; up += (size_t)B * 2 * H;
    unsigned short* czb   = up; up += (size_t)B * 2 * H;
    unsigned short* h1b   = up; up += (size_t)B * M1;
    unsigned short* h2b   = up; up += (size_t)B * M2;
    unsigned short* hm1b  = up; up += (size_t)B * M1;
    unsigned short* hm2b  = up; up += (size_t)B * M2;

    const int    widx[16] = {2, 3, 6, 7, 10, 11, 14, 15, 18, 20, 22, 24, 25, 28, 30, 32};
    const size_t wsz[16]  = {
        (size_t)G3 * NX, (size_t)G3 * H, (size_t)G3 * NX, (size_t)G3 * H,
        (size_t)G3 * NX, (size_t)G3 * H, (size_t)G3 * NX, (size_t)G3 * H,
        (size_t)M1 * 2 * H, (size_t)M2 * M1, (size_t)H * M2,
        (size_t)G3 * DIN, (size_t)G3 * H, (size_t)M1 * H, (size_t)M2 * M1,
        (size_t)NY * M2};
    unsigned short* wb[16];
    for (int i = 0; i < 16; ++i) { wb[i] = up; up += wsz[i]; }

    // ---- conversions + state init ----
    CvtArgs ca;
    for (int i = 0; i < 16; ++i) {
        ca.src[i] = (const float*)d_in[widx[i]];
        ca.dst[i] = wb[i];
        ca.n[i]   = (int)wsz[i];
    }
    ca.src[16] = x; ca.dst[16] = xb16; ca.n[16] = B * TX * NX;
    ca.src[17] = y; ca.dst[17] = yb16; ca.n[17] = B * TY * NY;
    k_cvt_all<<<dim3(64, 18), 256, 0, stream>>>(ca);

    hipMemsetAsync(Hs,   0, sizeof(float) * 4 * (size_t)B * H, stream);
    hipMemsetAsync(Hsb0, 0, sizeof(unsigned short) * 4 * (size_t)B * H, stream);
    hipMemsetAsync(hd,   0, sizeof(float) * (size_t)B * H, stream);
    hipMemsetAsync(hga,  0, sizeof(float) * (size_t)B * G3, stream);

    // ---- encoder: 1 fused launch per step ----
    EncP ep;
    ep.xb = xb16; ep.yb = yb16; ep.Hsb0 = Hsb0; ep.Hsb1 = Hsb1; ep.Hs = Hs;
    ep.wih[0] = wb[0]; ep.whh[0] = wb[1];
    ep.wih[1] = wb[2]; ep.whh[1] = wb[3];
    ep.wih[2] = wb[4]; ep.whh[2] = wb[5];
    ep.wih[3] = wb[6]; ep.whh[3] = wb[7];
    ep.bih[0] = xf_bih; ep.bhh[0] = xf_bhh;
    ep.bih[1] = xb_bih; ep.bhh[1] = xb_bhh;
    ep.bih[2] = ef_bih; ep.bhh[2] = ef_bhh;
    ep.bih[3] = eb_bih; ep.bhh[3] = eb_bhh;
    for (int t = 0; t < TY; ++t) {
        ep.t = t;
        ep.job0 = (t < TX) ? 0 : 2;
        const int nj = (t < TX) ? 4 : 2;
        k_enc_step<<<dim3(8, 2, nj), 512, 0, stream>>>(ep);
    }

    // ---- bottleneck MLP ----
    k_sum_concat<<<B * H / 256, 256, 0, stream>>>(Hs, hcatb, czb);
    k_mgemm<128, 128><<<dim3(M1 / 128, B / 128), 256, 0, stream>>>(
        hcatb, 2 * H, wb[8], 2 * H, em_b1, nullptr, 0, h1b, M1, 2 * H, 1);
    k_mgemm<128, 128><<<dim3(M2 / 128, B / 128), 256, 0, stream>>>(
        h1b, M1, wb[9], M1, em_b2, nullptr, 0, h2b, M2, M1, 1);
    k_mgemm<128, 128><<<dim3(H / 128, B / 128), 256, 0, stream>>>(
        h2b, M2, wb[10], M2, eo_b, nullptr, 0, czb + H, 2 * H, M2, 0);
    k_mgemm<128, 128><<<dim3(G3 / 128, B / 128), 256, 0, stream>>>(
        czb, 2 * H, wb[11], DIN, d_bih, constb, G3, nullptr, 0, 2 * H, 0);

    // ---- decoder: 3 launches per step ----
    DecP dp;
    dp.xb = xb16; dp.hdb = hdb; dp.hd = hd; dp.hga = hga; dp.constb = constb;
    dp.dWihb = wb[11]; dp.dbhh = d_bhh;
    dp.doWb = wb[15]; dp.dob = do_b;
    dp.hm2b = hm2b; dp.outp = out;
    for (int t = 0; t < HOR; ++t) {
        dp.mode = (t == 0) ? 0 : 1;
        dp.tprev = t - 1;
        k_dec_step<<<dim3(8, 2), 512, 0, stream>>>(dp);
        k_dec_bk<<<80, 256, 0, stream>>>(hdb, wb[12], wb[13], dm_b1, hga, hm1b);
        k_mgemm<64, 64><<<dim3(M2 / 64, B / 64), 256, 0, stream>>>(
            hm1b, M1, wb[14], M1, dm_b2, nullptr, 0, hm2b, M2, M1, 1);
    }
    dp.mode = 2;
    dp.tprev = HOR - 1;
    k_dec_step<<<dim3(1, 2), 512, 0, stream>>>(dp);
}

// Round 17
// 4158.258 us; speedup vs baseline: 1.2995x; 1.1035x over previous
//
#include <hip/hip_runtime.h>
#include <math.h>

#define B   256
#define TX  50
#define TY  100
#define NX  64
#define NY  64
#define H   512
#define HOR 60
#define M1  1024
#define M2  512
#define G3  (3*H)        // 1536
#define DIN (2*H + NY)   // 1088

typedef __attribute__((ext_vector_type(8))) short short8;
typedef __attribute__((ext_vector_type(4))) float floatx4;

__device__ __forceinline__ unsigned short f2bf(float f) {
    union { float f; unsigned u; } v; v.f = f;
    return (unsigned short)((v.u + 0x7FFFu + ((v.u >> 16) & 1u)) >> 16);
}

__device__ __forceinline__ float sigmoidf_(float v) {
    return 1.f / (1.f + __expf(-v));
}

__device__ __forceinline__ short8 ld8(const unsigned short* p) {
    return *(const short8*)p;
}

__device__ __forceinline__ floatx4 mfma16(short8 a, short8 b, floatx4 c) {
    return __builtin_amdgcn_mfma_f32_16x16x32_bf16(a, b, c, 0, 0, 0);
}

__device__ __forceinline__ void gload_lds16(const void* g, void* lds) {
    __builtin_amdgcn_global_load_lds(
        (const __attribute__((address_space(1))) void*)g,
        (__attribute__((address_space(3))) void*)lds, 16, 0, 0);
}

// BK=64 row layout: [row][8 chunks of 16B], row stride 128B.
// Swizzle (2-way bank aliasing): involution per row.
__device__ __forceinline__ int swz_src(int pc8, int row) {
    return (((pc8 >> 2) ^ (row & 1)) << 2) | ((pc8 & 3) ^ ((row >> 1) & 3));
}
__device__ __forceinline__ int swz_rd(int h, int lg, int row) {
    return (((h ^ (row & 1)) & 1) << 2) | ((lg ^ ((row >> 1) & 3)) & 3);
}

// ===========================================================================
// BMxBN MFMA GEMM body, 256 threads — BK=64 double-buffered K-pipeline.
// ===========================================================================
template<int BM, int BN>
__device__ __forceinline__ void mgemm_body(
    int tid, unsigned short* smA, unsigned short* smB,
    const unsigned short* __restrict__ A, int lda, int arow0,
    const unsigned short* __restrict__ W, int ldw, int wrow0,
    const float* __restrict__ bias,
    float* __restrict__ Cf, int ldcf,
    unsigned short* __restrict__ Cb, int ldcb,
    int K, int relu)
{
    constexpr int MF = BM / 32;
    constexpr int NF = BN / 32;
    const int w  = tid >> 6, l = tid & 63;
    const int wr = w >> 1, wc = w & 1;
    const int lg = l >> 4, r16 = l & 15;

    auto stage = [&](int k0, int buf) {
#pragma unroll
        for (int i = 0; i < BM / 32; ++i) {
            const int ci = tid + i * 256;
            const int row = ci >> 3, pc = ci & 7;
            const int lc = swz_src(pc, row);
            gload_lds16(A + (size_t)(arow0 + row) * lda + k0 + lc * 8,
                        (char*)smA + buf * (BM * 128) + ci * 16);
        }
#pragma unroll
        for (int i = 0; i < BN / 32; ++i) {
            const int ci = tid + i * 256;
            const int row = ci >> 3, pc = ci & 7;
            const int lc = swz_src(pc, row);
            gload_lds16(W + (size_t)(wrow0 + row) * ldw + k0 + lc * 8,
                        (char*)smB + buf * (BN * 128) + ci * 16);
        }
    };

    floatx4 acc[MF][NF];
#pragma unroll
    for (int m = 0; m < MF; ++m)
#pragma unroll
        for (int n = 0; n < NF; ++n) acc[m][n] = floatx4{0.f, 0.f, 0.f, 0.f};

    const int nk = K >> 6;
    stage(0, 0);
    for (int s = 0; s < nk; ++s) {
        __syncthreads();
        if (s + 1 < nk) stage((s + 1) << 6, (s + 1) & 1);
        const char* bA = (char*)smA + (s & 1) * (BM * 128);
        const char* bB = (char*)smB + (s & 1) * (BN * 128);
#pragma unroll
        for (int h = 0; h < 2; ++h) {
            short8 af[MF], bfr[NF];
#pragma unroll
            for (int m = 0; m < MF; ++m) {
                const int row = wr * (BM / 2) + m * 16 + r16;
                af[m] = *(const short8*)(bA + row * 128 + swz_rd(h, lg, row) * 16);
            }
#pragma unroll
            for (int n = 0; n < NF; ++n) {
                const int row = wc * (BN / 2) + n * 16 + r16;
                bfr[n] = *(const short8*)(bB + row * 128 + swz_rd(h, lg, row) * 16);
            }
#pragma unroll
            for (int m = 0; m < MF; ++m)
#pragma unroll
                for (int n = 0; n < NF; ++n)
                    acc[m][n] = mfma16(af[m], bfr[n], acc[m][n]);
        }
    }

#pragma unroll
    for (int m = 0; m < MF; ++m) {
#pragma unroll
        for (int n = 0; n < NF; ++n) {
#pragma unroll
            for (int j = 0; j < 4; ++j) {
                const int r = arow0 + wr * (BM / 2) + m * 16 + lg * 4 + j;
                const int c = wrow0 + wc * (BN / 2) + n * 16 + r16;
                float v = acc[m][n][j];
                if (bias) v += bias[c];
                if (relu && v < 0.f) v = 0.f;
                if (Cf) Cf[(size_t)r * ldcf + c] = v;
                if (Cb) Cb[(size_t)r * ldcb + c] = f2bf(v);
            }
        }
    }
}

template<int BM, int BN>
__global__ __launch_bounds__(256, 1) void k_mgemm(
    const unsigned short* __restrict__ A, int lda,
    const unsigned short* __restrict__ W, int ldw,
    const float* __restrict__ bias,
    float* __restrict__ Cf, int ldcf,
    unsigned short* __restrict__ Cb, int ldcb,
    int K, int relu)
{
    __shared__ __align__(16) unsigned short smA[2 * BM * 64];
    __shared__ __align__(16) unsigned short smB[2 * BN * 64];
    mgemm_body<BM, BN>(threadIdx.x, smA, smB, A, lda, blockIdx.y * BM,
                       W, ldw, blockIdx.x * BN, bias,
                       Cf, ldcf, Cb, ldcb, K, relu);
}

// ===========================================================================
// fused fp32 -> bf16 conversion (18 segments, one launch)
// ===========================================================================
struct CvtArgs {
    const float* src[18];
    unsigned short* dst[18];
    int n[18];
};

__global__ __launch_bounds__(256) void k_cvt_all(CvtArgs a)
{
    const int seg = blockIdx.y;
    const float* s = a.src[seg];
    unsigned short* d = a.dst[seg];
    const int c4 = a.n[seg] >> 2;
    for (int i = blockIdx.x * 256 + threadIdx.x; i < c4; i += gridDim.x * 256) {
        float4 v = ((const float4*)s)[i];
        ushort4 o;
        o.x = f2bf(v.x); o.y = f2bf(v.y); o.z = f2bf(v.z); o.w = f2bf(v.w);
        ((ushort4*)d)[i] = o;
    }
}

// ===========================================================================
// h_x = hxf + hxb ; h_y = hef + heb ; hcat = [h_x,h_y] bf16 ; cz[:, :H] = h_x
// ===========================================================================
__global__ __launch_bounds__(256) void k_sum_concat(
    const float* __restrict__ Hs,
    unsigned short* __restrict__ hcatb, unsigned short* __restrict__ czb)
{
    const int idx = blockIdx.x * 256 + threadIdx.x;  // B*H
    const int b = idx / H, i = idx % H;
    const float hx = Hs[idx] + Hs[(size_t)B * H + idx];
    const float hy = Hs[2 * (size_t)B * H + idx] + Hs[3 * (size_t)B * H + idx];
    const unsigned short hxb = f2bf(hx);
    hcatb[(size_t)b * (2 * H) + i] = hxb;
    hcatb[(size_t)b * (2 * H) + H + i] = f2bf(hy);
    czb[(size_t)b * (2 * H) + i] = hxb;
}

// ===========================================================================
// Fused encoder step — BK=64 pipeline, batch-split 2->4 (64 rows/block).
// Grid (8 hid-slices, 4 batch-quarters, njobs); 512 threads = 8 waves
// (2 row-groups of 32 x 4 col-groups of 48). LDS: A 2x8KB + B 2x24KB = 64KB.
// ===========================================================================
struct EncP {
    const unsigned short *xb, *yb;
    unsigned short *Hsb0, *Hsb1;
    float* Hs;
    const unsigned short *wih[4], *whh[4];
    const float *bih[4], *bhh[4];
    int t, job0;
};

__global__ __launch_bounds__(512, 2) void k_enc_step(EncP p)
{
    __shared__ __align__(16) char smA[2 * 8192];    // 2 x 64x64 bf16
    __shared__ __align__(16) char smB[2 * 24576];   // 2 x 192x64 bf16
    const int job = p.job0 + blockIdx.z;
    const int h0 = blockIdx.x * 64;
    const int row0 = blockIdx.y * 64;
    const int tid = threadIdx.x;
    const int w = tid >> 6, l = tid & 63;
    const int lg = l >> 4, r16 = l & 15;
    const int wrh = w >> 2, wcg = w & 3;
    const int T = (job < 2) ? TX : TY;
    const int tt = (job & 1) ? (T - 1 - p.t) : p.t;
    const unsigned short* xsrc = (job < 2) ? p.xb : p.yb;
    const unsigned short* wihg = p.wih[job];
    const unsigned short* whhg = p.whh[job];
    const unsigned short* hin =
        ((p.t & 1) ? p.Hsb1 : p.Hsb0) + (size_t)job * B * H;
    unsigned short* hout =
        ((p.t & 1) ? p.Hsb0 : p.Hsb1) + (size_t)job * B * H;

    // A staging: 64 rows x 8 chunks = 512 chunks (1/thread)
    const int aRow = tid >> 3;
    const int aLc = swz_src(tid & 7, aRow);
    // B staging: 192 rows x 8 chunks = 1536 chunks (3/thread)
    int bWr[3], bLc[3];
#pragma unroll
    for (int i = 0; i < 3; ++i) {
        const int ci = tid + i * 512;
        const int row = ci >> 3;
        const int f = row >> 4;
        bWr[i] = (f % 3) * H + h0 + (f / 3) * 16 + (row & 15);
        bLc[i] = swz_src(ci & 7, row);
    }

    auto stage = [&](int s, int buf) {
        char* dA = smA + buf * 8192;
        char* dB = smB + buf * 24576;
        if (s < 8) {
            const int k0 = s * 64;
            gload_lds16(hin + (size_t)(row0 + aRow) * H + k0 + aLc * 8,
                        dA + tid * 16);
#pragma unroll
            for (int i = 0; i < 3; ++i)
                gload_lds16(whhg + (size_t)bWr[i] * H + k0 + bLc[i] * 8,
                            dB + (tid + i * 512) * 16);
        } else {
            gload_lds16(xsrc + ((size_t)(row0 + aRow) * T + tt) * NX + aLc * 8,
                        dA + tid * 16);
#pragma unroll
            for (int i = 0; i < 3; ++i)
                gload_lds16(wihg + (size_t)bWr[i] * NX + bLc[i] * 8,
                            dB + (tid + i * 512) * 16);
        }
    };

    floatx4 am[2][3], axn[2];
#pragma unroll
    for (int m = 0; m < 2; ++m) {
        axn[m] = floatx4{0.f, 0.f, 0.f, 0.f};
#pragma unroll
        for (int g = 0; g < 3; ++g) am[m][g] = floatx4{0.f, 0.f, 0.f, 0.f};
    }

    stage(0, 0);
    for (int s = 0; s < 9; ++s) {
        __syncthreads();
        if (s + 1 < 9) stage(s + 1, (s + 1) & 1);
        const char* bA = smA + (s & 1) * 8192;
        const char* bB = smB + (s & 1) * 24576;
        const bool isx = (s == 8);
#pragma unroll
        for (int h = 0; h < 2; ++h) {
            short8 af[2], bf[3];
#pragma unroll
            for (int m = 0; m < 2; ++m) {
                const int row = wrh * 32 + m * 16 + r16;
                af[m] = *(const short8*)(bA + row * 128 + swz_rd(h, lg, row) * 16);
            }
#pragma unroll
            for (int g = 0; g < 3; ++g) {
                const int rb = wcg * 48 + g * 16 + r16;
                bf[g] = *(const short8*)(bB + rb * 128 + swz_rd(h, lg, rb) * 16);
            }
            if (!isx) {
#pragma unroll
                for (int m = 0; m < 2; ++m) {
                    am[m][0] = mfma16(af[m], bf[0], am[m][0]);
                    am[m][1] = mfma16(af[m], bf[1], am[m][1]);
                    am[m][2] = mfma16(af[m], bf[2], am[m][2]);
                }
            } else {
#pragma unroll
                for (int m = 0; m < 2; ++m) {
                    am[m][0] = mfma16(af[m], bf[0], am[m][0]);
                    am[m][1] = mfma16(af[m], bf[1], am[m][1]);
                    axn[m]   = mfma16(af[m], bf[2], axn[m]);
                }
            }
        }
    }

    // ---- gate epilogue ----
    const int u = h0 + wcg * 16 + r16;
    const float bi0 = p.bih[job][u]        + p.bhh[job][u];
    const float bi1 = p.bih[job][H + u]    + p.bhh[job][H + u];
    const float bi2 = p.bih[job][2 * H + u];
    const float bh2 = p.bhh[job][2 * H + u];
    float* HsJ = p.Hs + (size_t)job * B * H;
#pragma unroll
    for (int m = 0; m < 2; ++m) {
#pragma unroll
        for (int j = 0; j < 4; ++j) {
            const int br = row0 + wrh * 32 + m * 16 + lg * 4 + j;
            const float rr = sigmoidf_(am[m][0][j] + bi0);
            const float zz = sigmoidf_(am[m][1][j] + bi1);
            const float nn = tanhf(axn[m][j] + bi2 + rr * (am[m][2][j] + bh2));
            const float hold = HsJ[(size_t)br * H + u];
            const float hv = (1.f - zz) * nn + zz * hold;
            HsJ[(size_t)br * H + u] = hv;
            hout[(size_t)br * H + u] = f2bf(hv);
        }
    }
}

// ===========================================================================
// Decoder step kernel (STAGED, BK=64 phase A; r16-proven).
// Grid (8 hid-slices, 2 batch halves), 512 threads.
// mode: 0 = t==0 (y from x[:,-1]), 1 = normal, 2 = out-only (final y).
// ===========================================================================
struct DecP {
    const unsigned short* xb;
    unsigned short* hdb;
    float* hd;
    const float* hga;
    const float* constb;
    const unsigned short* dWihb;
    const float* dbhh;
    const unsigned short* doWb; const float* dob;
    const unsigned short* hm2b;
    float* outp;
    int mode, tprev;
};

__global__ __launch_bounds__(512, 2) void k_dec_step(DecP p)
{
    __shared__ __align__(16) char sA[2 * 16384];         // hm2 tiles (dbuf, 128x64)
    __shared__ __align__(16) char sW[2 * 8192];          // doW tiles (dbuf, 64x64)
    __shared__ __align__(16) char sX[2 * 12288];         // dWih gate tiles (old fmt)
    __shared__ __align__(16) unsigned short ytile[128 * 64];  // swizzled
    const int tid = threadIdx.x;
    const int w = tid >> 6, l = tid & 63;
    const int lg = l >> 4, r16 = l & 15;
    const int row0 = blockIdx.y * 128;
    const int h0 = blockIdx.x * 64;

    // old-format staging math for sX (32-elem rows, 4-chunk swizzle)
    const int sAr = tid >> 2;
    const int sAl = (tid & 3) ^ ((sAr >> 1) & 3);
    const int f0 = sAr >> 4;
    const int W0 = (f0 % 3) * H + h0 + (f0 / 3) * 16 + (sAr & 15);
    const int sB1r = 128 + (tid >> 2);             // tid<256 only
    const int sB1l = (tid & 3) ^ ((sB1r >> 1) & 3);
    const int f1 = sB1r >> 4;
    const int W1 = (f1 % 3) * H + h0 + (f1 / 3) * 16 + (sB1r & 15);

    // ---- issue gate-tile staging immediately (completes under phase A) ----
    if (p.mode != 2) {
#pragma unroll
        for (int kc = 0; kc < 2; ++kc) {
            gload_lds16(p.dWihb + (size_t)W0 * DIN + 2 * H + kc * 32 + sAl * 8,
                        sX + kc * 12288 + tid * 16);
            if (tid < 256)
                gload_lds16(p.dWihb + (size_t)W1 * DIN + 2 * H + kc * 32 + sB1l * 8,
                            sX + kc * 12288 + 8192 + tid * 16);
        }
    }

    if (p.mode != 0) {
        // ---- phase A: y = hm2b @ doW^T + dob (128x64, K=512), BK=64 dbuf ----
        int aRow[2], aLc[2];
#pragma unroll
        for (int i = 0; i < 2; ++i) {
            const int ci = tid + i * 512;
            aRow[i] = ci >> 3;
            aLc[i] = swz_src(ci & 7, aRow[i]);
        }
        const int wRow = tid >> 3;
        const int wLc = swz_src(tid & 7, wRow);
        auto stageA = [&](int s, int buf) {
            const int k0 = s * 64;
#pragma unroll
            for (int i = 0; i < 2; ++i)
                gload_lds16(p.hm2b + (size_t)(row0 + aRow[i]) * M2 + k0 + aLc[i] * 8,
                            sA + buf * 16384 + (tid + i * 512) * 16);
            gload_lds16(p.doWb + (size_t)wRow * M2 + k0 + wLc * 8,
                        sW + buf * 8192 + tid * 16);
        };
        const int wrA = w >> 1, wcA = w & 1;   // 4 x 2 waves, 32x32 tiles
        floatx4 acc[2][2];
#pragma unroll
        for (int mA = 0; mA < 2; ++mA)
#pragma unroll
            for (int nA = 0; nA < 2; ++nA) acc[mA][nA] = floatx4{0.f, 0.f, 0.f, 0.f};

        stageA(0, 0);
        for (int s = 0; s < 8; ++s) {
            __syncthreads();
            if (s + 1 < 8) stageA(s + 1, (s + 1) & 1);
            const char* bA = sA + (s & 1) * 16384;
            const char* bW = sW + (s & 1) * 8192;
#pragma unroll
            for (int h = 0; h < 2; ++h) {
                short8 av[2], bv[2];
#pragma unroll
                for (int mA = 0; mA < 2; ++mA) {
                    const int row = wrA * 32 + mA * 16 + r16;
                    av[mA] = *(const short8*)(bA + row * 128 + swz_rd(h, lg, row) * 16);
                }
#pragma unroll
                for (int nA = 0; nA < 2; ++nA) {
                    const int row = wcA * 32 + nA * 16 + r16;
                    bv[nA] = *(const short8*)(bW + row * 128 + swz_rd(h, lg, row) * 16);
                }
#pragma unroll
                for (int mA = 0; mA < 2; ++mA)
#pragma unroll
                    for (int nA = 0; nA < 2; ++nA)
                        acc[mA][nA] = mfma16(av[mA], bv[nA], acc[mA][nA]);
            }
        }
#pragma unroll
        for (int mA = 0; mA < 2; ++mA) {
#pragma unroll
            for (int nA = 0; nA < 2; ++nA) {
#pragma unroll
                for (int j = 0; j < 4; ++j) {
                    const int rr = wrA * 32 + mA * 16 + lg * 4 + j;
                    const int cc = wcA * 32 + nA * 16 + r16;
                    const float v = acc[mA][nA][j] + p.dob[cc];
                    if (blockIdx.x == 0)
                        p.outp[(size_t)(row0 + rr) * (HOR * NY)
                               + (size_t)p.tprev * NY + cc] = v;
                    *(unsigned short*)((char*)ytile + rr * 128
                        + ((cc * 2) ^ ((rr & 7) << 4))) = f2bf(v);
                }
            }
        }
    } else {
        for (int i = tid; i < 128 * 64; i += 512) {
            const int rr = i >> 6, cc = i & 63;
            const unsigned short v =
                p.xb[((size_t)(row0 + rr) * TX + TX - 1) * NX + cc];
            *(unsigned short*)((char*)ytile + rr * 128
                + ((cc * 2) ^ ((rr & 7) << 4))) = v;
        }
    }
    if (p.mode == 2) return;
    __syncthreads();   // ytile ready; sX staging drained

    // ---- phase B: xgd (128 x 192 gate-cols, K=64 from sX) + gates ----
    const int wrh = w >> 2, wcg = w & 3;
    floatx4 ag[4][3];
#pragma unroll
    for (int m = 0; m < 4; ++m)
#pragma unroll
        for (int g = 0; g < 3; ++g) ag[m][g] = floatx4{0.f, 0.f, 0.f, 0.f};
#pragma unroll
    for (int ks = 0; ks < 2; ++ks) {
        short8 ya[4], bf[3];
#pragma unroll
        for (int m = 0; m < 4; ++m) {
            const int row = wrh * 64 + m * 16 + r16;
            const int k0 = ks * 32 + lg * 8;
            ya[m] = *(const short8*)((char*)ytile + row * 128
                          + ((k0 * 2) ^ ((row & 7) << 4)));
        }
#pragma unroll
        for (int g = 0; g < 3; ++g) {
            const int rb = wcg * 48 + g * 16 + r16;
            bf[g] = *(const short8*)(sX + ks * 12288 + rb * 64
                          + ((lg ^ ((rb >> 1) & 3)) << 4));
        }
#pragma unroll
        for (int m = 0; m < 4; ++m)
#pragma unroll
            for (int g = 0; g < 3; ++g)
                ag[m][g] = mfma16(ya[m], bf[g], ag[m][g]);
    }

    const int u = h0 + wcg * 16 + r16;
    const float db0 = p.dbhh[u], db1 = p.dbhh[H + u], db2 = p.dbhh[2 * H + u];
#pragma unroll
    for (int m = 0; m < 4; ++m) {
#pragma unroll
        for (int j = 0; j < 4; ++j) {
            const int b = row0 + wrh * 64 + m * 16 + lg * 4 + j;
            const size_t g3 = (size_t)b * G3;
            const float xr = ag[m][0][j] + p.constb[g3 + u];
            const float xz = ag[m][1][j] + p.constb[g3 + H + u];
            const float xn = ag[m][2][j] + p.constb[g3 + 2 * H + u];
            const float hr = p.hga[g3 + u] + db0;
            const float hz = p.hga[g3 + H + u] + db1;
            const float hn = p.hga[g3 + 2 * H + u] + db2;
            const float rr = sigmoidf_(xr + hr);
            const float zz = sigmoidf_(xz + hz);
            const float nn = tanhf(xn + rr * hn);
            const float hold = p.hd[(size_t)b * H + u];
            const float hv = (1.f - zz) * nn + zz * hold;
            p.hd[(size_t)b * H + u] = hv;
            p.hdb[(size_t)b * H + u] = f2bf(hv);
        }
    }
}

// ===========================================================================
// kB: hga_next (48 roles) || MLP1 (32 roles) — 80 blocks x 256 threads.
// ===========================================================================
__global__ __launch_bounds__(256, 1) void k_dec_bk(
    const unsigned short* __restrict__ hdb,
    const unsigned short* __restrict__ dWhhb,
    const unsigned short* __restrict__ dmW1b, const float* __restrict__ dmb1,
    float* __restrict__ hga, unsigned short* __restrict__ hm1b)
{
    __shared__ __align__(16) unsigned short smA[2 * 64 * 64];
    __shared__ __align__(16) unsigned short smB[2 * 128 * 64];
    const int bid = blockIdx.x;
    if (bid < 48) {
        const int arow0 = (bid & 3) * 64, wrow0 = (bid >> 2) * 128;
        mgemm_body<64, 128>(threadIdx.x, smA, smB, hdb, H, arow0,
                            dWhhb, H, wrow0, nullptr,
                            hga, G3, nullptr, 0, H, 0);
    } else {
        const int b2 = bid - 48;
        const int arow0 = (b2 & 3) * 64, wrow0 = (b2 >> 2) * 128;
        mgemm_body<64, 128>(threadIdx.x, smA, smB, hdb, H, arow0,
                            dmW1b, H, wrow0, dmb1,
                            nullptr, 0, hm1b, M1, H, 1);
    }
}

// ===========================================================================
extern "C" void kernel_launch(void* const* d_in, const int* in_sizes, int n_in,
                              void* d_out, int out_size, void* d_ws, size_t ws_size,
                              hipStream_t stream)
{
    const float* x      = (const float*)d_in[0];
    const float* y      = (const float*)d_in[1];
    const float* xf_bih = (const float*)d_in[4];
    const float* xf_bhh = (const float*)d_in[5];
    const float* xb_bih = (const float*)d_in[8];
    const float* xb_bhh = (const float*)d_in[9];
    const float* ef_bih = (const float*)d_in[12];
    const float* ef_bhh = (const float*)d_in[13];
    const float* eb_bih = (const float*)d_in[16];
    const float* eb_bhh = (const float*)d_in[17];
    const float* em_b1  = (const float*)d_in[19];
    const float* em_b2  = (const float*)d_in[21];
    const float* eo_b   = (const float*)d_in[23];
    const float* d_bih  = (const float*)d_in[26];
    const float* d_bhh  = (const float*)d_in[27];
    const float* dm_b1  = (const float*)d_in[29];
    const float* dm_b2  = (const float*)d_in[31];
    const float* do_b   = (const float*)d_in[33];
    float* out = (float*)d_out;

    // ---- workspace carve-up ----
    float* fp = (float*)d_ws;
    float* Hs     = fp; fp += 4 * (size_t)B * H;
    float* hd     = fp; fp += (size_t)B * H;
    float* hga    = fp; fp += (size_t)B * G3;
    float* constb = fp; fp += (size_t)B * G3;

    unsigned short* up = (unsigned short*)fp;
    unsigned short* xb16  = up; up += (size_t)B * TX * NX;
    unsigned short* yb16  = up; up += (size_t)B * TY * NY;
    unsigned short* Hsb0  = up; up += 4 * (size_t)B * H;
    unsigned short* Hsb1  = up; up += 4 * (size_t)B * H;
    unsigned short* hdb   = up; up += (size_t)B * H;
    unsigned short* hcatb = up; up += (size_t)B * 2 * H;
    unsigned short* czb   = up; up += (size_t)B * 2 * H;
    unsigned short* h1b   = up; up += (size_t)B * M1;
    unsigned short* h2b   = up; up += (size_t)B * M2;
    unsigned short* hm1b  = up; up += (size_t)B * M1;
    unsigned short* hm2b  = up; up += (size_t)B * M2;

    const int    widx[16] = {2, 3, 6, 7, 10, 11, 14, 15, 18, 20, 22, 24, 25, 28, 30, 32};
    const size_t wsz[16]  = {
        (size_t)G3 * NX, (size_t)G3 * H, (size_t)G3 * NX, (size_t)G3 * H,
        (size_t)G3 * NX, (size_t)G3 * H, (size_t)G3 * NX, (size_t)G3 * H,
        (size_t)M1 * 2 * H, (size_t)M2 * M1, (size_t)H * M2,
        (size_t)G3 * DIN, (size_t)G3 * H, (size_t)M1 * H, (size_t)M2 * M1,
        (size_t)NY * M2};
    unsigned short* wb[16];
    for (int i = 0; i < 16; ++i) { wb[i] = up; up += wsz[i]; }

    // ---- conversions + state init ----
    CvtArgs ca;
    for (int i = 0; i < 16; ++i) {
        ca.src[i] = (const float*)d_in[widx[i]];
        ca.dst[i] = wb[i];
        ca.n[i]   = (int)wsz[i];
    }
    ca.src[16] = x; ca.dst[16] = xb16; ca.n[16] = B * TX * NX;
    ca.src[17] = y; ca.dst[17] = yb16; ca.n[17] = B * TY * NY;
    k_cvt_all<<<dim3(64, 18), 256, 0, stream>>>(ca);

    hipMemsetAsync(Hs,   0, sizeof(float) * 4 * (size_t)B * H, stream);
    hipMemsetAsync(Hsb0, 0, sizeof(unsigned short) * 4 * (size_t)B * H, stream);
    hipMemsetAsync(hd,   0, sizeof(float) * (size_t)B * H, stream);
    hipMemsetAsync(hga,  0, sizeof(float) * (size_t)B * G3, stream);

    // ---- encoder: 1 fused launch per step ----
    EncP ep;
    ep.xb = xb16; ep.yb = yb16; ep.Hsb0 = Hsb0; ep.Hsb1 = Hsb1; ep.Hs = Hs;
    ep.wih[0] = wb[0]; ep.whh[0] = wb[1];
    ep.wih[1] = wb[2]; ep.whh[1] = wb[3];
    ep.wih[2] = wb[4]; ep.whh[2] = wb[5];
    ep.wih[3] = wb[6]; ep.whh[3] = wb[7];
    ep.bih[0] = xf_bih; ep.bhh[0] = xf_bhh;
    ep.bih[1] = xb_bih; ep.bhh[1] = xb_bhh;
    ep.bih[2] = ef_bih; ep.bhh[2] = ef_bhh;
    ep.bih[3] = eb_bih; ep.bhh[3] = eb_bhh;
    for (int t = 0; t < TY; ++t) {
        ep.t = t;
        ep.job0 = (t < TX) ? 0 : 2;
        const int nj = (t < TX) ? 4 : 2;
        k_enc_step<<<dim3(8, 4, nj), 512, 0, stream>>>(ep);
    }

    // ---- bottleneck MLP ----
    k_sum_concat<<<B * H / 256, 256, 0, stream>>>(Hs, hcatb, czb);
    k_mgemm<128, 128><<<dim3(M1 / 128, B / 128), 256, 0, stream>>>(
        hcatb, 2 * H, wb[8], 2 * H, em_b1, nullptr, 0, h1b, M1, 2 * H, 1);
    k_mgemm<128, 128><<<dim3(M2 / 128, B / 128), 256, 0, stream>>>(
        h1b, M1, wb[9], M1, em_b2, nullptr, 0, h2b, M2, M1, 1);
    k_mgemm<128, 128><<<dim3(H / 128, B / 128), 256, 0, stream>>>(
        h2b, M2, wb[10], M2, eo_b, nullptr, 0, czb + H, 2 * H, M2, 0);
    k_mgemm<128, 128><<<dim3(G3 / 128, B / 128), 256, 0, stream>>>(
        czb, 2 * H, wb[11], DIN, d_bih, constb, G3, nullptr, 0, 2 * H, 0);

    // ---- decoder: 3 launches per step ----
    DecP dp;
    dp.xb = xb16; dp.hdb = hdb; dp.hd = hd; dp.hga = hga; dp.constb = constb;
    dp.dWihb = wb[11]; dp.dbhh = d_bhh;
    dp.doWb = wb[15]; dp.dob = do_b;
    dp.hm2b = hm2b; dp.outp = out;
    for (int t = 0; t < HOR; ++t) {
        dp.mode = (t == 0) ? 0 : 1;
        dp.tprev = t - 1;
        k_dec_step<<<dim3(8, 2), 512, 0, stream>>>(dp);
        k_dec_bk<<<80, 256, 0, stream>>>(hdb, wb[12], wb[13], dm_b1, hga, hm1b);
        k_mgemm<64, 64><<<dim3(M2 / 64, B / 64), 256, 0, stream>>>(
            hm1b, M1, wb[14], M1, dm_b2, nullptr, 0, hm2b, M2, M1, 1);
    }
    dp.mode = 2;
    dp.tprev = HOR - 1;
    k_dec_step<<<dim3(1, 2), 512, 0, stream>>>(dp);
}

// Round 18
// 3504.652 us; speedup vs baseline: 1.5419x; 1.1865x over previous
//
#include <hip/hip_runtime.h>
#include <math.h>

#define B   256
#define TX  50
#define TY  100
#define NX  64
#define NY  64
#define H   512
#define HOR 60
#define M1  1024
#define M2  512
#define G3  (3*H)        // 1536
#define DIN (2*H + NY)   // 1088

typedef __attribute__((ext_vector_type(8))) short short8;
typedef __attribute__((ext_vector_type(4))) float floatx4;

__device__ __forceinline__ unsigned short f2bf(float f) {
    union { float f; unsigned u; } v; v.f = f;
    return (unsigned short)((v.u + 0x7FFFu + ((v.u >> 16) & 1u)) >> 16);
}

__device__ __forceinline__ float sigmoidf_(float v) {
    return 1.f / (1.f + __expf(-v));
}

__device__ __forceinline__ short8 ld8(const unsigned short* p) {
    return *(const short8*)p;
}

__device__ __forceinline__ floatx4 mfma16(short8 a, short8 b, floatx4 c) {
    return __builtin_amdgcn_mfma_f32_16x16x32_bf16(a, b, c, 0, 0, 0);
}

__device__ __forceinline__ void gload_lds16(const void* g, void* lds) {
    __builtin_amdgcn_global_load_lds(
        (const __attribute__((address_space(1))) void*)g,
        (__attribute__((address_space(3))) void*)lds, 16, 0, 0);
}

// BK=64 row layout: [row][8 chunks of 16B], row stride 128B.
// Swizzle (2-way bank aliasing): involution per row.
__device__ __forceinline__ int swz_src(int pc8, int row) {
    return (((pc8 >> 2) ^ (row & 1)) << 2) | ((pc8 & 3) ^ ((row >> 1) & 3));
}
__device__ __forceinline__ int swz_rd(int h, int lg, int row) {
    return (((h ^ (row & 1)) & 1) << 2) | ((lg ^ ((row >> 1) & 3)) & 3);
}

// ===========================================================================
// BMxBN MFMA GEMM body, 256 threads — BK=64 double-buffered K-pipeline.
// ===========================================================================
template<int BM, int BN>
__device__ __forceinline__ void mgemm_body(
    int tid, unsigned short* smA, unsigned short* smB,
    const unsigned short* __restrict__ A, int lda, int arow0,
    const unsigned short* __restrict__ W, int ldw, int wrow0,
    const float* __restrict__ bias,
    float* __restrict__ Cf, int ldcf,
    unsigned short* __restrict__ Cb, int ldcb,
    int K, int relu)
{
    constexpr int MF = BM / 32;
    constexpr int NF = BN / 32;
    const int w  = tid >> 6, l = tid & 63;
    const int wr = w >> 1, wc = w & 1;
    const int lg = l >> 4, r16 = l & 15;

    auto stage = [&](int k0, int buf) {
#pragma unroll
        for (int i = 0; i < BM / 32; ++i) {
            const int ci = tid + i * 256;
            const int row = ci >> 3, pc = ci & 7;
            const int lc = swz_src(pc, row);
            gload_lds16(A + (size_t)(arow0 + row) * lda + k0 + lc * 8,
                        (char*)smA + buf * (BM * 128) + ci * 16);
        }
#pragma unroll
        for (int i = 0; i < BN / 32; ++i) {
            const int ci = tid + i * 256;
            const int row = ci >> 3, pc = ci & 7;
            const int lc = swz_src(pc, row);
            gload_lds16(W + (size_t)(wrow0 + row) * ldw + k0 + lc * 8,
                        (char*)smB + buf * (BN * 128) + ci * 16);
        }
    };

    floatx4 acc[MF][NF];
#pragma unroll
    for (int m = 0; m < MF; ++m)
#pragma unroll
        for (int n = 0; n < NF; ++n) acc[m][n] = floatx4{0.f, 0.f, 0.f, 0.f};

    const int nk = K >> 6;
    stage(0, 0);
    for (int s = 0; s < nk; ++s) {
        __syncthreads();
        if (s + 1 < nk) stage((s + 1) << 6, (s + 1) & 1);
        const char* bA = (char*)smA + (s & 1) * (BM * 128);
        const char* bB = (char*)smB + (s & 1) * (BN * 128);
#pragma unroll
        for (int h = 0; h < 2; ++h) {
            short8 af[MF], bfr[NF];
#pragma unroll
            for (int m = 0; m < MF; ++m) {
                const int row = wr * (BM / 2) + m * 16 + r16;
                af[m] = *(const short8*)(bA + row * 128 + swz_rd(h, lg, row) * 16);
            }
#pragma unroll
            for (int n = 0; n < NF; ++n) {
                const int row = wc * (BN / 2) + n * 16 + r16;
                bfr[n] = *(const short8*)(bB + row * 128 + swz_rd(h, lg, row) * 16);
            }
#pragma unroll
            for (int m = 0; m < MF; ++m)
#pragma unroll
                for (int n = 0; n < NF; ++n)
                    acc[m][n] = mfma16(af[m], bfr[n], acc[m][n]);
        }
    }

#pragma unroll
    for (int m = 0; m < MF; ++m) {
#pragma unroll
        for (int n = 0; n < NF; ++n) {
#pragma unroll
            for (int j = 0; j < 4; ++j) {
                const int r = arow0 + wr * (BM / 2) + m * 16 + lg * 4 + j;
                const int c = wrow0 + wc * (BN / 2) + n * 16 + r16;
                float v = acc[m][n][j];
                if (bias) v += bias[c];
                if (relu && v < 0.f) v = 0.f;
                if (Cf) Cf[(size_t)r * ldcf + c] = v;
                if (Cb) Cb[(size_t)r * ldcb + c] = f2bf(v);
            }
        }
    }
}

template<int BM, int BN>
__global__ __launch_bounds__(256, 1) void k_mgemm(
    const unsigned short* __restrict__ A, int lda,
    const unsigned short* __restrict__ W, int ldw,
    const float* __restrict__ bias,
    float* __restrict__ Cf, int ldcf,
    unsigned short* __restrict__ Cb, int ldcb,
    int K, int relu)
{
    __shared__ __align__(16) unsigned short smA[2 * BM * 64];
    __shared__ __align__(16) unsigned short smB[2 * BN * 64];
    mgemm_body<BM, BN>(threadIdx.x, smA, smB, A, lda, blockIdx.y * BM,
                       W, ldw, blockIdx.x * BN, bias,
                       Cf, ldcf, Cb, ldcb, K, relu);
}

// ===========================================================================
// fused fp32 -> bf16 conversion (18 segments, one launch)
// ===========================================================================
struct CvtArgs {
    const float* src[18];
    unsigned short* dst[18];
    int n[18];
};

__global__ __launch_bounds__(256) void k_cvt_all(CvtArgs a)
{
    const int seg = blockIdx.y;
    const float* s = a.src[seg];
    unsigned short* d = a.dst[seg];
    const int c4 = a.n[seg] >> 2;
    for (int i = blockIdx.x * 256 + threadIdx.x; i < c4; i += gridDim.x * 256) {
        float4 v = ((const float4*)s)[i];
        ushort4 o;
        o.x = f2bf(v.x); o.y = f2bf(v.y); o.z = f2bf(v.z); o.w = f2bf(v.w);
        ((ushort4*)d)[i] = o;
    }
}

// ===========================================================================
// h_x = hxf + hxb ; h_y = hef + heb ; hcat = [h_x,h_y] bf16 ; cz[:, :H] = h_x
// ===========================================================================
__global__ __launch_bounds__(256) void k_sum_concat(
    const float* __restrict__ Hs,
    unsigned short* __restrict__ hcatb, unsigned short* __restrict__ czb)
{
    const int idx = blockIdx.x * 256 + threadIdx.x;  // B*H
    const int b = idx / H, i = idx % H;
    const float hx = Hs[idx] + Hs[(size_t)B * H + idx];
    const float hy = Hs[2 * (size_t)B * H + idx] + Hs[3 * (size_t)B * H + idx];
    const unsigned short hxb = f2bf(hx);
    hcatb[(size_t)b * (2 * H) + i] = hxb;
    hcatb[(size_t)b * (2 * H) + H + i] = f2bf(hy);
    czb[(size_t)b * (2 * H) + i] = hxb;
}

// ===========================================================================
// Fused encoder step (r17-proven) — BK=64 pipeline, 64 rows/block.
// Grid (8 hid-slices, 4 batch-quarters, njobs); 512 threads.
// ===========================================================================
struct EncP {
    const unsigned short *xb, *yb;
    unsigned short *Hsb0, *Hsb1;
    float* Hs;
    const unsigned short *wih[4], *whh[4];
    const float *bih[4], *bhh[4];
    int t, job0;
};

__global__ __launch_bounds__(512, 2) void k_enc_step(EncP p)
{
    __shared__ __align__(16) char smA[2 * 8192];    // 2 x 64x64 bf16
    __shared__ __align__(16) char smB[2 * 24576];   // 2 x 192x64 bf16
    const int job = p.job0 + blockIdx.z;
    const int h0 = blockIdx.x * 64;
    const int row0 = blockIdx.y * 64;
    const int tid = threadIdx.x;
    const int w = tid >> 6, l = tid & 63;
    const int lg = l >> 4, r16 = l & 15;
    const int wrh = w >> 2, wcg = w & 3;
    const int T = (job < 2) ? TX : TY;
    const int tt = (job & 1) ? (T - 1 - p.t) : p.t;
    const unsigned short* xsrc = (job < 2) ? p.xb : p.yb;
    const unsigned short* wihg = p.wih[job];
    const unsigned short* whhg = p.whh[job];
    const unsigned short* hin =
        ((p.t & 1) ? p.Hsb1 : p.Hsb0) + (size_t)job * B * H;
    unsigned short* hout =
        ((p.t & 1) ? p.Hsb0 : p.Hsb1) + (size_t)job * B * H;

    const int aRow = tid >> 3;
    const int aLc = swz_src(tid & 7, aRow);
    int bWr[3], bLc[3];
#pragma unroll
    for (int i = 0; i < 3; ++i) {
        const int ci = tid + i * 512;
        const int row = ci >> 3;
        const int f = row >> 4;
        bWr[i] = (f % 3) * H + h0 + (f / 3) * 16 + (row & 15);
        bLc[i] = swz_src(ci & 7, row);
    }

    auto stage = [&](int s, int buf) {
        char* dA = smA + buf * 8192;
        char* dB = smB + buf * 24576;
        if (s < 8) {
            const int k0 = s * 64;
            gload_lds16(hin + (size_t)(row0 + aRow) * H + k0 + aLc * 8,
                        dA + tid * 16);
#pragma unroll
            for (int i = 0; i < 3; ++i)
                gload_lds16(whhg + (size_t)bWr[i] * H + k0 + bLc[i] * 8,
                            dB + (tid + i * 512) * 16);
        } else {
            gload_lds16(xsrc + ((size_t)(row0 + aRow) * T + tt) * NX + aLc * 8,
                        dA + tid * 16);
#pragma unroll
            for (int i = 0; i < 3; ++i)
                gload_lds16(wihg + (size_t)bWr[i] * NX + bLc[i] * 8,
                            dB + (tid + i * 512) * 16);
        }
    };

    floatx4 am[2][3], axn[2];
#pragma unroll
    for (int m = 0; m < 2; ++m) {
        axn[m] = floatx4{0.f, 0.f, 0.f, 0.f};
#pragma unroll
        for (int g = 0; g < 3; ++g) am[m][g] = floatx4{0.f, 0.f, 0.f, 0.f};
    }

    stage(0, 0);
    for (int s = 0; s < 9; ++s) {
        __syncthreads();
        if (s + 1 < 9) stage(s + 1, (s + 1) & 1);
        const char* bA = smA + (s & 1) * 8192;
        const char* bB = smB + (s & 1) * 24576;
        const bool isx = (s == 8);
#pragma unroll
        for (int h = 0; h < 2; ++h) {
            short8 af[2], bf[3];
#pragma unroll
            for (int m = 0; m < 2; ++m) {
                const int row = wrh * 32 + m * 16 + r16;
                af[m] = *(const short8*)(bA + row * 128 + swz_rd(h, lg, row) * 16);
            }
#pragma unroll
            for (int g = 0; g < 3; ++g) {
                const int rb = wcg * 48 + g * 16 + r16;
                bf[g] = *(const short8*)(bB + rb * 128 + swz_rd(h, lg, rb) * 16);
            }
            if (!isx) {
#pragma unroll
                for (int m = 0; m < 2; ++m) {
                    am[m][0] = mfma16(af[m], bf[0], am[m][0]);
                    am[m][1] = mfma16(af[m], bf[1], am[m][1]);
                    am[m][2] = mfma16(af[m], bf[2], am[m][2]);
                }
            } else {
#pragma unroll
                for (int m = 0; m < 2; ++m) {
                    am[m][0] = mfma16(af[m], bf[0], am[m][0]);
                    am[m][1] = mfma16(af[m], bf[1], am[m][1]);
                    axn[m]   = mfma16(af[m], bf[2], axn[m]);
                }
            }
        }
    }

    // ---- gate epilogue ----
    const int u = h0 + wcg * 16 + r16;
    const float bi0 = p.bih[job][u]        + p.bhh[job][u];
    const float bi1 = p.bih[job][H + u]    + p.bhh[job][H + u];
    const float bi2 = p.bih[job][2 * H + u];
    const float bh2 = p.bhh[job][2 * H + u];
    float* HsJ = p.Hs + (size_t)job * B * H;
#pragma unroll
    for (int m = 0; m < 2; ++m) {
#pragma unroll
        for (int j = 0; j < 4; ++j) {
            const int br = row0 + wrh * 32 + m * 16 + lg * 4 + j;
            const float rr = sigmoidf_(am[m][0][j] + bi0);
            const float zz = sigmoidf_(am[m][1][j] + bi1);
            const float nn = tanhf(axn[m][j] + bi2 + rr * (am[m][2][j] + bh2));
            const float hold = HsJ[(size_t)br * H + u];
            const float hv = (1.f - zz) * nn + zz * hold;
            HsJ[(size_t)br * H + u] = hv;
            hout[(size_t)br * H + u] = f2bf(hv);
        }
    }
}

// ===========================================================================
// Decoder step kernel — batch-split to 64 rows/block, grid (8, 4).
// Phase A: out-GEMM 64x64 (K=512, BK=64 dbuf, 2x4 waves / 32x16 tiles)
// Phase B: xgd (64 x 192 gate-cols) + gates.
// mode: 0 = t==0 (y from x[:,-1]), 1 = normal, 2 = out-only (final y).
// ===========================================================================
struct DecP {
    const unsigned short* xb;
    unsigned short* hdb;
    float* hd;
    const float* hga;
    const float* constb;
    const unsigned short* dWihb;
    const float* dbhh;
    const unsigned short* doWb; const float* dob;
    const unsigned short* hm2b;
    float* outp;
    int mode, tprev;
};

__global__ __launch_bounds__(512, 2) void k_dec_step(DecP p)
{
    __shared__ __align__(16) char sA[2 * 8192];          // hm2 tiles (64x64 dbuf)
    __shared__ __align__(16) char sW[2 * 8192];          // doW tiles (64x64 dbuf)
    __shared__ __align__(16) char sX[2 * 12288];         // dWih gate tiles (old fmt)
    __shared__ __align__(16) unsigned short ytile[64 * 64];   // swizzled
    const int tid = threadIdx.x;
    const int w = tid >> 6, l = tid & 63;
    const int lg = l >> 4, r16 = l & 15;
    const int row0 = blockIdx.y * 64;
    const int h0 = blockIdx.x * 64;

    // old-format staging math for sX (32-elem rows, 4-chunk swizzle)
    const int sAr = tid >> 2;
    const int sAl = (tid & 3) ^ ((sAr >> 1) & 3);
    const int f0 = sAr >> 4;
    const int W0 = (f0 % 3) * H + h0 + (f0 / 3) * 16 + (sAr & 15);
    const int sB1r = 128 + (tid >> 2);             // tid<256 only
    const int sB1l = (tid & 3) ^ ((sB1r >> 1) & 3);
    const int f1 = sB1r >> 4;
    const int W1 = (f1 % 3) * H + h0 + (f1 / 3) * 16 + (sB1r & 15);

    // ---- issue gate-tile staging immediately (completes under phase A) ----
    if (p.mode != 2) {
#pragma unroll
        for (int kc = 0; kc < 2; ++kc) {
            gload_lds16(p.dWihb + (size_t)W0 * DIN + 2 * H + kc * 32 + sAl * 8,
                        sX + kc * 12288 + tid * 16);
            if (tid < 256)
                gload_lds16(p.dWihb + (size_t)W1 * DIN + 2 * H + kc * 32 + sB1l * 8,
                            sX + kc * 12288 + 8192 + tid * 16);
        }
    }

    if (p.mode != 0) {
        // ---- phase A: y = hm2b @ doW^T + dob (64x64, K=512), BK=64 dbuf ----
        const int aRow = tid >> 3;
        const int aLc = swz_src(tid & 7, aRow);
        auto stageA = [&](int s, int buf) {
            const int k0 = s * 64;
            gload_lds16(p.hm2b + (size_t)(row0 + aRow) * M2 + k0 + aLc * 8,
                        sA + buf * 8192 + tid * 16);
            gload_lds16(p.doWb + (size_t)aRow * M2 + k0 + aLc * 8,
                        sW + buf * 8192 + tid * 16);
        };
        const int wrA = w >> 2, wcA = w & 3;   // 2 x 4 waves, 32x16 tiles
        floatx4 acc[2];
        acc[0] = floatx4{0.f, 0.f, 0.f, 0.f};
        acc[1] = floatx4{0.f, 0.f, 0.f, 0.f};

        stageA(0, 0);
        for (int s = 0; s < 8; ++s) {
            __syncthreads();
            if (s + 1 < 8) stageA(s + 1, (s + 1) & 1);
            const char* bA = sA + (s & 1) * 8192;
            const char* bW = sW + (s & 1) * 8192;
#pragma unroll
            for (int h = 0; h < 2; ++h) {
                short8 av[2], bv;
#pragma unroll
                for (int mA = 0; mA < 2; ++mA) {
                    const int row = wrA * 32 + mA * 16 + r16;
                    av[mA] = *(const short8*)(bA + row * 128 + swz_rd(h, lg, row) * 16);
                }
                {
                    const int row = wcA * 16 + r16;
                    bv = *(const short8*)(bW + row * 128 + swz_rd(h, lg, row) * 16);
                }
#pragma unroll
                for (int mA = 0; mA < 2; ++mA)
                    acc[mA] = mfma16(av[mA], bv, acc[mA]);
            }
        }
#pragma unroll
        for (int mA = 0; mA < 2; ++mA) {
#pragma unroll
            for (int j = 0; j < 4; ++j) {
                const int rr = wrA * 32 + mA * 16 + lg * 4 + j;
                const int cc = wcA * 16 + r16;
                const float v = acc[mA][j] + p.dob[cc];
                if (blockIdx.x == 0)
                    p.outp[(size_t)(row0 + rr) * (HOR * NY)
                           + (size_t)p.tprev * NY + cc] = v;
                *(unsigned short*)((char*)ytile + rr * 128
                    + ((cc * 2) ^ ((rr & 7) << 4))) = f2bf(v);
            }
        }
    } else {
        for (int i = tid; i < 64 * 64; i += 512) {
            const int rr = i >> 6, cc = i & 63;
            const unsigned short v =
                p.xb[((size_t)(row0 + rr) * TX + TX - 1) * NX + cc];
            *(unsigned short*)((char*)ytile + rr * 128
                + ((cc * 2) ^ ((rr & 7) << 4))) = v;
        }
    }
    if (p.mode == 2) return;
    __syncthreads();   // ytile ready; sX staging drained

    // ---- phase B: xgd (64 x 192 gate-cols, K=64 from sX) + gates ----
    const int wrh = w >> 2, wcg = w & 3;
    floatx4 ag[2][3];
#pragma unroll
    for (int m = 0; m < 2; ++m)
#pragma unroll
        for (int g = 0; g < 3; ++g) ag[m][g] = floatx4{0.f, 0.f, 0.f, 0.f};
#pragma unroll
    for (int ks = 0; ks < 2; ++ks) {
        short8 ya[2], bf[3];
#pragma unroll
        for (int m = 0; m < 2; ++m) {
            const int row = wrh * 32 + m * 16 + r16;
            const int k0 = ks * 32 + lg * 8;
            ya[m] = *(const short8*)((char*)ytile + row * 128
                          + ((k0 * 2) ^ ((row & 7) << 4)));
        }
#pragma unroll
        for (int g = 0; g < 3; ++g) {
            const int rb = wcg * 48 + g * 16 + r16;
            bf[g] = *(const short8*)(sX + ks * 12288 + rb * 64
                          + ((lg ^ ((rb >> 1) & 3)) << 4));
        }
#pragma unroll
        for (int m = 0; m < 2; ++m)
#pragma unroll
            for (int g = 0; g < 3; ++g)
                ag[m][g] = mfma16(ya[m], bf[g], ag[m][g]);
    }

    const int u = h0 + wcg * 16 + r16;
    const float db0 = p.dbhh[u], db1 = p.dbhh[H + u], db2 = p.dbhh[2 * H + u];
#pragma unroll
    for (int m = 0; m < 2; ++m) {
#pragma unroll
        for (int j = 0; j < 4; ++j) {
            const int b = row0 + wrh * 32 + m * 16 + lg * 4 + j;
            const size_t g3 = (size_t)b * G3;
            const float xr = ag[m][0][j] + p.constb[g3 + u];
            const float xz = ag[m][1][j] + p.constb[g3 + H + u];
            const float xn = ag[m][2][j] + p.constb[g3 + 2 * H + u];
            const float hr = p.hga[g3 + u] + db0;
            const float hz = p.hga[g3 + H + u] + db1;
            const float hn = p.hga[g3 + 2 * H + u] + db2;
            const float rr = sigmoidf_(xr + hr);
            const float zz = sigmoidf_(xz + hz);
            const float nn = tanhf(xn + rr * hn);
            const float hold = p.hd[(size_t)b * H + u];
            const float hv = (1.f - zz) * nn + zz * hold;
            p.hd[(size_t)b * H + u] = hv;
            p.hdb[(size_t)b * H + u] = f2bf(hv);
        }
    }
}

// ===========================================================================
// kB: hga_next (96 roles, 64x64) || MLP1 (64 roles, 64x64) — 160 blocks.
// ===========================================================================
__global__ __launch_bounds__(256, 1) void k_dec_bk(
    const unsigned short* __restrict__ hdb,
    const unsigned short* __restrict__ dWhhb,
    const unsigned short* __restrict__ dmW1b, const float* __restrict__ dmb1,
    float* __restrict__ hga, unsigned short* __restrict__ hm1b)
{
    __shared__ __align__(16) unsigned short smA[2 * 64 * 64];
    __shared__ __align__(16) unsigned short smB[2 * 64 * 64];
    const int bid = blockIdx.x;
    if (bid < 96) {
        const int arow0 = (bid & 3) * 64, wrow0 = (bid >> 2) * 64;
        mgemm_body<64, 64>(threadIdx.x, smA, smB, hdb, H, arow0,
                           dWhhb, H, wrow0, nullptr,
                           hga, G3, nullptr, 0, H, 0);
    } else {
        const int b2 = bid - 96;
        const int arow0 = (b2 & 3) * 64, wrow0 = (b2 >> 2) * 64;
        mgemm_body<64, 64>(threadIdx.x, smA, smB, hdb, H, arow0,
                           dmW1b, H, wrow0, dmb1,
                           nullptr, 0, hm1b, M1, H, 1);
    }
}

// ===========================================================================
extern "C" void kernel_launch(void* const* d_in, const int* in_sizes, int n_in,
                              void* d_out, int out_size, void* d_ws, size_t ws_size,
                              hipStream_t stream)
{
    const float* x      = (const float*)d_in[0];
    const float* y      = (const float*)d_in[1];
    const float* xf_bih = (const float*)d_in[4];
    const float* xf_bhh = (const float*)d_in[5];
    const float* xb_bih = (const float*)d_in[8];
    const float* xb_bhh = (const float*)d_in[9];
    const float* ef_bih = (const float*)d_in[12];
    const float* ef_bhh = (const float*)d_in[13];
    const float* eb_bih = (const float*)d_in[16];
    const float* eb_bhh = (const float*)d_in[17];
    const float* em_b1  = (const float*)d_in[19];
    const float* em_b2  = (const float*)d_in[21];
    const float* eo_b   = (const float*)d_in[23];
    const float* d_bih  = (const float*)d_in[26];
    const float* d_bhh  = (const float*)d_in[27];
    const float* dm_b1  = (const float*)d_in[29];
    const float* dm_b2  = (const float*)d_in[31];
    const float* do_b   = (const float*)d_in[33];
    float* out = (float*)d_out;

    // ---- workspace carve-up ----
    float* fp = (float*)d_ws;
    float* Hs     = fp; fp += 4 * (size_t)B * H;
    float* hd     = fp; fp += (size_t)B * H;
    float* hga    = fp; fp += (size_t)B * G3;
    float* constb = fp; fp += (size_t)B * G3;

    unsigned short* up = (unsigned short*)fp;
    unsigned short* xb16  = up; up += (size_t)B * TX * NX;
    unsigned short* yb16  = up; up += (size_t)B * TY * NY;
    unsigned short* Hsb0  = up; up += 4 * (size_t)B * H;
    unsigned short* Hsb1  = up; up += 4 * (size_t)B * H;
    unsigned short* hdb   = up; up += (size_t)B * H;
    unsigned short* hcatb = up; up += (size_t)B * 2 * H;
    unsigned short* czb   = up; up += (size_t)B * 2 * H;
    unsigned short* h1b   = up; up += (size_t)B * M1;
    unsigned short* h2b   = up; up += (size_t)B * M2;
    unsigned short* hm1b  = up; up += (size_t)B * M1;
    unsigned short* hm2b  = up; up += (size_t)B * M2;

    const int    widx[16] = {2, 3, 6, 7, 10, 11, 14, 15, 18, 20, 22, 24, 25, 28, 30, 32};
    const size_t wsz[16]  = {
        (size_t)G3 * NX, (size_t)G3 * H, (size_t)G3 * NX, (size_t)G3 * H,
        (size_t)G3 * NX, (size_t)G3 * H, (size_t)G3 * NX, (size_t)G3 * H,
        (size_t)M1 * 2 * H, (size_t)M2 * M1, (size_t)H * M2,
        (size_t)G3 * DIN, (size_t)G3 * H, (size_t)M1 * H, (size_t)M2 * M1,
        (size_t)NY * M2};
    unsigned short* wb[16];
    for (int i = 0; i < 16; ++i) { wb[i] = up; up += wsz[i]; }

    // ---- conversions + state init ----
    CvtArgs ca;
    for (int i = 0; i < 16; ++i) {
        ca.src[i] = (const float*)d_in[widx[i]];
        ca.dst[i] = wb[i];
        ca.n[i]   = (int)wsz[i];
    }
    ca.src[16] = x; ca.dst[16] = xb16; ca.n[16] = B * TX * NX;
    ca.src[17] = y; ca.dst[17] = yb16; ca.n[17] = B * TY * NY;
    k_cvt_all<<<dim3(64, 18), 256, 0, stream>>>(ca);

    hipMemsetAsync(Hs,   0, sizeof(float) * 4 * (size_t)B * H, stream);
    hipMemsetAsync(Hsb0, 0, sizeof(unsigned short) * 4 * (size_t)B * H, stream);
    hipMemsetAsync(hd,   0, sizeof(float) * (size_t)B * H, stream);
    hipMemsetAsync(hga,  0, sizeof(float) * (size_t)B * G3, stream);

    // ---- encoder: 1 fused launch per step ----
    EncP ep;
    ep.xb = xb16; ep.yb = yb16; ep.Hsb0 = Hsb0; ep.Hsb1 = Hsb1; ep.Hs = Hs;
    ep.wih[0] = wb[0]; ep.whh[0] = wb[1];
    ep.wih[1] = wb[2]; ep.whh[1] = wb[3];
    ep.wih[2] = wb[4]; ep.whh[2] = wb[5];
    ep.wih[3] = wb[6]; ep.whh[3] = wb[7];
    ep.bih[0] = xf_bih; ep.bhh[0] = xf_bhh;
    ep.bih[1] = xb_bih; ep.bhh[1] = xb_bhh;
    ep.bih[2] = ef_bih; ep.bhh[2] = ef_bhh;
    ep.bih[3] = eb_bih; ep.bhh[3] = eb_bhh;
    for (int t = 0; t < TY; ++t) {
        ep.t = t;
        ep.job0 = (t < TX) ? 0 : 2;
        const int nj = (t < TX) ? 4 : 2;
        k_enc_step<<<dim3(8, 4, nj), 512, 0, stream>>>(ep);
    }

    // ---- bottleneck MLP ----
    k_sum_concat<<<B * H / 256, 256, 0, stream>>>(Hs, hcatb, czb);
    k_mgemm<128, 128><<<dim3(M1 / 128, B / 128), 256, 0, stream>>>(
        hcatb, 2 * H, wb[8], 2 * H, em_b1, nullptr, 0, h1b, M1, 2 * H, 1);
    k_mgemm<128, 128><<<dim3(M2 / 128, B / 128), 256, 0, stream>>>(
        h1b, M1, wb[9], M1, em_b2, nullptr, 0, h2b, M2, M1, 1);
    k_mgemm<128, 128><<<dim3(H / 128, B / 128), 256, 0, stream>>>(
        h2b, M2, wb[10], M2, eo_b, nullptr, 0, czb + H, 2 * H, M2, 0);
    k_mgemm<128, 128><<<dim3(G3 / 128, B / 128), 256, 0, stream>>>(
        czb, 2 * H, wb[11], DIN, d_bih, constb, G3, nullptr, 0, 2 * H, 0);

    // ---- decoder: 3 launches per step ----
    DecP dp;
    dp.xb = xb16; dp.hdb = hdb; dp.hd = hd; dp.hga = hga; dp.constb = constb;
    dp.dWihb = wb[11]; dp.dbhh = d_bhh;
    dp.doWb = wb[15]; dp.dob = do_b;
    dp.hm2b = hm2b; dp.outp = out;
    for (int t = 0; t < HOR; ++t) {
        dp.mode = (t == 0) ? 0 : 1;
        dp.tprev = t - 1;
        k_dec_step<<<dim3(8, 4), 512, 0, stream>>>(dp);
        k_dec_bk<<<160, 256, 0, stream>>>(hdb, wb[12], wb[13], dm_b1, hga, hm1b);
        k_mgemm<64, 64><<<dim3(M2 / 64, B / 64), 256, 0, stream>>>(
            hm1b, M1, wb[14], M1, dm_b2, nullptr, 0, hm2b, M2, M1, 1);
    }
    dp.mode = 2;
    dp.tprev = HOR - 1;
    k_dec_step<<<dim3(1, 4), 512, 0, stream>>>(dp);
}

// Round 19
// 2945.052 us; speedup vs baseline: 1.8349x; 1.1900x over previous
//
#include <hip/hip_runtime.h>
#include <math.h>

#define B   256
#define TX  50
#define TY  100
#define NX  64
#define NY  64
#define H   512
#define HOR 60
#define M1  1024
#define M2  512
#define G3  (3*H)        // 1536
#define DIN (2*H + NY)   // 1088

typedef __attribute__((ext_vector_type(8))) short short8;
typedef __attribute__((ext_vector_type(4))) float floatx4;

__device__ __forceinline__ unsigned short f2bf(float f) {
    union { float f; unsigned u; } v; v.f = f;
    return (unsigned short)((v.u + 0x7FFFu + ((v.u >> 16) & 1u)) >> 16);
}

__device__ __forceinline__ float sigmoidf_(float v) {
    return 1.f / (1.f + __expf(-v));
}

__device__ __forceinline__ short8 ld8(const unsigned short* p) {
    return *(const short8*)p;
}

__device__ __forceinline__ floatx4 mfma16(short8 a, short8 b, floatx4 c) {
    return __builtin_amdgcn_mfma_f32_16x16x32_bf16(a, b, c, 0, 0, 0);
}

__device__ __forceinline__ void gload_lds16(const void* g, void* lds) {
    __builtin_amdgcn_global_load_lds(
        (const __attribute__((address_space(1))) void*)g,
        (__attribute__((address_space(3))) void*)lds, 16, 0, 0);
}

// BK=64 row layout: [row][8 chunks of 16B], row stride 128B.
// Swizzle (2-way bank aliasing): involution per row.
__device__ __forceinline__ int swz_src(int pc8, int row) {
    return (((pc8 >> 2) ^ (row & 1)) << 2) | ((pc8 & 3) ^ ((row >> 1) & 3));
}
__device__ __forceinline__ int swz_rd(int h, int lg, int row) {
    return (((h ^ (row & 1)) & 1) << 2) | ((lg ^ ((row >> 1) & 3)) & 3);
}

// ===========================================================================
// BMxBN MFMA GEMM body, 256 threads — BK=64 double-buffered K-pipeline.
// ===========================================================================
template<int BM, int BN>
__device__ __forceinline__ void mgemm_body(
    int tid, unsigned short* smA, unsigned short* smB,
    const unsigned short* __restrict__ A, int lda, int arow0,
    const unsigned short* __restrict__ W, int ldw, int wrow0,
    const float* __restrict__ bias,
    float* __restrict__ Cf, int ldcf,
    unsigned short* __restrict__ Cb, int ldcb,
    int K, int relu)
{
    constexpr int MF = BM / 32;
    constexpr int NF = BN / 32;
    const int w  = tid >> 6, l = tid & 63;
    const int wr = w >> 1, wc = w & 1;
    const int lg = l >> 4, r16 = l & 15;

    auto stage = [&](int k0, int buf) {
#pragma unroll
        for (int i = 0; i < BM / 32; ++i) {
            const int ci = tid + i * 256;
            const int row = ci >> 3, pc = ci & 7;
            const int lc = swz_src(pc, row);
            gload_lds16(A + (size_t)(arow0 + row) * lda + k0 + lc * 8,
                        (char*)smA + buf * (BM * 128) + ci * 16);
        }
#pragma unroll
        for (int i = 0; i < BN / 32; ++i) {
            const int ci = tid + i * 256;
            const int row = ci >> 3, pc = ci & 7;
            const int lc = swz_src(pc, row);
            gload_lds16(W + (size_t)(wrow0 + row) * ldw + k0 + lc * 8,
                        (char*)smB + buf * (BN * 128) + ci * 16);
        }
    };

    floatx4 acc[MF][NF];
#pragma unroll
    for (int m = 0; m < MF; ++m)
#pragma unroll
        for (int n = 0; n < NF; ++n) acc[m][n] = floatx4{0.f, 0.f, 0.f, 0.f};

    const int nk = K >> 6;
    stage(0, 0);
    for (int s = 0; s < nk; ++s) {
        __syncthreads();
        if (s + 1 < nk) stage((s + 1) << 6, (s + 1) & 1);
        const char* bA = (char*)smA + (s & 1) * (BM * 128);
        const char* bB = (char*)smB + (s & 1) * (BN * 128);
#pragma unroll
        for (int h = 0; h < 2; ++h) {
            short8 af[MF], bfr[NF];
#pragma unroll
            for (int m = 0; m < MF; ++m) {
                const int row = wr * (BM / 2) + m * 16 + r16;
                af[m] = *(const short8*)(bA + row * 128 + swz_rd(h, lg, row) * 16);
            }
#pragma unroll
            for (int n = 0; n < NF; ++n) {
                const int row = wc * (BN / 2) + n * 16 + r16;
                bfr[n] = *(const short8*)(bB + row * 128 + swz_rd(h, lg, row) * 16);
            }
#pragma unroll
            for (int m = 0; m < MF; ++m)
#pragma unroll
                for (int n = 0; n < NF; ++n)
                    acc[m][n] = mfma16(af[m], bfr[n], acc[m][n]);
        }
    }

#pragma unroll
    for (int m = 0; m < MF; ++m) {
#pragma unroll
        for (int n = 0; n < NF; ++n) {
#pragma unroll
            for (int j = 0; j < 4; ++j) {
                const int r = arow0 + wr * (BM / 2) + m * 16 + lg * 4 + j;
                const int c = wrow0 + wc * (BN / 2) + n * 16 + r16;
                float v = acc[m][n][j];
                if (bias) v += bias[c];
                if (relu && v < 0.f) v = 0.f;
                if (Cf) Cf[(size_t)r * ldcf + c] = v;
                if (Cb) Cb[(size_t)r * ldcb + c] = f2bf(v);
            }
        }
    }
}

template<int BM, int BN>
__global__ __launch_bounds__(256, 1) void k_mgemm(
    const unsigned short* __restrict__ A, int lda,
    const unsigned short* __restrict__ W, int ldw,
    const float* __restrict__ bias,
    float* __restrict__ Cf, int ldcf,
    unsigned short* __restrict__ Cb, int ldcb,
    int K, int relu)
{
    __shared__ __align__(16) unsigned short smA[2 * BM * 64];
    __shared__ __align__(16) unsigned short smB[2 * BN * 64];
    mgemm_body<BM, BN>(threadIdx.x, smA, smB, A, lda, blockIdx.y * BM,
                       W, ldw, blockIdx.x * BN, bias,
                       Cf, ldcf, Cb, ldcb, K, relu);
}

// ===========================================================================
// fused fp32 -> bf16 conversion (18 segments, one launch)
// ===========================================================================
struct CvtArgs {
    const float* src[18];
    unsigned short* dst[18];
    int n[18];
};

__global__ __launch_bounds__(256) void k_cvt_all(CvtArgs a)
{
    const int seg = blockIdx.y;
    const float* s = a.src[seg];
    unsigned short* d = a.dst[seg];
    const int c4 = a.n[seg] >> 2;
    for (int i = blockIdx.x * 256 + threadIdx.x; i < c4; i += gridDim.x * 256) {
        float4 v = ((const float4*)s)[i];
        ushort4 o;
        o.x = f2bf(v.x); o.y = f2bf(v.y); o.z = f2bf(v.z); o.w = f2bf(v.w);
        ((ushort4*)d)[i] = o;
    }
}

// ===========================================================================
// h_x = hxf + hxb ; h_y = hef + heb ; hcat = [h_x,h_y] bf16 ; cz[:, :H] = h_x
// ===========================================================================
__global__ __launch_bounds__(256) void k_sum_concat(
    const float* __restrict__ Hs,
    unsigned short* __restrict__ hcatb, unsigned short* __restrict__ czb)
{
    const int idx = blockIdx.x * 256 + threadIdx.x;  // B*H
    const int b = idx / H, i = idx % H;
    const float hx = Hs[idx] + Hs[(size_t)B * H + idx];
    const float hy = Hs[2 * (size_t)B * H + idx] + Hs[3 * (size_t)B * H + idx];
    const unsigned short hxb = f2bf(hx);
    hcatb[(size_t)b * (2 * H) + i] = hxb;
    hcatb[(size_t)b * (2 * H) + H + i] = f2bf(hy);
    czb[(size_t)b * (2 * H) + i] = hxb;
}

// ===========================================================================
// Fused encoder step — BK=64 pipeline, 16 hid-slices x 4 batch-quarters.
// Grid (16, 4, njobs); 512 threads = 8 waves (4 row-groups x 2 col-groups).
// Per block: 64 rows x 32 hidden (96 gate cols). LDS: A 2x8KB + B 2x12KB.
// ===========================================================================
struct EncP {
    const unsigned short *xb, *yb;
    unsigned short *Hsb0, *Hsb1;
    float* Hs;
    const unsigned short *wih[4], *whh[4];
    const float *bih[4], *bhh[4];
    int t, job0;
};

__global__ __launch_bounds__(512, 2) void k_enc_step(EncP p)
{
    __shared__ __align__(16) char smA[2 * 8192];    // 2 x 64x64 bf16
    __shared__ __align__(16) char smB[2 * 12288];   // 2 x 96x64 bf16
    const int job = p.job0 + blockIdx.z;
    const int h0 = blockIdx.x * 32;
    const int row0 = blockIdx.y * 64;
    const int tid = threadIdx.x;
    const int w = tid >> 6, l = tid & 63;
    const int lg = l >> 4, r16 = l & 15;
    const int wrh = w >> 1, wcg = w & 1;   // 4 row-groups of 16, 2 col-groups of 48
    const int T = (job < 2) ? TX : TY;
    const int tt = (job & 1) ? (T - 1 - p.t) : p.t;
    const unsigned short* xsrc = (job < 2) ? p.xb : p.yb;
    const unsigned short* wihg = p.wih[job];
    const unsigned short* whhg = p.whh[job];
    const unsigned short* hin =
        ((p.t & 1) ? p.Hsb1 : p.Hsb0) + (size_t)job * B * H;
    unsigned short* hout =
        ((p.t & 1) ? p.Hsb0 : p.Hsb1) + (size_t)job * B * H;

    // A staging: 64 rows x 8 chunks = 512 (1/thread)
    const int aRow = tid >> 3;
    const int aLc = swz_src(tid & 7, aRow);
    // B staging: 96 rows x 8 chunks = 768 (1/thread + tid<256 second)
    const int b0row = tid >> 3;
    const int b0f = b0row >> 4;
    const int bWr0 = (b0f % 3) * H + h0 + (b0f / 3) * 16 + (b0row & 15);
    const int bLc0 = swz_src(tid & 7, b0row);
    const int c1 = 512 + tid;                    // tid<256 only
    const int b1row = c1 >> 3;
    const int b1f = b1row >> 4;
    const int bWr1 = (b1f % 3) * H + h0 + (b1f / 3) * 16 + (b1row & 15);
    const int bLc1 = swz_src(c1 & 7, b1row);

    auto stage = [&](int s, int buf) {
        char* dA = smA + buf * 8192;
        char* dB = smB + buf * 12288;
        if (s < 8) {
            const int k0 = s * 64;
            gload_lds16(hin + (size_t)(row0 + aRow) * H + k0 + aLc * 8,
                        dA + tid * 16);
            gload_lds16(whhg + (size_t)bWr0 * H + k0 + bLc0 * 8,
                        dB + tid * 16);
            if (tid < 256)
                gload_lds16(whhg + (size_t)bWr1 * H + k0 + bLc1 * 8,
                            dB + c1 * 16);
        } else {
            gload_lds16(xsrc + ((size_t)(row0 + aRow) * T + tt) * NX + aLc * 8,
                        dA + tid * 16);
            gload_lds16(wihg + (size_t)bWr0 * NX + bLc0 * 8,
                        dB + tid * 16);
            if (tid < 256)
                gload_lds16(wihg + (size_t)bWr1 * NX + bLc1 * 8,
                            dB + c1 * 16);
        }
    };

    floatx4 am[3], axn;
    axn = floatx4{0.f, 0.f, 0.f, 0.f};
#pragma unroll
    for (int g = 0; g < 3; ++g) am[g] = floatx4{0.f, 0.f, 0.f, 0.f};

    stage(0, 0);
    for (int s = 0; s < 9; ++s) {
        __syncthreads();
        if (s + 1 < 9) stage(s + 1, (s + 1) & 1);
        const char* bA = smA + (s & 1) * 8192;
        const char* bB = smB + (s & 1) * 12288;
        const bool isx = (s == 8);
#pragma unroll
        for (int h = 0; h < 2; ++h) {
            short8 af, bf[3];
            {
                const int row = wrh * 16 + r16;
                af = *(const short8*)(bA + row * 128 + swz_rd(h, lg, row) * 16);
            }
#pragma unroll
            for (int g = 0; g < 3; ++g) {
                const int rb = wcg * 48 + g * 16 + r16;
                bf[g] = *(const short8*)(bB + rb * 128 + swz_rd(h, lg, rb) * 16);
            }
            if (!isx) {
                am[0] = mfma16(af, bf[0], am[0]);
                am[1] = mfma16(af, bf[1], am[1]);
                am[2] = mfma16(af, bf[2], am[2]);
            } else {
                am[0] = mfma16(af, bf[0], am[0]);
                am[1] = mfma16(af, bf[1], am[1]);
                axn   = mfma16(af, bf[2], axn);
            }
        }
    }

    // ---- gate epilogue ----
    const int u = h0 + wcg * 16 + r16;
    const float bi0 = p.bih[job][u]        + p.bhh[job][u];
    const float bi1 = p.bih[job][H + u]    + p.bhh[job][H + u];
    const float bi2 = p.bih[job][2 * H + u];
    const float bh2 = p.bhh[job][2 * H + u];
    float* HsJ = p.Hs + (size_t)job * B * H;
#pragma unroll
    for (int j = 0; j < 4; ++j) {
        const int br = row0 + wrh * 16 + lg * 4 + j;
        const float rr = sigmoidf_(am[0][j] + bi0);
        const float zz = sigmoidf_(am[1][j] + bi1);
        const float nn = tanhf(axn[j] + bi2 + rr * (am[2][j] + bh2));
        const float hold = HsJ[(size_t)br * H + u];
        const float hv = (1.f - zz) * nn + zz * hold;
        HsJ[(size_t)br * H + u] = hv;
        hout[(size_t)br * H + u] = f2bf(hv);
    }
}

// ===========================================================================
// Decoder step kernel — 32 rows/block, grid (8, 8).
// Phase A: out-GEMM 32x64 (K=512, BK=64 dbuf, 2x4 waves / 16x16 tiles)
// Phase B: xgd (32 x 192 gate-cols) + gates.
// mode: 0 = t==0 (y from x[:,-1]), 1 = normal, 2 = out-only (final y).
// ===========================================================================
struct DecP {
    const unsigned short* xb;
    unsigned short* hdb;
    float* hd;
    const float* hga;
    const float* constb;
    const unsigned short* dWihb;
    const float* dbhh;
    const unsigned short* doWb; const float* dob;
    const unsigned short* hm2b;
    float* outp;
    int mode, tprev;
};

__global__ __launch_bounds__(512, 2) void k_dec_step(DecP p)
{
    __shared__ __align__(16) char sA[2 * 4096];          // hm2 tiles (32x64 dbuf)
    __shared__ __align__(16) char sW[2 * 8192];          // doW tiles (64x64 dbuf)
    __shared__ __align__(16) char sX[2 * 12288];         // dWih gate tiles (old fmt)
    __shared__ __align__(16) unsigned short ytile[32 * 64];   // swizzled
    const int tid = threadIdx.x;
    const int w = tid >> 6, l = tid & 63;
    const int lg = l >> 4, r16 = l & 15;
    const int row0 = blockIdx.y * 32;
    const int h0 = blockIdx.x * 64;

    // old-format staging math for sX (32-elem rows, 4-chunk swizzle)
    const int sAr = tid >> 2;
    const int sAl = (tid & 3) ^ ((sAr >> 1) & 3);
    const int f0 = sAr >> 4;
    const int W0 = (f0 % 3) * H + h0 + (f0 / 3) * 16 + (sAr & 15);
    const int sB1r = 128 + (tid >> 2);             // tid<256 only
    const int sB1l = (tid & 3) ^ ((sB1r >> 1) & 3);
    const int f1 = sB1r >> 4;
    const int W1 = (f1 % 3) * H + h0 + (f1 / 3) * 16 + (sB1r & 15);

    // ---- issue gate-tile staging immediately (completes under phase A) ----
    if (p.mode != 2) {
#pragma unroll
        for (int kc = 0; kc < 2; ++kc) {
            gload_lds16(p.dWihb + (size_t)W0 * DIN + 2 * H + kc * 32 + sAl * 8,
                        sX + kc * 12288 + tid * 16);
            if (tid < 256)
                gload_lds16(p.dWihb + (size_t)W1 * DIN + 2 * H + kc * 32 + sB1l * 8,
                            sX + kc * 12288 + 8192 + tid * 16);
        }
    }

    if (p.mode != 0) {
        // ---- phase A: y = hm2b @ doW^T + dob (32x64, K=512), BK=64 dbuf ----
        const int aRow = tid >> 3;                 // tid<256: 32 rows x 8 chunks
        const int aLc = swz_src(tid & 7, aRow);
        const int wRow = tid >> 3;                 // full 512: 64 rows x 8
        const int wLc = swz_src(tid & 7, wRow);
        auto stageA = [&](int s, int buf) {
            const int k0 = s * 64;
            if (tid < 256)
                gload_lds16(p.hm2b + (size_t)(row0 + aRow) * M2 + k0 + aLc * 8,
                            sA + buf * 4096 + tid * 16);
            gload_lds16(p.doWb + (size_t)wRow * M2 + k0 + wLc * 8,
                        sW + buf * 8192 + tid * 16);
        };
        const int wrA = w >> 2, wcA = w & 3;   // 2 x 4 waves, 16x16 tiles
        floatx4 acc = floatx4{0.f, 0.f, 0.f, 0.f};

        stageA(0, 0);
        for (int s = 0; s < 8; ++s) {
            __syncthreads();
            if (s + 1 < 8) stageA(s + 1, (s + 1) & 1);
            const char* bA = sA + (s & 1) * 4096;
            const char* bW = sW + (s & 1) * 8192;
#pragma unroll
            for (int h = 0; h < 2; ++h) {
                short8 av, bv;
                {
                    const int row = wrA * 16 + r16;
                    av = *(const short8*)(bA + row * 128 + swz_rd(h, lg, row) * 16);
                }
                {
                    const int row = wcA * 16 + r16;
                    bv = *(const short8*)(bW + row * 128 + swz_rd(h, lg, row) * 16);
                }
                acc = mfma16(av, bv, acc);
            }
        }
#pragma unroll
        for (int j = 0; j < 4; ++j) {
            const int rr = wrA * 16 + lg * 4 + j;
            const int cc = wcA * 16 + r16;
            const float v = acc[j] + p.dob[cc];
            if (blockIdx.x == 0)
                p.outp[(size_t)(row0 + rr) * (HOR * NY)
                       + (size_t)p.tprev * NY + cc] = v;
            *(unsigned short*)((char*)ytile + rr * 128
                + ((cc * 2) ^ ((rr & 7) << 4))) = f2bf(v);
        }
    } else {
        for (int i = tid; i < 32 * 64; i += 512) {
            const int rr = i >> 6, cc = i & 63;
            const unsigned short v =
                p.xb[((size_t)(row0 + rr) * TX + TX - 1) * NX + cc];
            *(unsigned short*)((char*)ytile + rr * 128
                + ((cc * 2) ^ ((rr & 7) << 4))) = v;
        }
    }
    if (p.mode == 2) return;
    __syncthreads();   // ytile ready; sX staging drained

    // ---- phase B: xgd (32 x 192 gate-cols, K=64 from sX) + gates ----
    const int wrh = w >> 2, wcg = w & 3;   // 2 row-groups of 16, 4 col-groups of 48
    floatx4 ag[3];
#pragma unroll
    for (int g = 0; g < 3; ++g) ag[g] = floatx4{0.f, 0.f, 0.f, 0.f};
#pragma unroll
    for (int ks = 0; ks < 2; ++ks) {
        short8 ya, bf[3];
        {
            const int row = wrh * 16 + r16;
            const int k0 = ks * 32 + lg * 8;
            ya = *(const short8*)((char*)ytile + row * 128
                          + ((k0 * 2) ^ ((row & 7) << 4)));
        }
#pragma unroll
        for (int g = 0; g < 3; ++g) {
            const int rb = wcg * 48 + g * 16 + r16;
            bf[g] = *(const short8*)(sX + ks * 12288 + rb * 64
                          + ((lg ^ ((rb >> 1) & 3)) << 4));
        }
#pragma unroll
        for (int g = 0; g < 3; ++g)
            ag[g] = mfma16(ya, bf[g], ag[g]);
    }

    const int u = h0 + wcg * 16 + r16;
    const float db0 = p.dbhh[u], db1 = p.dbhh[H + u], db2 = p.dbhh[2 * H + u];
#pragma unroll
    for (int j = 0; j < 4; ++j) {
        const int b = row0 + wrh * 16 + lg * 4 + j;
        const size_t g3 = (size_t)b * G3;
        const float xr = ag[0][j] + p.constb[g3 + u];
        const float xz = ag[1][j] + p.constb[g3 + H + u];
        const float xn = ag[2][j] + p.constb[g3 + 2 * H + u];
        const float hr = p.hga[g3 + u] + db0;
        const float hz = p.hga[g3 + H + u] + db1;
        const float hn = p.hga[g3 + 2 * H + u] + db2;
        const float rr = sigmoidf_(xr + hr);
        const float zz = sigmoidf_(xz + hz);
        const float nn = tanhf(xn + rr * hn);
        const float hold = p.hd[(size_t)b * H + u];
        const float hv = (1.f - zz) * nn + zz * hold;
        p.hd[(size_t)b * H + u] = hv;
        p.hdb[(size_t)b * H + u] = f2bf(hv);
    }
}

// ===========================================================================
// kB: hga_next (96 roles, 64x64) || MLP1 (64 roles, 64x64) — 160 blocks.
// ===========================================================================
__global__ __launch_bounds__(256, 1) void k_dec_bk(
    const unsigned short* __restrict__ hdb,
    const unsigned short* __restrict__ dWhhb,
    const unsigned short* __restrict__ dmW1b, const float* __restrict__ dmb1,
    float* __restrict__ hga, unsigned short* __restrict__ hm1b)
{
    __shared__ __align__(16) unsigned short smA[2 * 64 * 64];
    __shared__ __align__(16) unsigned short smB[2 * 64 * 64];
    const int bid = blockIdx.x;
    if (bid < 96) {
        const int arow0 = (bid & 3) * 64, wrow0 = (bid >> 2) * 64;
        mgemm_body<64, 64>(threadIdx.x, smA, smB, hdb, H, arow0,
                           dWhhb, H, wrow0, nullptr,
                           hga, G3, nullptr, 0, H, 0);
    } else {
        const int b2 = bid - 96;
        const int arow0 = (b2 & 3) * 64, wrow0 = (b2 >> 2) * 64;
        mgemm_body<64, 64>(threadIdx.x, smA, smB, hdb, H, arow0,
                           dmW1b, H, wrow0, dmb1,
                           nullptr, 0, hm1b, M1, H, 1);
    }
}

// ===========================================================================
extern "C" void kernel_launch(void* const* d_in, const int* in_sizes, int n_in,
                              void* d_out, int out_size, void* d_ws, size_t ws_size,
                              hipStream_t stream)
{
    const float* x      = (const float*)d_in[0];
    const float* y      = (const float*)d_in[1];
    const float* xf_bih = (const float*)d_in[4];
    const float* xf_bhh = (const float*)d_in[5];
    const float* xb_bih = (const float*)d_in[8];
    const float* xb_bhh = (const float*)d_in[9];
    const float* ef_bih = (const float*)d_in[12];
    const float* ef_bhh = (const float*)d_in[13];
    const float* eb_bih = (const float*)d_in[16];
    const float* eb_bhh = (const float*)d_in[17];
    const float* em_b1  = (const float*)d_in[19];
    const float* em_b2  = (const float*)d_in[21];
    const float* eo_b   = (const float*)d_in[23];
    const float* d_bih  = (const float*)d_in[26];
    const float* d_bhh  = (const float*)d_in[27];
    const float* dm_b1  = (const float*)d_in[29];
    const float* dm_b2  = (const float*)d_in[31];
    const float* do_b   = (const float*)d_in[33];
    float* out = (float*)d_out;

    // ---- workspace carve-up ----
    float* fp = (float*)d_ws;
    float* Hs     = fp; fp += 4 * (size_t)B * H;
    float* hd     = fp; fp += (size_t)B * H;
    float* hga    = fp; fp += (size_t)B * G3;
    float* constb = fp; fp += (size_t)B * G3;

    unsigned short* up = (unsigned short*)fp;
    unsigned short* xb16  = up; up += (size_t)B * TX * NX;
    unsigned short* yb16  = up; up += (size_t)B * TY * NY;
    unsigned short* Hsb0  = up; up += 4 * (size_t)B * H;
    unsigned short* Hsb1  = up; up += 4 * (size_t)B * H;
    unsigned short* hdb   = up; up += (size_t)B * H;
    unsigned short* hcatb = up; up += (size_t)B * 2 * H;
    unsigned short* czb   = up; up += (size_t)B * 2 * H;
    unsigned short* h1b   = up; up += (size_t)B * M1;
    unsigned short* h2b   = up; up += (size_t)B * M2;
    unsigned short* hm1b  = up; up += (size_t)B * M1;
    unsigned short* hm2b  = up; up += (size_t)B * M2;

    const int    widx[16] = {2, 3, 6, 7, 10, 11, 14, 15, 18, 20, 22, 24, 25, 28, 30, 32};
    const size_t wsz[16]  = {
        (size_t)G3 * NX, (size_t)G3 * H, (size_t)G3 * NX, (size_t)G3 * H,
        (size_t)G3 * NX, (size_t)G3 * H, (size_t)G3 * NX, (size_t)G3 * H,
        (size_t)M1 * 2 * H, (size_t)M2 * M1, (size_t)H * M2,
        (size_t)G3 * DIN, (size_t)G3 * H, (size_t)M1 * H, (size_t)M2 * M1,
        (size_t)NY * M2};
    unsigned short* wb[16];
    for (int i = 0; i < 16; ++i) { wb[i] = up; up += wsz[i]; }

    // ---- conversions + state init ----
    CvtArgs ca;
    for (int i = 0; i < 16; ++i) {
        ca.src[i] = (const float*)d_in[widx[i]];
        ca.dst[i] = wb[i];
        ca.n[i]   = (int)wsz[i];
    }
    ca.src[16] = x; ca.dst[16] = xb16; ca.n[16] = B * TX * NX;
    ca.src[17] = y; ca.dst[17] = yb16; ca.n[17] = B * TY * NY;
    k_cvt_all<<<dim3(64, 18), 256, 0, stream>>>(ca);

    hipMemsetAsync(Hs,   0, sizeof(float) * 4 * (size_t)B * H, stream);
    hipMemsetAsync(Hsb0, 0, sizeof(unsigned short) * 4 * (size_t)B * H, stream);
    hipMemsetAsync(hd,   0, sizeof(float) * (size_t)B * H, stream);
    hipMemsetAsync(hga,  0, sizeof(float) * (size_t)B * G3, stream);

    // ---- encoder: 1 fused launch per step ----
    EncP ep;
    ep.xb = xb16; ep.yb = yb16; ep.Hsb0 = Hsb0; ep.Hsb1 = Hsb1; ep.Hs = Hs;
    ep.wih[0] = wb[0]; ep.whh[0] = wb[1];
    ep.wih[1] = wb[2]; ep.whh[1] = wb[3];
    ep.wih[2] = wb[4]; ep.whh[2] = wb[5];
    ep.wih[3] = wb[6]; ep.whh[3] = wb[7];
    ep.bih[0] = xf_bih; ep.bhh[0] = xf_bhh;
    ep.bih[1] = xb_bih; ep.bhh[1] = xb_bhh;
    ep.bih[2] = ef_bih; ep.bhh[2] = ef_bhh;
    ep.bih[3] = eb_bih; ep.bhh[3] = eb_bhh;
    for (int t = 0; t < TY; ++t) {
        ep.t = t;
        ep.job0 = (t < TX) ? 0 : 2;
        const int nj = (t < TX) ? 4 : 2;
        k_enc_step<<<dim3(16, 4, nj), 512, 0, stream>>>(ep);
    }

    // ---- bottleneck MLP ----
    k_sum_concat<<<B * H / 256, 256, 0, stream>>>(Hs, hcatb, czb);
    k_mgemm<128, 128><<<dim3(M1 / 128, B / 128), 256, 0, stream>>>(
        hcatb, 2 * H, wb[8], 2 * H, em_b1, nullptr, 0, h1b, M1, 2 * H, 1);
    k_mgemm<128, 128><<<dim3(M2 / 128, B / 128), 256, 0, stream>>>(
        h1b, M1, wb[9], M1, em_b2, nullptr, 0, h2b, M2, M1, 1);
    k_mgemm<128, 128><<<dim3(H / 128, B / 128), 256, 0, stream>>>(
        h2b, M2, wb[10], M2, eo_b, nullptr, 0, czb + H, 2 * H, M2, 0);
    k_mgemm<128, 128><<<dim3(G3 / 128, B / 128), 256, 0, stream>>>(
        czb, 2 * H, wb[11], DIN, d_bih, constb, G3, nullptr, 0, 2 * H, 0);

    // ---- decoder: 3 launches per step ----
    DecP dp;
    dp.xb = xb16; dp.hdb = hdb; dp.hd = hd; dp.hga = hga; dp.constb = constb;
    dp.dWihb = wb[11]; dp.dbhh = d_bhh;
    dp.doWb = wb[15]; dp.dob = do_b;
    dp.hm2b = hm2b; dp.outp = out;
    for (int t = 0; t < HOR; ++t) {
        dp.mode = (t == 0) ? 0 : 1;
        dp.tprev = t - 1;
        k_dec_step<<<dim3(8, 8), 512, 0, stream>>>(dp);
        k_dec_bk<<<160, 256, 0, stream>>>(hdb, wb[12], wb[13], dm_b1, hga, hm1b);
        k_mgemm<64, 32><<<dim3(M2 / 32, B / 64), 256, 0, stream>>>(
            hm1b, M1, wb[14], M1, dm_b2, nullptr, 0, hm2b, M2, M1, 1);
    }
    dp.mode = 2;
    dp.tprev = HOR - 1;
    k_dec_step<<<dim3(1, 8), 512, 0, stream>>>(dp);
}

// Round 20
// 2808.262 us; speedup vs baseline: 1.9243x; 1.0487x over previous
//
#include <hip/hip_runtime.h>
#include <math.h>

#define B   256
#define TX  50
#define TY  100
#define NX  64
#define NY  64
#define H   512
#define HOR 60
#define M1  1024
#define M2  512
#define G3  (3*H)        // 1536
#define DIN (2*H + NY)   // 1088

typedef __attribute__((ext_vector_type(8))) short short8;
typedef __attribute__((ext_vector_type(4))) float floatx4;

__device__ __forceinline__ unsigned short f2bf(float f) {
    union { float f; unsigned u; } v; v.f = f;
    return (unsigned short)((v.u + 0x7FFFu + ((v.u >> 16) & 1u)) >> 16);
}

__device__ __forceinline__ float sigmoidf_(float v) {
    return 1.f / (1.f + __expf(-v));
}

__device__ __forceinline__ short8 ld8(const unsigned short* p) {
    return *(const short8*)p;
}

__device__ __forceinline__ floatx4 mfma16(short8 a, short8 b, floatx4 c) {
    return __builtin_amdgcn_mfma_f32_16x16x32_bf16(a, b, c, 0, 0, 0);
}

__device__ __forceinline__ void gload_lds16(const void* g, void* lds) {
    __builtin_amdgcn_global_load_lds(
        (const __attribute__((address_space(1))) void*)g,
        (__attribute__((address_space(3))) void*)lds, 16, 0, 0);
}

// BK=64 row layout: [row][8 chunks of 16B], row stride 128B.
// Swizzle (2-way bank aliasing): involution per row.
__device__ __forceinline__ int swz_src(int pc8, int row) {
    return (((pc8 >> 2) ^ (row & 1)) << 2) | ((pc8 & 3) ^ ((row >> 1) & 3));
}
__device__ __forceinline__ int swz_rd(int h, int lg, int row) {
    return (((h ^ (row & 1)) & 1) << 2) | ((lg ^ ((row >> 1) & 3)) & 3);
}

// ===========================================================================
// BMxBN MFMA GEMM body, 256 threads — BK=64 double-buffered K-pipeline.
// ===========================================================================
template<int BM, int BN>
__device__ __forceinline__ void mgemm_body(
    int tid, unsigned short* smA, unsigned short* smB,
    const unsigned short* __restrict__ A, int lda, int arow0,
    const unsigned short* __restrict__ W, int ldw, int wrow0,
    const float* __restrict__ bias,
    float* __restrict__ Cf, int ldcf,
    unsigned short* __restrict__ Cb, int ldcb,
    int K, int relu)
{
    constexpr int MF = BM / 32;
    constexpr int NF = BN / 32;
    const int w  = tid >> 6, l = tid & 63;
    const int wr = w >> 1, wc = w & 1;
    const int lg = l >> 4, r16 = l & 15;

    auto stage = [&](int k0, int buf) {
#pragma unroll
        for (int i = 0; i < BM / 32; ++i) {
            const int ci = tid + i * 256;
            const int row = ci >> 3, pc = ci & 7;
            const int lc = swz_src(pc, row);
            gload_lds16(A + (size_t)(arow0 + row) * lda + k0 + lc * 8,
                        (char*)smA + buf * (BM * 128) + ci * 16);
        }
#pragma unroll
        for (int i = 0; i < BN / 32; ++i) {
            const int ci = tid + i * 256;
            const int row = ci >> 3, pc = ci & 7;
            const int lc = swz_src(pc, row);
            gload_lds16(W + (size_t)(wrow0 + row) * ldw + k0 + lc * 8,
                        (char*)smB + buf * (BN * 128) + ci * 16);
        }
    };

    floatx4 acc[MF][NF];
#pragma unroll
    for (int m = 0; m < MF; ++m)
#pragma unroll
        for (int n = 0; n < NF; ++n) acc[m][n] = floatx4{0.f, 0.f, 0.f, 0.f};

    const int nk = K >> 6;
    stage(0, 0);
    for (int s = 0; s < nk; ++s) {
        __syncthreads();
        if (s + 1 < nk) stage((s + 1) << 6, (s + 1) & 1);
        const char* bA = (char*)smA + (s & 1) * (BM * 128);
        const char* bB = (char*)smB + (s & 1) * (BN * 128);
#pragma unroll
        for (int h = 0; h < 2; ++h) {
            short8 af[MF], bfr[NF];
#pragma unroll
            for (int m = 0; m < MF; ++m) {
                const int row = wr * (BM / 2) + m * 16 + r16;
                af[m] = *(const short8*)(bA + row * 128 + swz_rd(h, lg, row) * 16);
            }
#pragma unroll
            for (int n = 0; n < NF; ++n) {
                const int row = wc * (BN / 2) + n * 16 + r16;
                bfr[n] = *(const short8*)(bB + row * 128 + swz_rd(h, lg, row) * 16);
            }
#pragma unroll
            for (int m = 0; m < MF; ++m)
#pragma unroll
                for (int n = 0; n < NF; ++n)
                    acc[m][n] = mfma16(af[m], bfr[n], acc[m][n]);
        }
    }

#pragma unroll
    for (int m = 0; m < MF; ++m) {
#pragma unroll
        for (int n = 0; n < NF; ++n) {
#pragma unroll
            for (int j = 0; j < 4; ++j) {
                const int r = arow0 + wr * (BM / 2) + m * 16 + lg * 4 + j;
                const int c = wrow0 + wc * (BN / 2) + n * 16 + r16;
                float v = acc[m][n][j];
                if (bias) v += bias[c];
                if (relu && v < 0.f) v = 0.f;
                if (Cf) Cf[(size_t)r * ldcf + c] = v;
                if (Cb) Cb[(size_t)r * ldcb + c] = f2bf(v);
            }
        }
    }
}

template<int BM, int BN>
__global__ __launch_bounds__(256, 1) void k_mgemm(
    const unsigned short* __restrict__ A, int lda,
    const unsigned short* __restrict__ W, int ldw,
    const float* __restrict__ bias,
    float* __restrict__ Cf, int ldcf,
    unsigned short* __restrict__ Cb, int ldcb,
    int K, int relu)
{
    __shared__ __align__(16) unsigned short smA[2 * BM * 64];
    __shared__ __align__(16) unsigned short smB[2 * BN * 64];
    mgemm_body<BM, BN>(threadIdx.x, smA, smB, A, lda, blockIdx.y * BM,
                       W, ldw, blockIdx.x * BN, bias,
                       Cf, ldcf, Cb, ldcb, K, relu);
}

// ===========================================================================
// fused fp32 -> bf16 conversion (18 segments, one launch)
// ===========================================================================
struct CvtArgs {
    const float* src[18];
    unsigned short* dst[18];
    int n[18];
};

__global__ __launch_bounds__(256) void k_cvt_all(CvtArgs a)
{
    const int seg = blockIdx.y;
    const float* s = a.src[seg];
    unsigned short* d = a.dst[seg];
    const int c4 = a.n[seg] >> 2;
    for (int i = blockIdx.x * 256 + threadIdx.x; i < c4; i += gridDim.x * 256) {
        float4 v = ((const float4*)s)[i];
        ushort4 o;
        o.x = f2bf(v.x); o.y = f2bf(v.y); o.z = f2bf(v.z); o.w = f2bf(v.w);
        ((ushort4*)d)[i] = o;
    }
}

// ===========================================================================
// h_x = hxf + hxb ; h_y = hef + heb ; hcat = [h_x,h_y] bf16 ; cz[:, :H] = h_x
// ===========================================================================
__global__ __launch_bounds__(256) void k_sum_concat(
    const float* __restrict__ Hs,
    unsigned short* __restrict__ hcatb, unsigned short* __restrict__ czb)
{
    const int idx = blockIdx.x * 256 + threadIdx.x;  // B*H
    const int b = idx / H, i = idx % H;
    const float hx = Hs[idx] + Hs[(size_t)B * H + idx];
    const float hy = Hs[2 * (size_t)B * H + idx] + Hs[3 * (size_t)B * H + idx];
    const unsigned short hxb = f2bf(hx);
    hcatb[(size_t)b * (2 * H) + i] = hxb;
    hcatb[(size_t)b * (2 * H) + H + i] = f2bf(hy);
    czb[(size_t)b * (2 * H) + i] = hxb;
}

// ===========================================================================
// Fused encoder step — BK=64 pipeline, 16 hid-slices x variable batch split.
// Grid (16, nyb, njobs), rows = B/nyb (64 when nyb=4, 32 when nyb=8).
// 512 threads = 8 waves (4 row-groups x 2 col-groups); row-groups beyond
// `rows` compute garbage that is masked from the epilogue.
// ===========================================================================
struct EncP {
    const unsigned short *xb, *yb;
    unsigned short *Hsb0, *Hsb1;
    float* Hs;
    const unsigned short *wih[4], *whh[4];
    const float *bih[4], *bhh[4];
    int t, job0;
};

__global__ __launch_bounds__(512, 2) void k_enc_step(EncP p)
{
    __shared__ __align__(16) char smA[2 * 8192];    // 2 x 64x64 bf16 (max)
    __shared__ __align__(16) char smB[2 * 12288];   // 2 x 96x64 bf16
    const int job = p.job0 + blockIdx.z;
    const int h0 = blockIdx.x * 32;
    const int rows = B / gridDim.y;                 // 64 or 32
    const int row0 = blockIdx.y * rows;
    const int tid = threadIdx.x;
    const int w = tid >> 6, l = tid & 63;
    const int lg = l >> 4, r16 = l & 15;
    const int wrh = w >> 1, wcg = w & 1;   // 4 row-groups of 16, 2 col-groups
    const int T = (job < 2) ? TX : TY;
    const int tt = (job & 1) ? (T - 1 - p.t) : p.t;
    const unsigned short* xsrc = (job < 2) ? p.xb : p.yb;
    const unsigned short* wihg = p.wih[job];
    const unsigned short* whhg = p.whh[job];
    const unsigned short* hin =
        ((p.t & 1) ? p.Hsb1 : p.Hsb0) + (size_t)job * B * H;
    unsigned short* hout =
        ((p.t & 1) ? p.Hsb0 : p.Hsb1) + (size_t)job * B * H;

    // A staging: rows x 8 chunks (tid < rows*8 active)
    const int aRow = tid >> 3;
    const int aLc = swz_src(tid & 7, aRow);
    const bool aAct = (tid < rows * 8);
    // B staging: 96 rows x 8 chunks = 768 (1/thread + tid<256 second)
    const int b0row = tid >> 3;
    const int b0f = b0row >> 4;
    const int bWr0 = (b0f % 3) * H + h0 + (b0f / 3) * 16 + (b0row & 15);
    const int bLc0 = swz_src(tid & 7, b0row);
    const int c1 = 512 + tid;                    // tid<256 only
    const int b1row = c1 >> 3;
    const int b1f = b1row >> 4;
    const int bWr1 = (b1f % 3) * H + h0 + (b1f / 3) * 16 + (b1row & 15);
    const int bLc1 = swz_src(c1 & 7, b1row);

    auto stage = [&](int s, int buf) {
        char* dA = smA + buf * 8192;
        char* dB = smB + buf * 12288;
        if (s < 8) {
            const int k0 = s * 64;
            if (aAct)
                gload_lds16(hin + (size_t)(row0 + aRow) * H + k0 + aLc * 8,
                            dA + tid * 16);
            gload_lds16(whhg + (size_t)bWr0 * H + k0 + bLc0 * 8,
                        dB + tid * 16);
            if (tid < 256)
                gload_lds16(whhg + (size_t)bWr1 * H + k0 + bLc1 * 8,
                            dB + c1 * 16);
        } else {
            if (aAct)
                gload_lds16(xsrc + ((size_t)(row0 + aRow) * T + tt) * NX + aLc * 8,
                            dA + tid * 16);
            gload_lds16(wihg + (size_t)bWr0 * NX + bLc0 * 8,
                        dB + tid * 16);
            if (tid < 256)
                gload_lds16(wihg + (size_t)bWr1 * NX + bLc1 * 8,
                            dB + c1 * 16);
        }
    };

    floatx4 am[3], axn;
    axn = floatx4{0.f, 0.f, 0.f, 0.f};
#pragma unroll
    for (int g = 0; g < 3; ++g) am[g] = floatx4{0.f, 0.f, 0.f, 0.f};

    stage(0, 0);
    for (int s = 0; s < 9; ++s) {
        __syncthreads();
        if (s + 1 < 9) stage(s + 1, (s + 1) & 1);
        const char* bA = smA + (s & 1) * 8192;
        const char* bB = smB + (s & 1) * 12288;
        const bool isx = (s == 8);
#pragma unroll
        for (int h = 0; h < 2; ++h) {
            short8 af, bf[3];
            {
                const int row = wrh * 16 + r16;
                af = *(const short8*)(bA + row * 128 + swz_rd(h, lg, row) * 16);
            }
#pragma unroll
            for (int g = 0; g < 3; ++g) {
                const int rb = wcg * 48 + g * 16 + r16;
                bf[g] = *(const short8*)(bB + rb * 128 + swz_rd(h, lg, rb) * 16);
            }
            if (!isx) {
                am[0] = mfma16(af, bf[0], am[0]);
                am[1] = mfma16(af, bf[1], am[1]);
                am[2] = mfma16(af, bf[2], am[2]);
            } else {
                am[0] = mfma16(af, bf[0], am[0]);
                am[1] = mfma16(af, bf[1], am[1]);
                axn   = mfma16(af, bf[2], axn);
            }
        }
    }

    // ---- gate epilogue (masked for row-groups beyond `rows`) ----
    if (wrh * 16 < rows) {
        const int u = h0 + wcg * 16 + r16;
        const float bi0 = p.bih[job][u]        + p.bhh[job][u];
        const float bi1 = p.bih[job][H + u]    + p.bhh[job][H + u];
        const float bi2 = p.bih[job][2 * H + u];
        const float bh2 = p.bhh[job][2 * H + u];
        float* HsJ = p.Hs + (size_t)job * B * H;
#pragma unroll
        for (int j = 0; j < 4; ++j) {
            const int br = row0 + wrh * 16 + lg * 4 + j;
            const float rr = sigmoidf_(am[0][j] + bi0);
            const float zz = sigmoidf_(am[1][j] + bi1);
            const float nn = tanhf(axn[j] + bi2 + rr * (am[2][j] + bh2));
            const float hold = HsJ[(size_t)br * H + u];
            const float hv = (1.f - zz) * nn + zz * hold;
            HsJ[(size_t)br * H + u] = hv;
            hout[(size_t)br * H + u] = f2bf(hv);
        }
    }
}

// ===========================================================================
// Decoder step kernel (r19-proven) — 32 rows/block, grid (8, 8).
// Phase A: out-GEMM 32x64 (K=512, BK=64 dbuf, 2x4 waves / 16x16 tiles)
// Phase B: xgd (32 x 192 gate-cols) + gates.
// mode: 0 = t==0 (y from x[:,-1]), 1 = normal, 2 = out-only (final y).
// ===========================================================================
struct DecP {
    const unsigned short* xb;
    unsigned short* hdb;
    float* hd;
    const float* hga;
    const float* constb;
    const unsigned short* dWihb;
    const float* dbhh;
    const unsigned short* doWb; const float* dob;
    const unsigned short* hm2b;
    float* outp;
    int mode, tprev;
};

__global__ __launch_bounds__(512, 2) void k_dec_step(DecP p)
{
    __shared__ __align__(16) char sA[2 * 4096];          // hm2 tiles (32x64 dbuf)
    __shared__ __align__(16) char sW[2 * 8192];          // doW tiles (64x64 dbuf)
    __shared__ __align__(16) char sX[2 * 12288];         // dWih gate tiles (old fmt)
    __shared__ __align__(16) unsigned short ytile[32 * 64];   // swizzled
    const int tid = threadIdx.x;
    const int w = tid >> 6, l = tid & 63;
    const int lg = l >> 4, r16 = l & 15;
    const int row0 = blockIdx.y * 32;
    const int h0 = blockIdx.x * 64;

    // old-format staging math for sX (32-elem rows, 4-chunk swizzle)
    const int sAr = tid >> 2;
    const int sAl = (tid & 3) ^ ((sAr >> 1) & 3);
    const int f0 = sAr >> 4;
    const int W0 = (f0 % 3) * H + h0 + (f0 / 3) * 16 + (sAr & 15);
    const int sB1r = 128 + (tid >> 2);             // tid<256 only
    const int sB1l = (tid & 3) ^ ((sB1r >> 1) & 3);
    const int f1 = sB1r >> 4;
    const int W1 = (f1 % 3) * H + h0 + (f1 / 3) * 16 + (sB1r & 15);

    // ---- issue gate-tile staging immediately (completes under phase A) ----
    if (p.mode != 2) {
#pragma unroll
        for (int kc = 0; kc < 2; ++kc) {
            gload_lds16(p.dWihb + (size_t)W0 * DIN + 2 * H + kc * 32 + sAl * 8,
                        sX + kc * 12288 + tid * 16);
            if (tid < 256)
                gload_lds16(p.dWihb + (size_t)W1 * DIN + 2 * H + kc * 32 + sB1l * 8,
                            sX + kc * 12288 + 8192 + tid * 16);
        }
    }

    if (p.mode != 0) {
        // ---- phase A: y = hm2b @ doW^T + dob (32x64, K=512), BK=64 dbuf ----
        const int aRow = tid >> 3;                 // tid<256: 32 rows x 8 chunks
        const int aLc = swz_src(tid & 7, aRow);
        const int wRow = tid >> 3;                 // full 512: 64 rows x 8
        const int wLc = swz_src(tid & 7, wRow);
        auto stageA = [&](int s, int buf) {
            const int k0 = s * 64;
            if (tid < 256)
                gload_lds16(p.hm2b + (size_t)(row0 + aRow) * M2 + k0 + aLc * 8,
                            sA + buf * 4096 + tid * 16);
            gload_lds16(p.doWb + (size_t)wRow * M2 + k0 + wLc * 8,
                        sW + buf * 8192 + tid * 16);
        };
        const int wrA = w >> 2, wcA = w & 3;   // 2 x 4 waves, 16x16 tiles
        floatx4 acc = floatx4{0.f, 0.f, 0.f, 0.f};

        stageA(0, 0);
        for (int s = 0; s < 8; ++s) {
            __syncthreads();
            if (s + 1 < 8) stageA(s + 1, (s + 1) & 1);
            const char* bA = sA + (s & 1) * 4096;
            const char* bW = sW + (s & 1) * 8192;
#pragma unroll
            for (int h = 0; h < 2; ++h) {
                short8 av, bv;
                {
                    const int row = wrA * 16 + r16;
                    av = *(const short8*)(bA + row * 128 + swz_rd(h, lg, row) * 16);
                }
                {
                    const int row = wcA * 16 + r16;
                    bv = *(const short8*)(bW + row * 128 + swz_rd(h, lg, row) * 16);
                }
                acc = mfma16(av, bv, acc);
            }
        }
#pragma unroll
        for (int j = 0; j < 4; ++j) {
            const int rr = wrA * 16 + lg * 4 + j;
            const int cc = wcA * 16 + r16;
            const float v = acc[j] + p.dob[cc];
            if (blockIdx.x == 0)
                p.outp[(size_t)(row0 + rr) * (HOR * NY)
                       + (size_t)p.tprev * NY + cc] = v;
            *(unsigned short*)((char*)ytile + rr * 128
                + ((cc * 2) ^ ((rr & 7) << 4))) = f2bf(v);
        }
    } else {
        for (int i = tid; i < 32 * 64; i += 512) {
            const int rr = i >> 6, cc = i & 63;
            const unsigned short v =
                p.xb[((size_t)(row0 + rr) * TX + TX - 1) * NX + cc];
            *(unsigned short*)((char*)ytile + rr * 128
                + ((cc * 2) ^ ((rr & 7) << 4))) = v;
        }
    }
    if (p.mode == 2) return;
    __syncthreads();   // ytile ready; sX staging drained

    // ---- phase B: xgd (32 x 192 gate-cols, K=64 from sX) + gates ----
    const int wrh = w >> 2, wcg = w & 3;   // 2 row-groups of 16, 4 col-groups
    floatx4 ag[3];
#pragma unroll
    for (int g = 0; g < 3; ++g) ag[g] = floatx4{0.f, 0.f, 0.f, 0.f};
#pragma unroll
    for (int ks = 0; ks < 2; ++ks) {
        short8 ya, bf[3];
        {
            const int row = wrh * 16 + r16;
            const int k0 = ks * 32 + lg * 8;
            ya = *(const short8*)((char*)ytile + row * 128
                          + ((k0 * 2) ^ ((row & 7) << 4)));
        }
#pragma unroll
        for (int g = 0; g < 3; ++g) {
            const int rb = wcg * 48 + g * 16 + r16;
            bf[g] = *(const short8*)(sX + ks * 12288 + rb * 64
                          + ((lg ^ ((rb >> 1) & 3)) << 4));
        }
#pragma unroll
        for (int g = 0; g < 3; ++g)
            ag[g] = mfma16(ya, bf[g], ag[g]);
    }

    const int u = h0 + wcg * 16 + r16;
    const float db0 = p.dbhh[u], db1 = p.dbhh[H + u], db2 = p.dbhh[2 * H + u];
#pragma unroll
    for (int j = 0; j < 4; ++j) {
        const int b = row0 + wrh * 16 + lg * 4 + j;
        const size_t g3 = (size_t)b * G3;
        const float xr = ag[0][j] + p.constb[g3 + u];
        const float xz = ag[1][j] + p.constb[g3 + H + u];
        const float xn = ag[2][j] + p.constb[g3 + 2 * H + u];
        const float hr = p.hga[g3 + u] + db0;
        const float hz = p.hga[g3 + H + u] + db1;
        const float hn = p.hga[g3 + 2 * H + u] + db2;
        const float rr = sigmoidf_(xr + hr);
        const float zz = sigmoidf_(xz + hz);
        const float nn = tanhf(xn + rr * hn);
        const float hold = p.hd[(size_t)b * H + u];
        const float hv = (1.f - zz) * nn + zz * hold;
        p.hd[(size_t)b * H + u] = hv;
        p.hdb[(size_t)b * H + u] = f2bf(hv);
    }
}

// ===========================================================================
// kB: hga_next (96 roles, 64x64) || MLP1 (64 roles, 64x64) — 160 blocks.
// ===========================================================================
__global__ __launch_bounds__(256, 1) void k_dec_bk(
    const unsigned short* __restrict__ hdb,
    const unsigned short* __restrict__ dWhhb,
    const unsigned short* __restrict__ dmW1b, const float* __restrict__ dmb1,
    float* __restrict__ hga, unsigned short* __restrict__ hm1b)
{
    __shared__ __align__(16) unsigned short smA[2 * 64 * 64];
    __shared__ __align__(16) unsigned short smB[2 * 64 * 64];
    const int bid = blockIdx.x;
    if (bid < 96) {
        const int arow0 = (bid & 3) * 64, wrow0 = (bid >> 2) * 64;
        mgemm_body<64, 64>(threadIdx.x, smA, smB, hdb, H, arow0,
                           dWhhb, H, wrow0, nullptr,
                           hga, G3, nullptr, 0, H, 0);
    } else {
        const int b2 = bid - 96;
        const int arow0 = (b2 & 3) * 64, wrow0 = (b2 >> 2) * 64;
        mgemm_body<64, 64>(threadIdx.x, smA, smB, hdb, H, arow0,
                           dmW1b, H, wrow0, dmb1,
                           nullptr, 0, hm1b, M1, H, 1);
    }
}

// ===========================================================================
extern "C" void kernel_launch(void* const* d_in, const int* in_sizes, int n_in,
                              void* d_out, int out_size, void* d_ws, size_t ws_size,
                              hipStream_t stream)
{
    const float* x      = (const float*)d_in[0];
    const float* y      = (const float*)d_in[1];
    const float* xf_bih = (const float*)d_in[4];
    const float* xf_bhh = (const float*)d_in[5];
    const float* xb_bih = (const float*)d_in[8];
    const float* xb_bhh = (const float*)d_in[9];
    const float* ef_bih = (const float*)d_in[12];
    const float* ef_bhh = (const float*)d_in[13];
    const float* eb_bih = (const float*)d_in[16];
    const float* eb_bhh = (const float*)d_in[17];
    const float* em_b1  = (const float*)d_in[19];
    const float* em_b2  = (const float*)d_in[21];
    const float* eo_b   = (const float*)d_in[23];
    const float* d_bih  = (const float*)d_in[26];
    const float* d_bhh  = (const float*)d_in[27];
    const float* dm_b1  = (const float*)d_in[29];
    const float* dm_b2  = (const float*)d_in[31];
    const float* do_b   = (const float*)d_in[33];
    float* out = (float*)d_out;

    // ---- workspace carve-up ----
    float* fp = (float*)d_ws;
    float* Hs     = fp; fp += 4 * (size_t)B * H;
    float* hd     = fp; fp += (size_t)B * H;
    float* hga    = fp; fp += (size_t)B * G3;
    float* constb = fp; fp += (size_t)B * G3;

    unsigned short* up = (unsigned short*)fp;
    unsigned short* xb16  = up; up += (size_t)B * TX * NX;
    unsigned short* yb16  = up; up += (size_t)B * TY * NY;
    unsigned short* Hsb0  = up; up += 4 * (size_t)B * H;
    unsigned short* Hsb1  = up; up += 4 * (size_t)B * H;
    unsigned short* hdb   = up; up += (size_t)B * H;
    unsigned short* hcatb = up; up += (size_t)B * 2 * H;
    unsigned short* czb   = up; up += (size_t)B * 2 * H;
    unsigned short* h1b   = up; up += (size_t)B * M1;
    unsigned short* h2b   = up; up += (size_t)B * M2;
    unsigned short* hm1b  = up; up += (size_t)B * M1;
    unsigned short* hm2b  = up; up += (size_t)B * M2;

    const int    widx[16] = {2, 3, 6, 7, 10, 11, 14, 15, 18, 20, 22, 24, 25, 28, 30, 32};
    const size_t wsz[16]  = {
        (size_t)G3 * NX, (size_t)G3 * H, (size_t)G3 * NX, (size_t)G3 * H,
        (size_t)G3 * NX, (size_t)G3 * H, (size_t)G3 * NX, (size_t)G3 * H,
        (size_t)M1 * 2 * H, (size_t)M2 * M1, (size_t)H * M2,
        (size_t)G3 * DIN, (size_t)G3 * H, (size_t)M1 * H, (size_t)M2 * M1,
        (size_t)NY * M2};
    unsigned short* wb[16];
    for (int i = 0; i < 16; ++i) { wb[i] = up; up += wsz[i]; }

    // ---- conversions + state init ----
    CvtArgs ca;
    for (int i = 0; i < 16; ++i) {
        ca.src[i] = (const float*)d_in[widx[i]];
        ca.dst[i] = wb[i];
        ca.n[i]   = (int)wsz[i];
    }
    ca.src[16] = x; ca.dst[16] = xb16; ca.n[16] = B * TX * NX;
    ca.src[17] = y; ca.dst[17] = yb16; ca.n[17] = B * TY * NY;
    k_cvt_all<<<dim3(64, 18), 256, 0, stream>>>(ca);

    hipMemsetAsync(Hs,   0, sizeof(float) * 4 * (size_t)B * H, stream);
    hipMemsetAsync(Hsb0, 0, sizeof(unsigned short) * 4 * (size_t)B * H, stream);
    hipMemsetAsync(hd,   0, sizeof(float) * (size_t)B * H, stream);
    hipMemsetAsync(hga,  0, sizeof(float) * (size_t)B * G3, stream);

    // ---- encoder: 1 fused launch per step, full-machine grid always ----
    EncP ep;
    ep.xb = xb16; ep.yb = yb16; ep.Hsb0 = Hsb0; ep.Hsb1 = Hsb1; ep.Hs = Hs;
    ep.wih[0] = wb[0]; ep.whh[0] = wb[1];
    ep.wih[1] = wb[2]; ep.whh[1] = wb[3];
    ep.wih[2] = wb[4]; ep.whh[2] = wb[5];
    ep.wih[3] = wb[6]; ep.whh[3] = wb[7];
    ep.bih[0] = xf_bih; ep.bhh[0] = xf_bhh;
    ep.bih[1] = xb_bih; ep.bhh[1] = xb_bhh;
    ep.bih[2] = ef_bih; ep.bhh[2] = ef_bhh;
    ep.bih[3] = eb_bih; ep.bhh[3] = eb_bhh;
    for (int t = 0; t < TY; ++t) {
        ep.t = t;
        ep.job0 = (t < TX) ? 0 : 2;
        const int nj = (t < TX) ? 4 : 2;
        const int nyb = (t < TX) ? 4 : 8;
        k_enc_step<<<dim3(16, nyb, nj), 512, 0, stream>>>(ep);
    }

    // ---- bottleneck MLP ----
    k_sum_concat<<<B * H / 256, 256, 0, stream>>>(Hs, hcatb, czb);
    k_mgemm<128, 128><<<dim3(M1 / 128, B / 128), 256, 0, stream>>>(
        hcatb, 2 * H, wb[8], 2 * H, em_b1, nullptr, 0, h1b, M1, 2 * H, 1);
    k_mgemm<128, 128><<<dim3(M2 / 128, B / 128), 256, 0, stream>>>(
        h1b, M1, wb[9], M1, em_b2, nullptr, 0, h2b, M2, M1, 1);
    k_mgemm<128, 128><<<dim3(H / 128, B / 128), 256, 0, stream>>>(
        h2b, M2, wb[10], M2, eo_b, nullptr, 0, czb + H, 2 * H, M2, 0);
    k_mgemm<128, 128><<<dim3(G3 / 128, B / 128), 256, 0, stream>>>(
        czb, 2 * H, wb[11], DIN, d_bih, constb, G3, nullptr, 0, 2 * H, 0);

    // ---- decoder: 3 launches per step ----
    DecP dp;
    dp.xb = xb16; dp.hdb = hdb; dp.hd = hd; dp.hga = hga; dp.constb = constb;
    dp.dWihb = wb[11]; dp.dbhh = d_bhh;
    dp.doWb = wb[15]; dp.dob = do_b;
    dp.hm2b = hm2b; dp.outp = out;
    for (int t = 0; t < HOR; ++t) {
        dp.mode = (t == 0) ? 0 : 1;
        dp.tprev = t - 1;
        k_dec_step<<<dim3(8, 8), 512, 0, stream>>>(dp);
        k_dec_bk<<<160, 256, 0, stream>>>(hdb, wb[12], wb[13], dm_b1, hga, hm1b);
        k_mgemm<32, 32><<<dim3(M2 / 32, B / 32), 256, 0, stream>>>(
            hm1b, M1, wb[14], M1, dm_b2, nullptr, 0, hm2b, M2, M1, 1);
    }
    dp.mode = 2;
    dp.tprev = HOR - 1;
    k_dec_step<<<dim3(1, 8), 512, 0, stream>>>(dp);
}

// Round 21
// 2712.910 us; speedup vs baseline: 1.9919x; 1.0351x over previous
//
#include <hip/hip_runtime.h>
#include <math.h>

#define B   256
#define TX  50
#define TY  100
#define NX  64
#define NY  64
#define H   512
#define HOR 60
#define M1  1024
#define M2  512
#define G3  (3*H)        // 1536
#define DIN (2*H + NY)   // 1088

typedef __attribute__((ext_vector_type(8))) short short8;
typedef __attribute__((ext_vector_type(4))) float floatx4;

__device__ __forceinline__ unsigned short f2bf(float f) {
    union { float f; unsigned u; } v; v.f = f;
    return (unsigned short)((v.u + 0x7FFFu + ((v.u >> 16) & 1u)) >> 16);
}

__device__ __forceinline__ float sigmoidf_(float v) {
    return 1.f / (1.f + __expf(-v));
}

__device__ __forceinline__ short8 ld8(const unsigned short* p) {
    return *(const short8*)p;
}

__device__ __forceinline__ floatx4 mfma16(short8 a, short8 b, floatx4 c) {
    return __builtin_amdgcn_mfma_f32_16x16x32_bf16(a, b, c, 0, 0, 0);
}

__device__ __forceinline__ void gload_lds16(const void* g, void* lds) {
    __builtin_amdgcn_global_load_lds(
        (const __attribute__((address_space(1))) void*)g,
        (__attribute__((address_space(3))) void*)lds, 16, 0, 0);
}

// BK=64 row layout: [row][8 chunks of 16B], row stride 128B.
// Swizzle (2-way bank aliasing): involution per row.
__device__ __forceinline__ int swz_src(int pc8, int row) {
    return (((pc8 >> 2) ^ (row & 1)) << 2) | ((pc8 & 3) ^ ((row >> 1) & 3));
}
__device__ __forceinline__ int swz_rd(int h, int lg, int row) {
    return (((h ^ (row & 1)) & 1) << 2) | ((lg ^ ((row >> 1) & 3)) & 3);
}

// ===========================================================================
// BMxBN MFMA GEMM body, 256 threads — BK=64 double-buffered K-pipeline.
// ===========================================================================
template<int BM, int BN>
__device__ __forceinline__ void mgemm_body(
    int tid, unsigned short* smA, unsigned short* smB,
    const unsigned short* __restrict__ A, int lda, int arow0,
    const unsigned short* __restrict__ W, int ldw, int wrow0,
    const float* __restrict__ bias,
    float* __restrict__ Cf, int ldcf,
    unsigned short* __restrict__ Cb, int ldcb,
    int K, int relu)
{
    constexpr int MF = BM / 32;
    constexpr int NF = BN / 32;
    const int w  = tid >> 6, l = tid & 63;
    const int wr = w >> 1, wc = w & 1;
    const int lg = l >> 4, r16 = l & 15;

    auto stage = [&](int k0, int buf) {
#pragma unroll
        for (int i = 0; i < BM / 32; ++i) {
            const int ci = tid + i * 256;
            const int row = ci >> 3, pc = ci & 7;
            const int lc = swz_src(pc, row);
            gload_lds16(A + (size_t)(arow0 + row) * lda + k0 + lc * 8,
                        (char*)smA + buf * (BM * 128) + ci * 16);
        }
#pragma unroll
        for (int i = 0; i < BN / 32; ++i) {
            const int ci = tid + i * 256;
            const int row = ci >> 3, pc = ci & 7;
            const int lc = swz_src(pc, row);
            gload_lds16(W + (size_t)(wrow0 + row) * ldw + k0 + lc * 8,
                        (char*)smB + buf * (BN * 128) + ci * 16);
        }
    };

    floatx4 acc[MF][NF];
#pragma unroll
    for (int m = 0; m < MF; ++m)
#pragma unroll
        for (int n = 0; n < NF; ++n) acc[m][n] = floatx4{0.f, 0.f, 0.f, 0.f};

    const int nk = K >> 6;
    stage(0, 0);
    for (int s = 0; s < nk; ++s) {
        __syncthreads();
        if (s + 1 < nk) stage((s + 1) << 6, (s + 1) & 1);
        const char* bA = (char*)smA + (s & 1) * (BM * 128);
        const char* bB = (char*)smB + (s & 1) * (BN * 128);
#pragma unroll
        for (int h = 0; h < 2; ++h) {
            short8 af[MF], bfr[NF];
#pragma unroll
            for (int m = 0; m < MF; ++m) {
                const int row = wr * (BM / 2) + m * 16 + r16;
                af[m] = *(const short8*)(bA + row * 128 + swz_rd(h, lg, row) * 16);
            }
#pragma unroll
            for (int n = 0; n < NF; ++n) {
                const int row = wc * (BN / 2) + n * 16 + r16;
                bfr[n] = *(const short8*)(bB + row * 128 + swz_rd(h, lg, row) * 16);
            }
#pragma unroll
            for (int m = 0; m < MF; ++m)
#pragma unroll
                for (int n = 0; n < NF; ++n)
                    acc[m][n] = mfma16(af[m], bfr[n], acc[m][n]);
        }
    }

#pragma unroll
    for (int m = 0; m < MF; ++m) {
#pragma unroll
        for (int n = 0; n < NF; ++n) {
#pragma unroll
            for (int j = 0; j < 4; ++j) {
                const int r = arow0 + wr * (BM / 2) + m * 16 + lg * 4 + j;
                const int c = wrow0 + wc * (BN / 2) + n * 16 + r16;
                float v = acc[m][n][j];
                if (bias) v += bias[c];
                if (relu && v < 0.f) v = 0.f;
                if (Cf) Cf[(size_t)r * ldcf + c] = v;
                if (Cb) Cb[(size_t)r * ldcb + c] = f2bf(v);
            }
        }
    }
}

template<int BM, int BN>
__global__ __launch_bounds__(256, 1) void k_mgemm(
    const unsigned short* __restrict__ A, int lda,
    const unsigned short* __restrict__ W, int ldw,
    const float* __restrict__ bias,
    float* __restrict__ Cf, int ldcf,
    unsigned short* __restrict__ Cb, int ldcb,
    int K, int relu)
{
    __shared__ __align__(16) unsigned short smA[2 * BM * 64];
    __shared__ __align__(16) unsigned short smB[2 * BN * 64];
    mgemm_body<BM, BN>(threadIdx.x, smA, smB, A, lda, blockIdx.y * BM,
                       W, ldw, blockIdx.x * BN, bias,
                       Cf, ldcf, Cb, ldcb, K, relu);
}

// ===========================================================================
// fused fp32 -> bf16 conversion (18 segments, one launch)
// ===========================================================================
struct CvtArgs {
    const float* src[18];
    unsigned short* dst[18];
    int n[18];
};

__global__ __launch_bounds__(256) void k_cvt_all(CvtArgs a)
{
    const int seg = blockIdx.y;
    const float* s = a.src[seg];
    unsigned short* d = a.dst[seg];
    const int c4 = a.n[seg] >> 2;
    for (int i = blockIdx.x * 256 + threadIdx.x; i < c4; i += gridDim.x * 256) {
        float4 v = ((const float4*)s)[i];
        ushort4 o;
        o.x = f2bf(v.x); o.y = f2bf(v.y); o.z = f2bf(v.z); o.w = f2bf(v.w);
        ((ushort4*)d)[i] = o;
    }
}

// ===========================================================================
// h_x = hxf + hxb ; h_y = hef + heb ; hcat = [h_x,h_y] bf16 ; cz[:, :H] = h_x
// ===========================================================================
__global__ __launch_bounds__(256) void k_sum_concat(
    const float* __restrict__ Hs,
    unsigned short* __restrict__ hcatb, unsigned short* __restrict__ czb)
{
    const int idx = blockIdx.x * 256 + threadIdx.x;  // B*H
    const int b = idx / H, i = idx % H;
    const float hx = Hs[idx] + Hs[(size_t)B * H + idx];
    const float hy = Hs[2 * (size_t)B * H + idx] + Hs[3 * (size_t)B * H + idx];
    const unsigned short hxb = f2bf(hx);
    hcatb[(size_t)b * (2 * H) + i] = hxb;
    hcatb[(size_t)b * (2 * H) + H + i] = f2bf(hy);
    czb[(size_t)b * (2 * H) + i] = hxb;
}

// ===========================================================================
// Fused encoder step (r20-proven) — BK=64 pipeline, variable batch split.
// Grid (16, nyb, njobs), rows = B/nyb. 512 threads = 8 waves.
// ===========================================================================
struct EncP {
    const unsigned short *xb, *yb;
    unsigned short *Hsb0, *Hsb1;
    float* Hs;
    const unsigned short *wih[4], *whh[4];
    const float *bih[4], *bhh[4];
    int t, job0;
};

__global__ __launch_bounds__(512, 2) void k_enc_step(EncP p)
{
    __shared__ __align__(16) char smA[2 * 8192];    // 2 x 64x64 bf16 (max)
    __shared__ __align__(16) char smB[2 * 12288];   // 2 x 96x64 bf16
    const int job = p.job0 + blockIdx.z;
    const int h0 = blockIdx.x * 32;
    const int rows = B / gridDim.y;                 // 64 or 32
    const int row0 = blockIdx.y * rows;
    const int tid = threadIdx.x;
    const int w = tid >> 6, l = tid & 63;
    const int lg = l >> 4, r16 = l & 15;
    const int wrh = w >> 1, wcg = w & 1;   // 4 row-groups of 16, 2 col-groups
    const int T = (job < 2) ? TX : TY;
    const int tt = (job & 1) ? (T - 1 - p.t) : p.t;
    const unsigned short* xsrc = (job < 2) ? p.xb : p.yb;
    const unsigned short* wihg = p.wih[job];
    const unsigned short* whhg = p.whh[job];
    const unsigned short* hin =
        ((p.t & 1) ? p.Hsb1 : p.Hsb0) + (size_t)job * B * H;
    unsigned short* hout =
        ((p.t & 1) ? p.Hsb0 : p.Hsb1) + (size_t)job * B * H;

    // A staging: rows x 8 chunks (tid < rows*8 active)
    const int aRow = tid >> 3;
    const int aLc = swz_src(tid & 7, aRow);
    const bool aAct = (tid < rows * 8);
    // B staging: 96 rows x 8 chunks = 768 (1/thread + tid<256 second)
    const int b0row = tid >> 3;
    const int b0f = b0row >> 4;
    const int bWr0 = (b0f % 3) * H + h0 + (b0f / 3) * 16 + (b0row & 15);
    const int bLc0 = swz_src(tid & 7, b0row);
    const int c1 = 512 + tid;                    // tid<256 only
    const int b1row = c1 >> 3;
    const int b1f = b1row >> 4;
    const int bWr1 = (b1f % 3) * H + h0 + (b1f / 3) * 16 + (b1row & 15);
    const int bLc1 = swz_src(c1 & 7, b1row);

    auto stage = [&](int s, int buf) {
        char* dA = smA + buf * 8192;
        char* dB = smB + buf * 12288;
        if (s < 8) {
            const int k0 = s * 64;
            if (aAct)
                gload_lds16(hin + (size_t)(row0 + aRow) * H + k0 + aLc * 8,
                            dA + tid * 16);
            gload_lds16(whhg + (size_t)bWr0 * H + k0 + bLc0 * 8,
                        dB + tid * 16);
            if (tid < 256)
                gload_lds16(whhg + (size_t)bWr1 * H + k0 + bLc1 * 8,
                            dB + c1 * 16);
        } else {
            if (aAct)
                gload_lds16(xsrc + ((size_t)(row0 + aRow) * T + tt) * NX + aLc * 8,
                            dA + tid * 16);
            gload_lds16(wihg + (size_t)bWr0 * NX + bLc0 * 8,
                        dB + tid * 16);
            if (tid < 256)
                gload_lds16(wihg + (size_t)bWr1 * NX + bLc1 * 8,
                            dB + c1 * 16);
        }
    };

    floatx4 am[3], axn;
    axn = floatx4{0.f, 0.f, 0.f, 0.f};
#pragma unroll
    for (int g = 0; g < 3; ++g) am[g] = floatx4{0.f, 0.f, 0.f, 0.f};

    stage(0, 0);
    for (int s = 0; s < 9; ++s) {
        __syncthreads();
        if (s + 1 < 9) stage(s + 1, (s + 1) & 1);
        const char* bA = smA + (s & 1) * 8192;
        const char* bB = smB + (s & 1) * 12288;
        const bool isx = (s == 8);
#pragma unroll
        for (int h = 0; h < 2; ++h) {
            short8 af, bf[3];
            {
                const int row = wrh * 16 + r16;
                af = *(const short8*)(bA + row * 128 + swz_rd(h, lg, row) * 16);
            }
#pragma unroll
            for (int g = 0; g < 3; ++g) {
                const int rb = wcg * 48 + g * 16 + r16;
                bf[g] = *(const short8*)(bB + rb * 128 + swz_rd(h, lg, rb) * 16);
            }
            if (!isx) {
                am[0] = mfma16(af, bf[0], am[0]);
                am[1] = mfma16(af, bf[1], am[1]);
                am[2] = mfma16(af, bf[2], am[2]);
            } else {
                am[0] = mfma16(af, bf[0], am[0]);
                am[1] = mfma16(af, bf[1], am[1]);
                axn   = mfma16(af, bf[2], axn);
            }
        }
    }

    // ---- gate epilogue (masked for row-groups beyond `rows`) ----
    if (wrh * 16 < rows) {
        const int u = h0 + wcg * 16 + r16;
        const float bi0 = p.bih[job][u]        + p.bhh[job][u];
        const float bi1 = p.bih[job][H + u]    + p.bhh[job][H + u];
        const float bi2 = p.bih[job][2 * H + u];
        const float bh2 = p.bhh[job][2 * H + u];
        float* HsJ = p.Hs + (size_t)job * B * H;
#pragma unroll
        for (int j = 0; j < 4; ++j) {
            const int br = row0 + wrh * 16 + lg * 4 + j;
            const float rr = sigmoidf_(am[0][j] + bi0);
            const float zz = sigmoidf_(am[1][j] + bi1);
            const float nn = tanhf(axn[j] + bi2 + rr * (am[2][j] + bh2));
            const float hold = HsJ[(size_t)br * H + u];
            const float hv = (1.f - zz) * nn + zz * hold;
            HsJ[(size_t)br * H + u] = hv;
            hout[(size_t)br * H + u] = f2bf(hv);
        }
    }
}

// ===========================================================================
// Decoder step kernel (r19/r20-proven) — 32 rows/block, grid (8, 8).
// ===========================================================================
struct DecP {
    const unsigned short* xb;
    unsigned short* hdb;
    float* hd;
    const float* hga;
    const float* constb;
    const unsigned short* dWihb;
    const float* dbhh;
    const unsigned short* doWb; const float* dob;
    const unsigned short* hm2b;
    float* outp;
    int mode, tprev;
};

__global__ __launch_bounds__(512, 2) void k_dec_step(DecP p)
{
    __shared__ __align__(16) char sA[2 * 4096];          // hm2 tiles (32x64 dbuf)
    __shared__ __align__(16) char sW[2 * 8192];          // doW tiles (64x64 dbuf)
    __shared__ __align__(16) char sX[2 * 12288];         // dWih gate tiles (old fmt)
    __shared__ __align__(16) unsigned short ytile[32 * 64];   // swizzled
    const int tid = threadIdx.x;
    const int w = tid >> 6, l = tid & 63;
    const int lg = l >> 4, r16 = l & 15;
    const int row0 = blockIdx.y * 32;
    const int h0 = blockIdx.x * 64;

    // old-format staging math for sX (32-elem rows, 4-chunk swizzle)
    const int sAr = tid >> 2;
    const int sAl = (tid & 3) ^ ((sAr >> 1) & 3);
    const int f0 = sAr >> 4;
    const int W0 = (f0 % 3) * H + h0 + (f0 / 3) * 16 + (sAr & 15);
    const int sB1r = 128 + (tid >> 2);             // tid<256 only
    const int sB1l = (tid & 3) ^ ((sB1r >> 1) & 3);
    const int f1 = sB1r >> 4;
    const int W1 = (f1 % 3) * H + h0 + (f1 / 3) * 16 + (sB1r & 15);

    // ---- issue gate-tile staging immediately (completes under phase A) ----
    if (p.mode != 2) {
#pragma unroll
        for (int kc = 0; kc < 2; ++kc) {
            gload_lds16(p.dWihb + (size_t)W0 * DIN + 2 * H + kc * 32 + sAl * 8,
                        sX + kc * 12288 + tid * 16);
            if (tid < 256)
                gload_lds16(p.dWihb + (size_t)W1 * DIN + 2 * H + kc * 32 + sB1l * 8,
                            sX + kc * 12288 + 8192 + tid * 16);
        }
    }

    if (p.mode != 0) {
        // ---- phase A: y = hm2b @ doW^T + dob (32x64, K=512), BK=64 dbuf ----
        const int aRow = tid >> 3;                 // tid<256: 32 rows x 8 chunks
        const int aLc = swz_src(tid & 7, aRow);
        const int wRow = tid >> 3;                 // full 512: 64 rows x 8
        const int wLc = swz_src(tid & 7, wRow);
        auto stageA = [&](int s, int buf) {
            const int k0 = s * 64;
            if (tid < 256)
                gload_lds16(p.hm2b + (size_t)(row0 + aRow) * M2 + k0 + aLc * 8,
                            sA + buf * 4096 + tid * 16);
            gload_lds16(p.doWb + (size_t)wRow * M2 + k0 + wLc * 8,
                        sW + buf * 8192 + tid * 16);
        };
        const int wrA = w >> 2, wcA = w & 3;   // 2 x 4 waves, 16x16 tiles
        floatx4 acc = floatx4{0.f, 0.f, 0.f, 0.f};

        stageA(0, 0);
        for (int s = 0; s < 8; ++s) {
            __syncthreads();
            if (s + 1 < 8) stageA(s + 1, (s + 1) & 1);
            const char* bA = sA + (s & 1) * 4096;
            const char* bW = sW + (s & 1) * 8192;
#pragma unroll
            for (int h = 0; h < 2; ++h) {
                short8 av, bv;
                {
                    const int row = wrA * 16 + r16;
                    av = *(const short8*)(bA + row * 128 + swz_rd(h, lg, row) * 16);
                }
                {
                    const int row = wcA * 16 + r16;
                    bv = *(const short8*)(bW + row * 128 + swz_rd(h, lg, row) * 16);
                }
                acc = mfma16(av, bv, acc);
            }
        }
#pragma unroll
        for (int j = 0; j < 4; ++j) {
            const int rr = wrA * 16 + lg * 4 + j;
            const int cc = wcA * 16 + r16;
            const float v = acc[j] + p.dob[cc];
            if (blockIdx.x == 0)
                p.outp[(size_t)(row0 + rr) * (HOR * NY)
                       + (size_t)p.tprev * NY + cc] = v;
            *(unsigned short*)((char*)ytile + rr * 128
                + ((cc * 2) ^ ((rr & 7) << 4))) = f2bf(v);
        }
    } else {
        for (int i = tid; i < 32 * 64; i += 512) {
            const int rr = i >> 6, cc = i & 63;
            const unsigned short v =
                p.xb[((size_t)(row0 + rr) * TX + TX - 1) * NX + cc];
            *(unsigned short*)((char*)ytile + rr * 128
                + ((cc * 2) ^ ((rr & 7) << 4))) = v;
        }
    }
    if (p.mode == 2) return;
    __syncthreads();   // ytile ready; sX staging drained

    // ---- phase B: xgd (32 x 192 gate-cols, K=64 from sX) + gates ----
    const int wrh = w >> 2, wcg = w & 3;   // 2 row-groups of 16, 4 col-groups
    floatx4 ag[3];
#pragma unroll
    for (int g = 0; g < 3; ++g) ag[g] = floatx4{0.f, 0.f, 0.f, 0.f};
#pragma unroll
    for (int ks = 0; ks < 2; ++ks) {
        short8 ya, bf[3];
        {
            const int row = wrh * 16 + r16;
            const int k0 = ks * 32 + lg * 8;
            ya = *(const short8*)((char*)ytile + row * 128
                          + ((k0 * 2) ^ ((row & 7) << 4)));
        }
#pragma unroll
        for (int g = 0; g < 3; ++g) {
            const int rb = wcg * 48 + g * 16 + r16;
            bf[g] = *(const short8*)(sX + ks * 12288 + rb * 64
                          + ((lg ^ ((rb >> 1) & 3)) << 4));
        }
#pragma unroll
        for (int g = 0; g < 3; ++g)
            ag[g] = mfma16(ya, bf[g], ag[g]);
    }

    const int u = h0 + wcg * 16 + r16;
    const float db0 = p.dbhh[u], db1 = p.dbhh[H + u], db2 = p.dbhh[2 * H + u];
#pragma unroll
    for (int j = 0; j < 4; ++j) {
        const int b = row0 + wrh * 16 + lg * 4 + j;
        const size_t g3 = (size_t)b * G3;
        const float xr = ag[0][j] + p.constb[g3 + u];
        const float xz = ag[1][j] + p.constb[g3 + H + u];
        const float xn = ag[2][j] + p.constb[g3 + 2 * H + u];
        const float hr = p.hga[g3 + u] + db0;
        const float hz = p.hga[g3 + H + u] + db1;
        const float hn = p.hga[g3 + 2 * H + u] + db2;
        const float rr = sigmoidf_(xr + hr);
        const float zz = sigmoidf_(xz + hz);
        const float nn = tanhf(xn + rr * hn);
        const float hold = p.hd[(size_t)b * H + u];
        const float hv = (1.f - zz) * nn + zz * hold;
        p.hd[(size_t)b * H + u] = hv;
        p.hdb[(size_t)b * H + u] = f2bf(hv);
    }
}

// ===========================================================================
// kB: hga_next (192 roles, 64x32) || MLP1 (128 roles, 64x32) — 320 blocks.
// ===========================================================================
__global__ __launch_bounds__(256, 1) void k_dec_bk(
    const unsigned short* __restrict__ hdb,
    const unsigned short* __restrict__ dWhhb,
    const unsigned short* __restrict__ dmW1b, const float* __restrict__ dmb1,
    float* __restrict__ hga, unsigned short* __restrict__ hm1b)
{
    __shared__ __align__(16) unsigned short smA[2 * 64 * 64];
    __shared__ __align__(16) unsigned short smB[2 * 32 * 64];
    const int bid = blockIdx.x;
    if (bid < 192) {
        const int arow0 = (bid & 3) * 64, wrow0 = (bid >> 2) * 32;
        mgemm_body<64, 32>(threadIdx.x, smA, smB, hdb, H, arow0,
                           dWhhb, H, wrow0, nullptr,
                           hga, G3, nullptr, 0, H, 0);
    } else {
        const int b2 = bid - 192;
        const int arow0 = (b2 & 3) * 64, wrow0 = (b2 >> 2) * 32;
        mgemm_body<64, 32>(threadIdx.x, smA, smB, hdb, H, arow0,
                           dmW1b, H, wrow0, dmb1,
                           nullptr, 0, hm1b, M1, H, 1);
    }
}

// ===========================================================================
extern "C" void kernel_launch(void* const* d_in, const int* in_sizes, int n_in,
                              void* d_out, int out_size, void* d_ws, size_t ws_size,
                              hipStream_t stream)
{
    const float* x      = (const float*)d_in[0];
    const float* y      = (const float*)d_in[1];
    const float* xf_bih = (const float*)d_in[4];
    const float* xf_bhh = (const float*)d_in[5];
    const float* xb_bih = (const float*)d_in[8];
    const float* xb_bhh = (const float*)d_in[9];
    const float* ef_bih = (const float*)d_in[12];
    const float* ef_bhh = (const float*)d_in[13];
    const float* eb_bih = (const float*)d_in[16];
    const float* eb_bhh = (const float*)d_in[17];
    const float* em_b1  = (const float*)d_in[19];
    const float* em_b2  = (const float*)d_in[21];
    const float* eo_b   = (const float*)d_in[23];
    const float* d_bih  = (const float*)d_in[26];
    const float* d_bhh  = (const float*)d_in[27];
    const float* dm_b1  = (const float*)d_in[29];
    const float* dm_b2  = (const float*)d_in[31];
    const float* do_b   = (const float*)d_in[33];
    float* out = (float*)d_out;

    // ---- workspace carve-up ----
    float* fp = (float*)d_ws;
    float* Hs     = fp; fp += 4 * (size_t)B * H;
    float* hd     = fp; fp += (size_t)B * H;
    float* hga    = fp; fp += (size_t)B * G3;
    float* constb = fp; fp += (size_t)B * G3;

    unsigned short* up = (unsigned short*)fp;
    unsigned short* xb16  = up; up += (size_t)B * TX * NX;
    unsigned short* yb16  = up; up += (size_t)B * TY * NY;
    unsigned short* Hsb0  = up; up += 4 * (size_t)B * H;
    unsigned short* Hsb1  = up; up += 4 * (size_t)B * H;
    unsigned short* hdb   = up; up += (size_t)B * H;
    unsigned short* hcatb = up; up += (size_t)B * 2 * H;
    unsigned short* czb   = up; up += (size_t)B * 2 * H;
    unsigned short* h1b   = up; up += (size_t)B * M1;
    unsigned short* h2b   = up; up += (size_t)B * M2;
    unsigned short* hm1b  = up; up += (size_t)B * M1;
    unsigned short* hm2b  = up; up += (size_t)B * M2;

    const int    widx[16] = {2, 3, 6, 7, 10, 11, 14, 15, 18, 20, 22, 24, 25, 28, 30, 32};
    const size_t wsz[16]  = {
        (size_t)G3 * NX, (size_t)G3 * H, (size_t)G3 * NX, (size_t)G3 * H,
        (size_t)G3 * NX, (size_t)G3 * H, (size_t)G3 * NX, (size_t)G3 * H,
        (size_t)M1 * 2 * H, (size_t)M2 * M1, (size_t)H * M2,
        (size_t)G3 * DIN, (size_t)G3 * H, (size_t)M1 * H, (size_t)M2 * M1,
        (size_t)NY * M2};
    unsigned short* wb[16];
    for (int i = 0; i < 16; ++i) { wb[i] = up; up += wsz[i]; }

    // ---- conversions + state init ----
    CvtArgs ca;
    for (int i = 0; i < 16; ++i) {
        ca.src[i] = (const float*)d_in[widx[i]];
        ca.dst[i] = wb[i];
        ca.n[i]   = (int)wsz[i];
    }
    ca.src[16] = x; ca.dst[16] = xb16; ca.n[16] = B * TX * NX;
    ca.src[17] = y; ca.dst[17] = yb16; ca.n[17] = B * TY * NY;
    k_cvt_all<<<dim3(64, 18), 256, 0, stream>>>(ca);

    hipMemsetAsync(Hs,   0, sizeof(float) * 4 * (size_t)B * H, stream);
    hipMemsetAsync(Hsb0, 0, sizeof(unsigned short) * 4 * (size_t)B * H, stream);
    hipMemsetAsync(hd,   0, sizeof(float) * (size_t)B * H, stream);
    hipMemsetAsync(hga,  0, sizeof(float) * (size_t)B * G3, stream);

    // ---- encoder: 1 fused launch per step, full-machine grid always ----
    EncP ep;
    ep.xb = xb16; ep.yb = yb16; ep.Hsb0 = Hsb0; ep.Hsb1 = Hsb1; ep.Hs = Hs;
    ep.wih[0] = wb[0]; ep.whh[0] = wb[1];
    ep.wih[1] = wb[2]; ep.whh[1] = wb[3];
    ep.wih[2] = wb[4]; ep.whh[2] = wb[5];
    ep.wih[3] = wb[6]; ep.whh[3] = wb[7];
    ep.bih[0] = xf_bih; ep.bhh[0] = xf_bhh;
    ep.bih[1] = xb_bih; ep.bhh[1] = xb_bhh;
    ep.bih[2] = ef_bih; ep.bhh[2] = ef_bhh;
    ep.bih[3] = eb_bih; ep.bhh[3] = eb_bhh;
    for (int t = 0; t < TY; ++t) {
        ep.t = t;
        ep.job0 = (t < TX) ? 0 : 2;
        const int nj = (t < TX) ? 4 : 2;
        const int nyb = (t < TX) ? 4 : 8;
        k_enc_step<<<dim3(16, nyb, nj), 512, 0, stream>>>(ep);
    }

    // ---- bottleneck MLP ----
    k_sum_concat<<<B * H / 256, 256, 0, stream>>>(Hs, hcatb, czb);
    k_mgemm<128, 128><<<dim3(M1 / 128, B / 128), 256, 0, stream>>>(
        hcatb, 2 * H, wb[8], 2 * H, em_b1, nullptr, 0, h1b, M1, 2 * H, 1);
    k_mgemm<128, 128><<<dim3(M2 / 128, B / 128), 256, 0, stream>>>(
        h1b, M1, wb[9], M1, em_b2, nullptr, 0, h2b, M2, M1, 1);
    k_mgemm<128, 128><<<dim3(H / 128, B / 128), 256, 0, stream>>>(
        h2b, M2, wb[10], M2, eo_b, nullptr, 0, czb + H, 2 * H, M2, 0);
    k_mgemm<128, 128><<<dim3(G3 / 128, B / 128), 256, 0, stream>>>(
        czb, 2 * H, wb[11], DIN, d_bih, constb, G3, nullptr, 0, 2 * H, 0);

    // ---- decoder: 3 launches per step ----
    DecP dp;
    dp.xb = xb16; dp.hdb = hdb; dp.hd = hd; dp.hga = hga; dp.constb = constb;
    dp.dWihb = wb[11]; dp.dbhh = d_bhh;
    dp.doWb = wb[15]; dp.dob = do_b;
    dp.hm2b = hm2b; dp.outp = out;
    for (int t = 0; t < HOR; ++t) {
        dp.mode = (t == 0) ? 0 : 1;
        dp.tprev = t - 1;
        k_dec_step<<<dim3(8, 8), 512, 0, stream>>>(dp);
        k_dec_bk<<<320, 256, 0, stream>>>(hdb, wb[12], wb[13], dm_b1, hga, hm1b);
        k_mgemm<32, 32><<<dim3(M2 / 32, B / 32), 256, 0, stream>>>(
            hm1b, M1, wb[14], M1, dm_b2, nullptr, 0, hm2b, M2, M1, 1);
    }
    dp.mode = 2;
    dp.tprev = HOR - 1;
    k_dec_step<<<dim3(1, 8), 512, 0, stream>>>(dp);
}